// Round 1
// baseline (4447.755 us; speedup 1.0000x reference)
//
#include <hip/hip_runtime.h>
#include <hip/hip_bf16.h>
#include <math.h>

// ---------------------------------------------------------------------------
// GPT forward on MI355X. Round 1: correctness-first bf16-MFMA implementation.
//   x = tok_emb[ids] + pos_emb
//   8 x { ln1, qkv, scores(causal), softmax, pv, out+res, ln2, fc1+gelu, fc2+res }
//   lnf, logits = x @ tok_emb^T
// All GEMMs: bf16 MFMA 16x16x32, fp32 accumulate, inputs converted fp32->bf16
// during LDS staging.
// ---------------------------------------------------------------------------

#define DEV_INLINE __device__ __forceinline__

typedef float  f32x4  __attribute__((ext_vector_type(4)));
typedef __bf16 bf16x8 __attribute__((ext_vector_type(8)));
typedef short  s16x4  __attribute__((ext_vector_type(4)));
typedef unsigned int u32x4 __attribute__((ext_vector_type(4)));

#define BBATCH 2
#define TSEQ   1024
#define DMODEL 1024
#define NHEAD  16
#define HDIM   64
#define NLAYER 8
#define NVOCAB 32000
#define MTOK   (BBATCH*TSEQ)   // 2048

DEV_INLINE short f2bf(float f) {
    union { float f; unsigned u; } x; x.f = f;
    unsigned u = x.u;
    unsigned r = (u + 0x7FFFu + ((u >> 16) & 1u)) >> 16;  // RNE
    return (short)r;
}
DEV_INLINE float bf2f(short s) {
    union { unsigned u; float f; } x; x.u = ((unsigned)(unsigned short)s) << 16;
    return x.f;
}

DEV_INLINE float block_sum(float v) {
    __shared__ float sb[4];
    #pragma unroll
    for (int o = 32; o > 0; o >>= 1) v += __shfl_down(v, o, 64);
    if ((threadIdx.x & 63) == 0) sb[threadIdx.x >> 6] = v;
    __syncthreads();
    float r = sb[0] + sb[1] + sb[2] + sb[3];
    __syncthreads();
    return r;
}
DEV_INLINE float block_max(float v) {
    __shared__ float sm[4];
    #pragma unroll
    for (int o = 32; o > 0; o >>= 1) v = fmaxf(v, __shfl_down(v, o, 64));
    if ((threadIdx.x & 63) == 0) sm[threadIdx.x >> 6] = v;
    __syncthreads();
    float r = fmaxf(fmaxf(sm[0], sm[1]), fmaxf(sm[2], sm[3]));
    __syncthreads();
    return r;
}

// ---------------------------------------------------------------------------
// Generic 128x128 tile GEMM, BK=32, 4 waves (2x2), 16x16x32 bf16 MFMA.
//   BT:     B is stored [N][K] (row-major over N) instead of [K][N]
//   ABF16:  A is already bf16 (P matrix); else fp32
//   EPI:    0 = store f32
//           1 = store bf16 scaled (scores)
//           2 = store f32 + bias[n] + resid[m][n]
//           3 = store f32 gelu(acc + bias[n])
//   CAUSAL: 0 none; 1 = skip blocks fully above diagonal (scores);
//           2 = clip K to bm0+128 (pv)
// Batched over blockIdx.z: z -> (zb = z/Hdiv, zh = z%Hdiv); element offsets
//   A += zb*sAb + zh*sAh  (same for B, C).
// Requires: M % 128 == 0, K % 32 == 0 (Keff too). N arbitrary (guarded).
// ---------------------------------------------------------------------------
#define LDK 40   // 32 + 8 pad (keeps 16B alignment, breaks bank stride)

template<bool BT, bool ABF16, int EPI, int CAUSAL>
__global__ __launch_bounds__(256) void gemm_k(
    const void* __restrict__ Ag, const float* __restrict__ Bg,
    void* __restrict__ Cg, const float* __restrict__ bias,
    const float* __restrict__ resid,
    int M, int N, int K, int lda, int ldb, int ldc, int Hdiv,
    long long sAb, long long sAh, long long sBb, long long sBh,
    long long sCb, long long sCh, float scale)
{
    const int bn0 = blockIdx.x * 128;
    const int bm0 = blockIdx.y * 128;
    if (CAUSAL == 1 && bn0 > bm0 + 127) return;

    const int z  = blockIdx.z;
    const int zb = z / Hdiv, zh = z - zb * Hdiv;

    const float* Af = nullptr; const short* Ab = nullptr;
    if (ABF16) Ab = (const short*)Ag + zb * sAb + zh * sAh;
    else       Af = (const float*)Ag + zb * sAb + zh * sAh;
    const float* Bp = Bg + zb * sBb + zh * sBh;

    __shared__ short Als[128][LDK];
    __shared__ short Bls[128][LDK];

    const int tid  = threadIdx.x;
    const int lane = tid & 63;
    const int wave = tid >> 6;
    const int wm = wave >> 1, wn = wave & 1;
    const int lr = lane & 15, kg = lane >> 4;

    f32x4 acc[4][4] = {};

    int Keff = K;
    if (CAUSAL == 2) { int kl = bm0 + 128; Keff = (kl < K) ? kl : K; }
    const int nk = Keff >> 5;

    const int sm  = tid >> 1;          // staging row 0..127
    const int sk  = (tid & 1) << 4;    // 0 or 16
    const int bn4 = (tid & 31) << 2;   // non-BT B staging: n offset 0..124
    const int bkq = (tid >> 5) << 2;   // non-BT B staging: k offset 0..28

    for (int kt = 0; kt < nk; ++kt) {
        const int k0 = kt << 5;
        // ---- stage A tile: rows bm0..+127, k k0..+31
        {
            union { u32x4 q[2]; short s[16]; } aw;
            if (ABF16) {
                const short* ap = Ab + (long long)(bm0 + sm) * lda + k0 + sk;
                aw.q[0] = *(const u32x4*)ap;
                aw.q[1] = *(const u32x4*)(ap + 8);
            } else {
                const float* ap = Af + (long long)(bm0 + sm) * lda + k0 + sk;
                float4 v0 = *(const float4*)(ap + 0);
                float4 v1 = *(const float4*)(ap + 4);
                float4 v2 = *(const float4*)(ap + 8);
                float4 v3 = *(const float4*)(ap + 12);
                aw.s[0]=f2bf(v0.x); aw.s[1]=f2bf(v0.y); aw.s[2]=f2bf(v0.z); aw.s[3]=f2bf(v0.w);
                aw.s[4]=f2bf(v1.x); aw.s[5]=f2bf(v1.y); aw.s[6]=f2bf(v1.z); aw.s[7]=f2bf(v1.w);
                aw.s[8]=f2bf(v2.x); aw.s[9]=f2bf(v2.y); aw.s[10]=f2bf(v2.z); aw.s[11]=f2bf(v2.w);
                aw.s[12]=f2bf(v3.x); aw.s[13]=f2bf(v3.y); aw.s[14]=f2bf(v3.z); aw.s[15]=f2bf(v3.w);
            }
            *(u32x4*)&Als[sm][sk]     = aw.q[0];
            *(u32x4*)&Als[sm][sk + 8] = aw.q[1];
        }
        // ---- stage B tile into Bls[n][k]
        if (BT) {
            union { u32x4 q[2]; short s[16]; } bw;
            const float* bp = Bp + (long long)(bn0 + sm) * ldb + k0 + sk;
            float4 v0 = *(const float4*)(bp + 0);
            float4 v1 = *(const float4*)(bp + 4);
            float4 v2 = *(const float4*)(bp + 8);
            float4 v3 = *(const float4*)(bp + 12);
            bw.s[0]=f2bf(v0.x); bw.s[1]=f2bf(v0.y); bw.s[2]=f2bf(v0.z); bw.s[3]=f2bf(v0.w);
            bw.s[4]=f2bf(v1.x); bw.s[5]=f2bf(v1.y); bw.s[6]=f2bf(v1.z); bw.s[7]=f2bf(v1.w);
            bw.s[8]=f2bf(v2.x); bw.s[9]=f2bf(v2.y); bw.s[10]=f2bf(v2.z); bw.s[11]=f2bf(v2.w);
            bw.s[12]=f2bf(v3.x); bw.s[13]=f2bf(v3.y); bw.s[14]=f2bf(v3.z); bw.s[15]=f2bf(v3.w);
            *(u32x4*)&Bls[sm][sk]     = bw.q[0];
            *(u32x4*)&Bls[sm][sk + 8] = bw.q[1];
        } else {
            const int gn = bn0 + bn4;
            float4 r0 = {0,0,0,0}, r1 = {0,0,0,0}, r2 = {0,0,0,0}, r3 = {0,0,0,0};
            if (gn + 3 < N) {
                const float* bp = Bp + (long long)(k0 + bkq) * ldb + gn;
                r0 = *(const float4*)(bp);
                r1 = *(const float4*)(bp + ldb);
                r2 = *(const float4*)(bp + 2 * ldb);
                r3 = *(const float4*)(bp + 3 * ldb);
            }
            s16x4 w0 = { f2bf(r0.x), f2bf(r1.x), f2bf(r2.x), f2bf(r3.x) };
            s16x4 w1 = { f2bf(r0.y), f2bf(r1.y), f2bf(r2.y), f2bf(r3.y) };
            s16x4 w2 = { f2bf(r0.z), f2bf(r1.z), f2bf(r2.z), f2bf(r3.z) };
            s16x4 w3 = { f2bf(r0.w), f2bf(r1.w), f2bf(r2.w), f2bf(r3.w) };
            *(s16x4*)&Bls[bn4 + 0][bkq] = w0;
            *(s16x4*)&Bls[bn4 + 1][bkq] = w1;
            *(s16x4*)&Bls[bn4 + 2][bkq] = w2;
            *(s16x4*)&Bls[bn4 + 3][bkq] = w3;
        }
        __syncthreads();
        // ---- compute: frag k-layout: elem e -> k = kg*4 + (e&3) + 16*(e>>2)
        union Frag { bf16x8 v; s16x4 h[2]; } af[4], bfr[4];
        #pragma unroll
        for (int i = 0; i < 4; ++i) {
            af[i].h[0] = *(const s16x4*)&Als[wm * 64 + i * 16 + lr][kg * 4];
            af[i].h[1] = *(const s16x4*)&Als[wm * 64 + i * 16 + lr][kg * 4 + 16];
        }
        #pragma unroll
        for (int j = 0; j < 4; ++j) {
            bfr[j].h[0] = *(const s16x4*)&Bls[wn * 64 + j * 16 + lr][kg * 4];
            bfr[j].h[1] = *(const s16x4*)&Bls[wn * 64 + j * 16 + lr][kg * 4 + 16];
        }
        #pragma unroll
        for (int i = 0; i < 4; ++i)
            #pragma unroll
            for (int j = 0; j < 4; ++j)
                acc[i][j] = __builtin_amdgcn_mfma_f32_16x16x32_bf16(
                    af[i].v, bfr[j].v, acc[i][j], 0, 0, 0);
        __syncthreads();
    }

    // ---- epilogue: D elem p -> row = kg*4+p, col = lr
    if (EPI == 1) {
        short* Cs = (short*)Cg + zb * sCb + zh * sCh;
        #pragma unroll
        for (int i = 0; i < 4; ++i)
            #pragma unroll
            for (int j = 0; j < 4; ++j) {
                const int gr = bm0 + wm * 64 + i * 16 + kg * 4;
                const int gc = bn0 + wn * 64 + j * 16 + lr;
                if (gc < N) {
                    #pragma unroll
                    for (int p = 0; p < 4; ++p)
                        Cs[(long long)(gr + p) * ldc + gc] = f2bf(acc[i][j][p] * scale);
                }
            }
    } else {
        float* Cf = (float*)Cg + zb * sCb + zh * sCh;
        #pragma unroll
        for (int i = 0; i < 4; ++i)
            #pragma unroll
            for (int j = 0; j < 4; ++j) {
                const int gr = bm0 + wm * 64 + i * 16 + kg * 4;
                const int gc = bn0 + wn * 64 + j * 16 + lr;
                if (gc < N) {
                    #pragma unroll
                    for (int p = 0; p < 4; ++p) {
                        float v = acc[i][j][p];
                        if (EPI == 2)
                            v += bias[gc] + resid[(long long)(gr + p) * ldc + gc];
                        if (EPI == 3) {
                            v += bias[gc];
                            v = 0.5f * v * (1.0f + erff(v * 0.70710678118654752f));
                        }
                        Cf[(long long)(gr + p) * ldc + gc] = v;
                    }
                }
            }
    }
}

// ---------------------------------------------------------------------------
__global__ __launch_bounds__(256) void embed_k(
    const int* __restrict__ ids, const float* __restrict__ tok,
    const float* __restrict__ pos, float* __restrict__ x)
{
    const int gid = blockIdx.x * 256 + threadIdx.x;   // MTOK*256 total
    const int row = gid >> 8;
    const int c   = (gid & 255) << 2;
    const int t   = row & (TSEQ - 1);
    const int id  = ids[row];
    const float4 a = *(const float4*)&tok[(long long)id * DMODEL + c];
    const float4 p = *(const float4*)&pos[(long long)t * DMODEL + c];
    float4 o; o.x = a.x + p.x; o.y = a.y + p.y; o.z = a.z + p.z; o.w = a.w + p.w;
    *(float4*)&x[(long long)row * DMODEL + c] = o;
}

__global__ __launch_bounds__(256) void ln_k(
    const float* __restrict__ x, const float* __restrict__ w,
    const float* __restrict__ b, float* __restrict__ o)
{
    const int row = blockIdx.x;
    const float* xp = x + (long long)row * DMODEL;
    const int i = threadIdx.x * 4;
    float4 v = *(const float4*)&xp[i];
    float s  = v.x + v.y + v.z + v.w;
    float s2 = v.x * v.x + v.y * v.y + v.z * v.z + v.w * v.w;
    s  = block_sum(s);
    s2 = block_sum(s2);
    const float mean = s * (1.0f / DMODEL);
    const float var  = s2 * (1.0f / DMODEL) - mean * mean;
    const float rs   = rsqrtf(var + 1e-5f);
    float4 wv = *(const float4*)&w[i];
    float4 bv = *(const float4*)&b[i];
    float4 ov;
    ov.x = (v.x - mean) * rs * wv.x + bv.x;
    ov.y = (v.y - mean) * rs * wv.y + bv.y;
    ov.z = (v.z - mean) * rs * wv.z + bv.z;
    ov.w = (v.w - mean) * rs * wv.w + bv.w;
    *(float4*)&o[(long long)row * DMODEL + i] = ov;
}

// Row softmax over causal-masked bf16 scores; writes normalized bf16 P
// (zeros beyond the diagonal so PV can run un-masked).
__global__ __launch_bounds__(256) void softmax_k(
    const short* __restrict__ S, short* __restrict__ P)
{
    const int row = blockIdx.x;            // z*TSEQ + q
    const int q   = row & (TSEQ - 1);
    const short* sp = S + (long long)row * TSEQ;
    short*       pp = P + (long long)row * TSEQ;
    const int i0 = threadIdx.x * 4;
    s16x4 raw = *(const s16x4*)&sp[i0];
    float v0 = (i0 + 0 <= q) ? bf2f(raw[0]) : -1e30f;
    float v1 = (i0 + 1 <= q) ? bf2f(raw[1]) : -1e30f;
    float v2 = (i0 + 2 <= q) ? bf2f(raw[2]) : -1e30f;
    float v3 = (i0 + 3 <= q) ? bf2f(raw[3]) : -1e30f;
    float m = fmaxf(fmaxf(v0, v1), fmaxf(v2, v3));
    m = block_max(m);
    float e0 = expf(v0 - m), e1 = expf(v1 - m), e2 = expf(v2 - m), e3 = expf(v3 - m);
    float s = block_sum(e0 + e1 + e2 + e3);
    const float inv = 1.0f / s;
    s16x4 o;
    o[0] = f2bf(e0 * inv); o[1] = f2bf(e1 * inv);
    o[2] = f2bf(e2 * inv); o[3] = f2bf(e3 * inv);
    *(s16x4*)&pp[i0] = o;
}

// ---------------------------------------------------------------------------
extern "C" void kernel_launch(void* const* d_in, const int* in_sizes, int n_in,
                              void* d_out, int out_size, void* d_ws, size_t ws_size,
                              hipStream_t stream)
{
    const int*   ids  = (const int*)  d_in[0];
    const float* tok  = (const float*)d_in[1];
    const float* pos  = (const float*)d_in[2];
    const float* ln1w = (const float*)d_in[3];
    const float* ln1b = (const float*)d_in[4];
    const float* qkvw = (const float*)d_in[5];
    const float* outw = (const float*)d_in[6];
    const float* outb = (const float*)d_in[7];
    const float* ln2w = (const float*)d_in[8];
    const float* ln2b = (const float*)d_in[9];
    const float* fc1w = (const float*)d_in[10];
    const float* fc1b = (const float*)d_in[11];
    const float* fc2w = (const float*)d_in[12];
    const float* fc2b = (const float*)d_in[13];
    const float* lnfw = (const float*)d_in[14];
    const float* lnfb = (const float*)d_in[15];

    char* ws = (char*)d_ws;
    const size_t MB = 1024 * 1024;
    float* x   = (float*)(ws + 0);          //  8 MB  [2048,1024]
    float* h   = (float*)(ws + 8  * MB);    //  8 MB  [2048,1024] (ln out / attn out / lnf out)
    float* qkv = (float*)(ws + 16 * MB);    // 24 MB  [2048,3072]
    short* S   = (short*)(ws + 40 * MB);    // 64 MB  [32,1024,1024] bf16
    short* P   = (short*)(ws + 104 * MB);   // 64 MB  [32,1024,1024] bf16
    float* g   = (float*)(ws + 40 * MB);    // 32 MB  [2048,4096] (aliases S; disjoint phase)
    float* out = (float*)d_out;             // [2048,32000] f32

    const long long sQb = (long long)TSEQ * 3 * DMODEL;  // batch stride in qkv buf
    const long long sSb = (long long)NHEAD * TSEQ * TSEQ;
    const long long sSh = (long long)TSEQ * TSEQ;

    dim3 blk(256);
    embed_k<<<MTOK, blk, 0, stream>>>(ids, tok, pos, x);

    for (int l = 0; l < NLAYER; ++l) {
        ln_k<<<MTOK, blk, 0, stream>>>(x, ln1w + l * DMODEL, ln1b + l * DMODEL, h);

        // qkv = h @ qkv_w[l]   [2048,1024]x[1024,3072]
        gemm_k<false, false, 0, 0><<<dim3(24, 16, 1), blk, 0, stream>>>(
            h, qkvw + (long long)l * DMODEL * 3 * DMODEL, qkv, nullptr, nullptr,
            MTOK, 3 * DMODEL, DMODEL, DMODEL, 3 * DMODEL, 3 * DMODEL, 1,
            0, 0, 0, 0, 0, 0, 1.0f);

        // S[z] = scale * Q K^T  (skip fully-masked upper blocks)
        gemm_k<true, false, 1, 1><<<dim3(8, 8, BBATCH * NHEAD), blk, 0, stream>>>(
            qkv, qkv + DMODEL, S, nullptr, nullptr,
            TSEQ, TSEQ, HDIM, 3 * DMODEL, 3 * DMODEL, TSEQ, NHEAD,
            sQb, HDIM, sQb, HDIM, sSb, sSh, 0.125f);

        softmax_k<<<BBATCH * NHEAD * TSEQ, blk, 0, stream>>>(S, P);

        // attn_out[z] = P V   -> h   (K clipped to diagonal)
        gemm_k<false, true, 0, 2><<<dim3(1, 8, BBATCH * NHEAD), blk, 0, stream>>>(
            P, qkv + 2 * DMODEL, h, nullptr, nullptr,
            TSEQ, HDIM, TSEQ, TSEQ, 3 * DMODEL, DMODEL, NHEAD,
            sSb, sSh, sQb, HDIM, (long long)TSEQ * DMODEL, HDIM, 1.0f);

        // x = x + attn_out @ out_w[l] + out_b[l]
        gemm_k<false, false, 2, 0><<<dim3(8, 16, 1), blk, 0, stream>>>(
            h, outw + (long long)l * DMODEL * DMODEL, x, outb + l * DMODEL, x,
            MTOK, DMODEL, DMODEL, DMODEL, DMODEL, DMODEL, 1,
            0, 0, 0, 0, 0, 0, 1.0f);

        ln_k<<<MTOK, blk, 0, stream>>>(x, ln2w + l * DMODEL, ln2b + l * DMODEL, h);

        // g = gelu(h @ fc1_w[l] + fc1_b[l])
        gemm_k<false, false, 3, 0><<<dim3(32, 16, 1), blk, 0, stream>>>(
            h, fc1w + (long long)l * DMODEL * 4 * DMODEL, g,
            fc1b + (long long)l * 4 * DMODEL, nullptr,
            MTOK, 4 * DMODEL, DMODEL, DMODEL, 4 * DMODEL, 4 * DMODEL, 1,
            0, 0, 0, 0, 0, 0, 1.0f);

        // x = x + g @ fc2_w[l] + fc2_b[l]
        gemm_k<false, false, 2, 0><<<dim3(8, 16, 1), blk, 0, stream>>>(
            g, fc2w + (long long)l * 4 * DMODEL * DMODEL, x, fc2b + l * DMODEL, x,
            MTOK, DMODEL, 4 * DMODEL, 4 * DMODEL, DMODEL, DMODEL, 1,
            0, 0, 0, 0, 0, 0, 1.0f);
    }

    ln_k<<<MTOK, blk, 0, stream>>>(x, lnfw, lnfb, h);

    // logits = h @ tok_emb^T
    gemm_k<true, false, 0, 0><<<dim3(NVOCAB / 128, 16, 1), blk, 0, stream>>>(
        h, tok, out, nullptr, nullptr,
        MTOK, NVOCAB, DMODEL, DMODEL, DMODEL, NVOCAB, 1,
        0, 0, 0, 0, 0, 0, 1.0f);
}

// Round 2
// 2388.835 us; speedup vs baseline: 1.8619x; 1.8619x over previous
//
#include <hip/hip_runtime.h>
#include <hip/hip_bf16.h>
#include <math.h>

// ---------------------------------------------------------------------------
// GPT forward, round 2: all GEMMs bf16-MFMA with global_load_lds staging,
// swizzled LDS (pre-swizzled global source), XCD grid swizzle.
// Weights converted fp32->bf16 (transposed to [N][K]) once per call.
// ---------------------------------------------------------------------------

#define DEV_INLINE __device__ __forceinline__

typedef float  f32x4  __attribute__((ext_vector_type(4)));
typedef __bf16 bf16x8 __attribute__((ext_vector_type(8)));
typedef short  s16x4  __attribute__((ext_vector_type(4)));
typedef short  s16x8  __attribute__((ext_vector_type(8)));

#define BBATCH 2
#define TSEQ   1024
#define DMODEL 1024
#define NHEAD  16
#define HDIM   64
#define NLAYER 8
#define NVOCAB 32000
#define MTOK   (BBATCH*TSEQ)   // 2048

DEV_INLINE short f2bf(float f) {
    __bf16 h = (__bf16)f;
    union { __bf16 h; short s; } u; u.h = h; return u.s;
}
DEV_INLINE float bf2f(short s) {
    union { unsigned u; float f; } x; x.u = ((unsigned)(unsigned short)s) << 16;
    return x.f;
}

typedef const __attribute__((address_space(1))) unsigned int* gas_t;
typedef __attribute__((address_space(3))) unsigned int* las_t;
DEV_INLINE void llds16(const void* g, void* l) {
    __builtin_amdgcn_global_load_lds((gas_t)g, (las_t)l, 16, 0, 0);
}

DEV_INLINE float block_sum(float v) {
    __shared__ float sb[4];
    #pragma unroll
    for (int o = 32; o > 0; o >>= 1) v += __shfl_down(v, o, 64);
    if ((threadIdx.x & 63) == 0) sb[threadIdx.x >> 6] = v;
    __syncthreads();
    float r = sb[0] + sb[1] + sb[2] + sb[3];
    __syncthreads();
    return r;
}

// ---------------------------------------------------------------------------
// GEMM: A bf16 [M][K] (lda), B bf16 [N][K] (ldb), 128x(BN)x64 tiles, 4 waves.
// EPI: 0 = f32 plain, 1 = bf16 * scale, 2 = f32 + bias[n] + resid, 3 = bf16
//      gelu(acc + bias[n]).
// CAUSAL: 0 none, 1 skip blocks fully above diagonal, 2 clip K to bm0+128.
// Staging: global_load_lds 16B; LDS tile [rows][64] bf16 with 16B-chunk XOR
// swizzle (chunk ^= row&7) applied on the *global source address*, so reads
// use the same XOR and fragments are single ds_read_b128. A and B share the
// same k-permutation, which cancels in the MFMA dot product.
// ---------------------------------------------------------------------------
template<int BN, int EPI, int CAUSAL>
__global__ __launch_bounds__(256) void gemm_k(
    const short* __restrict__ Ag, const short* __restrict__ Bg,
    void* __restrict__ Cg, const float* __restrict__ bias,
    const float* __restrict__ resid,
    int M, int N, int K, int lda, int ldb, int ldc, int Hdiv,
    long long sAb, long long sAh, long long sBb, long long sBh,
    long long sCb, long long sCh, float scale, int swz)
{
    int bx = blockIdx.x, by = blockIdx.y;
    if (swz) {
        const int gx = gridDim.x;
        const int nwg = gx * gridDim.y;
        if ((nwg & 7) == 0) {
            int wg = by * gx + bx;
            int wg2 = (wg & 7) * (nwg >> 3) + (wg >> 3);
            bx = wg2 % gx; by = wg2 / gx;
        }
    }
    const int bn0 = bx * BN, bm0 = by * 128;
    if (CAUSAL == 1 && bn0 > bm0 + 127) return;

    const int z  = blockIdx.z;
    const int zb = z / Hdiv, zh = z - zb * Hdiv;
    const short* A = Ag + zb * sAb + zh * sAh;
    const short* B = Bg + zb * sBb + zh * sBh;

    __shared__ short Als[128 * 64];
    __shared__ short Bls[BN * 64];

    const int tid  = threadIdx.x;
    const int lane = tid & 63;
    const int wave = tid >> 6;
    constexpr int WMS = (BN == 128) ? 64 : 32;   // wave m-span
    constexpr int MI  = (BN == 128) ? 4 : 2;
    constexpr int NJ  = 4;
    const int wm = (BN == 128) ? (wave >> 1) : wave;
    const int wn = (BN == 128) ? (wave & 1) : 0;
    const int lr = lane & 15, kg = lane >> 4;
    const int xv = (lr & 7) << 4;                 // read-side byte XOR

    // staging geometry: thread -> (row 0..31 per iter, swizzled 16B chunk)
    const int sr = tid >> 3;                       // 0..31
    const int sc = (tid & 7) ^ (sr & 7);           // swizzled chunk 0..7
    const short* aP = A + (long long)(bm0 + sr) * lda + sc * 8;
    const short* bP = B + (long long)(bn0 + sr) * ldb + sc * 8;
    short* aL = &Als[wave * 512];
    short* bL = &Bls[wave * 512];

    f32x4 acc[MI][NJ] = {};

    int Keff = K;
    if (CAUSAL == 2) { int kl = bm0 + 128; Keff = (kl < K) ? kl : K; }
    const int nk = Keff >> 6;

    for (int kt = 0; kt < nk; ++kt) {
        const int k0 = kt << 6;
        #pragma unroll
        for (int it = 0; it < 4; ++it)
            llds16(aP + (long long)it * 32 * lda + k0, aL + it * 2048);
        #pragma unroll
        for (int it = 0; it < BN / 32; ++it)
            llds16(bP + (long long)it * 32 * ldb + k0, bL + it * 2048);
        __syncthreads();

        #pragma unroll
        for (int s = 0; s < 2; ++s) {
            const int ofs = (((s << 6) | (kg << 4)) ^ xv) >> 1;  // shorts
            bf16x8 af[MI], bf[NJ];
            #pragma unroll
            for (int i = 0; i < MI; ++i)
                af[i] = *(const bf16x8*)&Als[(wm * WMS + i * 16 + lr) * 64 + ofs];
            #pragma unroll
            for (int j = 0; j < NJ; ++j)
                bf[j] = *(const bf16x8*)&Bls[(wn * 64 + j * 16 + lr) * 64 + ofs];
            #pragma unroll
            for (int i = 0; i < MI; ++i)
                #pragma unroll
                for (int j = 0; j < NJ; ++j)
                    acc[i][j] = __builtin_amdgcn_mfma_f32_16x16x32_bf16(
                        af[i], bf[j], acc[i][j], 0, 0, 0);
        }
        __syncthreads();
    }

    // epilogue: C/D elem p -> row kg*4+p, col lr
    short* Cs = (short*)Cg + zb * sCb + zh * sCh;
    float* Cf = (float*)Cg + zb * sCb + zh * sCh;
    #pragma unroll
    for (int i = 0; i < MI; ++i) {
        #pragma unroll
        for (int j = 0; j < NJ; ++j) {
            const int gr = bm0 + wm * WMS + i * 16 + kg * 4;
            const int gc = bn0 + wn * 64 + j * 16 + lr;
            #pragma unroll
            for (int p = 0; p < 4; ++p) {
                const long long off = (long long)(gr + p) * ldc + gc;
                float v = acc[i][j][p];
                if (EPI == 0) {
                    Cf[off] = v;
                } else if (EPI == 1) {
                    Cs[off] = f2bf(v * scale);
                } else if (EPI == 2) {
                    Cf[off] = v + bias[gc] + resid[off];
                } else {
                    v += bias[gc];
                    v = 0.5f * v * (1.0f + erff(v * 0.70710678118654752f));
                    Cs[off] = f2bf(v);
                }
            }
        }
    }
}

// ---------------------------------------------------------------------------
__global__ __launch_bounds__(256) void embed_k(
    const int* __restrict__ ids, const float* __restrict__ tok,
    const float* __restrict__ pos, float* __restrict__ x)
{
    const int gid = blockIdx.x * 256 + threadIdx.x;
    const int row = gid >> 8;
    const int c   = (gid & 255) << 2;
    const int t   = row & (TSEQ - 1);
    const int id  = ids[row];
    const float4 a = *(const float4*)&tok[(long long)id * DMODEL + c];
    const float4 p = *(const float4*)&pos[(long long)t * DMODEL + c];
    float4 o; o.x = a.x + p.x; o.y = a.y + p.y; o.z = a.z + p.z; o.w = a.w + p.w;
    *(float4*)&x[(long long)row * DMODEL + c] = o;
}

__global__ __launch_bounds__(256) void ln_k(
    const float* __restrict__ x, const float* __restrict__ w,
    const float* __restrict__ b, short* __restrict__ o)
{
    const int row = blockIdx.x;
    const float* xp = x + (long long)row * DMODEL;
    const int i = threadIdx.x * 4;
    float4 v = *(const float4*)&xp[i];
    float s  = v.x + v.y + v.z + v.w;
    float s2 = v.x * v.x + v.y * v.y + v.z * v.z + v.w * v.w;
    s  = block_sum(s);
    s2 = block_sum(s2);
    const float mean = s * (1.0f / DMODEL);
    const float var  = s2 * (1.0f / DMODEL) - mean * mean;
    const float rs   = rsqrtf(var + 1e-5f);
    float4 wv = *(const float4*)&w[i];
    float4 bv = *(const float4*)&b[i];
    s16x4 ov;
    ov[0] = f2bf((v.x - mean) * rs * wv.x + bv.x);
    ov[1] = f2bf((v.y - mean) * rs * wv.y + bv.y);
    ov[2] = f2bf((v.z - mean) * rs * wv.z + bv.z);
    ov[3] = f2bf((v.w - mean) * rs * wv.w + bv.w);
    *(s16x4*)&o[(long long)row * DMODEL + i] = ov;
}

// wave-per-row in-place causal softmax over bf16 scores [32*1024 rows][1024]
__global__ __launch_bounds__(256) void softmax_k(short* __restrict__ S)
{
    const int row  = blockIdx.x * 4 + (threadIdx.x >> 6);
    const int q    = row & (TSEQ - 1);
    const int lane = threadIdx.x & 63;
    short* sp = S + (long long)row * TSEQ + lane * 16;
    s16x8 r0 = *(const s16x8*)sp;
    s16x8 r1 = *(const s16x8*)(sp + 8);
    float f[16];
    float m = -1e30f;
    #pragma unroll
    for (int i = 0; i < 16; ++i) {
        const int col = lane * 16 + i;
        const short raw = (i < 8) ? r0[i] : r1[i - 8];
        f[i] = (col <= q) ? bf2f(raw) : -1e30f;
        m = fmaxf(m, f[i]);
    }
    #pragma unroll
    for (int o = 1; o < 64; o <<= 1) m = fmaxf(m, __shfl_xor(m, o, 64));
    float sum = 0.f;
    #pragma unroll
    for (int i = 0; i < 16; ++i) { f[i] = __expf(f[i] - m); sum += f[i]; }
    #pragma unroll
    for (int o = 1; o < 64; o <<= 1) sum += __shfl_xor(sum, o, 64);
    const float inv = 1.0f / sum;
    s16x8 w0, w1;
    #pragma unroll
    for (int i = 0; i < 8; ++i) { w0[i] = f2bf(f[i] * inv); w1[i] = f2bf(f[i + 8] * inv); }
    *(s16x8*)sp = w0;
    *(s16x8*)(sp + 8) = w1;
}

// transpose-convert: src [R][C] (T = float|short) -> dst bf16 [C][R], 64x64 tiles
template<typename T>
__global__ __launch_bounds__(256) void tcvt_k(
    const T* __restrict__ src, short* __restrict__ dst,
    int lds_, int ldd, int Hdiv,
    long long sSb, long long sSh, long long sDb, long long sDh)
{
    __shared__ short ls[64][68];
    const int z = blockIdx.z, zb = z / Hdiv, zh = z - zb * Hdiv;
    const T* sp = src + zb * sSb + zh * sSh;
    short* dp = dst + zb * sDb + zh * sDh;
    const int tr0 = blockIdx.y * 64, tc0 = blockIdx.x * 64;
    const int t = threadIdx.x;
    const int rr = t >> 4, cc = (t & 15) * 4;
    #pragma unroll
    for (int q = 0; q < 4; ++q) {
        const int r = q * 16 + rr;
        if constexpr (sizeof(T) == 4) {
            float4 v = *(const float4*)&sp[(long long)(tr0 + r) * lds_ + tc0 + cc];
            ls[cc + 0][r] = f2bf(v.x); ls[cc + 1][r] = f2bf(v.y);
            ls[cc + 2][r] = f2bf(v.z); ls[cc + 3][r] = f2bf(v.w);
        } else {
            s16x4 v = *(const s16x4*)&sp[(long long)(tr0 + r) * lds_ + tc0 + cc];
            ls[cc + 0][r] = v[0]; ls[cc + 1][r] = v[1];
            ls[cc + 2][r] = v[2]; ls[cc + 3][r] = v[3];
        }
    }
    __syncthreads();
    #pragma unroll
    for (int q = 0; q < 4; ++q) {
        const int c = q * 16 + rr;
        s16x4 v;
        v[0] = ls[c][cc]; v[1] = ls[c][cc + 1]; v[2] = ls[c][cc + 2]; v[3] = ls[c][cc + 3];
        *(s16x4*)&dp[(long long)(tc0 + c) * ldd + tr0 + cc] = v;
    }
}

// plain fp32 -> bf16 convert (n4 = count/4)
__global__ __launch_bounds__(256) void cvt_k(
    const float* __restrict__ s, short* __restrict__ d, int n4)
{
    int i = blockIdx.x * 256 + threadIdx.x;
    const int stride = gridDim.x * 256;
    for (; i < n4; i += stride) {
        float4 v = *(const float4*)&s[(long long)i * 4];
        s16x4 o = { f2bf(v.x), f2bf(v.y), f2bf(v.z), f2bf(v.w) };
        *(s16x4*)&d[(long long)i * 4] = o;
    }
}

// ---------------------------------------------------------------------------
extern "C" void kernel_launch(void* const* d_in, const int* in_sizes, int n_in,
                              void* d_out, int out_size, void* d_ws, size_t ws_size,
                              hipStream_t stream)
{
    const int*   ids  = (const int*)  d_in[0];
    const float* tok  = (const float*)d_in[1];
    const float* pos  = (const float*)d_in[2];
    const float* ln1w = (const float*)d_in[3];
    const float* ln1b = (const float*)d_in[4];
    const float* qkvw = (const float*)d_in[5];
    const float* outw = (const float*)d_in[6];
    const float* outb = (const float*)d_in[7];
    const float* ln2w = (const float*)d_in[8];
    const float* ln2b = (const float*)d_in[9];
    const float* fc1w = (const float*)d_in[10];
    const float* fc1b = (const float*)d_in[11];
    const float* fc2w = (const float*)d_in[12];
    const float* fc2b = (const float*)d_in[13];
    const float* lnfw = (const float*)d_in[14];
    const float* lnfb = (const float*)d_in[15];
    float* out = (float*)d_out;

    char* ws = (char*)d_ws;
    const size_t MB = 1024 * 1024;
    float* x    = (float*)(ws);             //  8 MB f32 residual
    short* hb   = (short*)(ws + 8 * MB);    //  4 MB bf16 [2048][1024]
    short* qkvb = (short*)(ws + 12 * MB);   // 12 MB bf16 [2048][3072]
    short* S    = (short*)(ws + 24 * MB);   // 64 MB bf16 [32][1024][1024]
    short* g    = (short*)(ws + 24 * MB);   // 16 MB bf16 (aliases S)
    short* Vt   = (short*)(ws + 88 * MB);   //  4 MB bf16 [32][64][1024]

    const bool big = ws_size >= (size_t)352 * MB;
    short *wq, *wo, *w1, *w2, *tokb;
    if (big) {
        wq   = (short*)(ws + 92  * MB);     // 48 MB (8 layers)
        wo   = (short*)(ws + 140 * MB);     // 16 MB
        w1   = (short*)(ws + 156 * MB);     // 64 MB
        w2   = (short*)(ws + 220 * MB);     // 64 MB
        tokb = (short*)(ws + 284 * MB);     // 62.5 MB
    } else {
        wq   = (short*)(ws + 92  * MB);     //  6 MB (per-layer JIT)
        wo   = (short*)(ws + 98  * MB);     //  2 MB
        w1   = (short*)(ws + 100 * MB);     //  8 MB
        w2   = (short*)(ws + 108 * MB);     //  8 MB
        tokb = (short*)(ws + 24  * MB);     // aliases S (dead by lm_head)
    }

    const long long LWQ = 3072LL * 1024, LWO = 1024LL * 1024;
    const long long LW1 = 4096LL * 1024, LW2 = 1024LL * 4096;

    dim3 blk(256);
    embed_k<<<MTOK, blk, 0, stream>>>(ids, tok, pos, x);

    if (big) {
        tcvt_k<float><<<dim3(48, 16, 8), blk, 0, stream>>>(qkvw, wq, 3072, 1024, 1, LWQ, 0, LWQ, 0);
        tcvt_k<float><<<dim3(16, 16, 8), blk, 0, stream>>>(outw, wo, 1024, 1024, 1, LWO, 0, LWO, 0);
        tcvt_k<float><<<dim3(64, 16, 8), blk, 0, stream>>>(fc1w, w1, 4096, 1024, 1, LW1, 0, LW1, 0);
        tcvt_k<float><<<dim3(16, 64, 8), blk, 0, stream>>>(fc2w, w2, 1024, 4096, 1, LW2, 0, LW2, 0);
        cvt_k<<<2048, blk, 0, stream>>>(tok, tokb, NVOCAB * DMODEL / 4);
    }

    for (int l = 0; l < NLAYER; ++l) {
        short* wql = wq + (big ? l * LWQ : 0);
        short* wol = wo + (big ? l * LWO : 0);
        short* w1l = w1 + (big ? l * LW1 : 0);
        short* w2l = w2 + (big ? l * LW2 : 0);
        if (!big) {
            tcvt_k<float><<<dim3(48, 16, 1), blk, 0, stream>>>(qkvw + l * LWQ, wql, 3072, 1024, 1, 0, 0, 0, 0);
            tcvt_k<float><<<dim3(16, 16, 1), blk, 0, stream>>>(outw + l * LWO, wol, 1024, 1024, 1, 0, 0, 0, 0);
            tcvt_k<float><<<dim3(64, 16, 1), blk, 0, stream>>>(fc1w + l * LW1, w1l, 4096, 1024, 1, 0, 0, 0, 0);
            tcvt_k<float><<<dim3(16, 64, 1), blk, 0, stream>>>(fc2w + l * LW2, w2l, 1024, 4096, 1, 0, 0, 0, 0);
        }

        ln_k<<<MTOK, blk, 0, stream>>>(x, ln1w + l * DMODEL, ln1b + l * DMODEL, hb);

        // qkv = ln1 @ Wqkv   [2048,1024]x[1024,3072] -> bf16
        gemm_k<128, 1, 0><<<dim3(24, 16, 1), blk, 0, stream>>>(
            hb, wql, qkvb, nullptr, nullptr,
            MTOK, 3 * DMODEL, DMODEL, DMODEL, DMODEL, 3 * DMODEL, 1,
            0, 0, 0, 0, 0, 0, 1.0f, 1);

        // S[z] = 0.125 * Q K^T (bf16, causal block skip)
        gemm_k<128, 1, 1><<<dim3(8, 8, BBATCH * NHEAD), blk, 0, stream>>>(
            qkvb, qkvb + DMODEL, S, nullptr, nullptr,
            TSEQ, TSEQ, HDIM, 3 * DMODEL, 3 * DMODEL, TSEQ, NHEAD,
            (long long)TSEQ * 3 * DMODEL, HDIM,
            (long long)TSEQ * 3 * DMODEL, HDIM,
            (long long)NHEAD * TSEQ * TSEQ, (long long)TSEQ * TSEQ, 0.125f, 0);

        softmax_k<<<BBATCH * NHEAD * TSEQ / 4, blk, 0, stream>>>(S);

        // Vt[z] = V^T  [64][1024] per head
        tcvt_k<short><<<dim3(1, 16, BBATCH * NHEAD), blk, 0, stream>>>(
            qkvb + 2 * DMODEL, Vt, 3 * DMODEL, TSEQ, NHEAD,
            (long long)TSEQ * 3 * DMODEL, HDIM,
            (long long)NHEAD * HDIM * TSEQ, (long long)HDIM * TSEQ);

        // attn = P V -> hb (bf16), K clipped at diagonal
        gemm_k<64, 1, 2><<<dim3(1, 8, BBATCH * NHEAD), blk, 0, stream>>>(
            S, Vt, hb, nullptr, nullptr,
            TSEQ, HDIM, TSEQ, TSEQ, TSEQ, DMODEL, NHEAD,
            (long long)NHEAD * TSEQ * TSEQ, (long long)TSEQ * TSEQ,
            (long long)NHEAD * HDIM * TSEQ, (long long)HDIM * TSEQ,
            (long long)TSEQ * DMODEL, HDIM, 1.0f, 0);

        // x += attn @ Wout + b
        gemm_k<128, 2, 0><<<dim3(8, 16, 1), blk, 0, stream>>>(
            hb, wol, x, outb + l * DMODEL, x,
            MTOK, DMODEL, DMODEL, DMODEL, DMODEL, DMODEL, 1,
            0, 0, 0, 0, 0, 0, 1.0f, 1);

        ln_k<<<MTOK, blk, 0, stream>>>(x, ln2w + l * DMODEL, ln2b + l * DMODEL, hb);

        // g = gelu(ln2 @ Wfc1 + b) -> bf16
        gemm_k<128, 3, 0><<<dim3(32, 16, 1), blk, 0, stream>>>(
            hb, w1l, g, fc1b + (long long)l * 4 * DMODEL, nullptr,
            MTOK, 4 * DMODEL, DMODEL, DMODEL, DMODEL, 4 * DMODEL, 1,
            0, 0, 0, 0, 0, 0, 1.0f, 1);

        // x += g @ Wfc2 + b
        gemm_k<128, 2, 0><<<dim3(8, 16, 1), blk, 0, stream>>>(
            g, w2l, x, fc2b + l * DMODEL, x,
            MTOK, DMODEL, 4 * DMODEL, 4 * DMODEL, 4 * DMODEL, DMODEL, 1,
            0, 0, 0, 0, 0, 0, 1.0f, 1);
    }

    ln_k<<<MTOK, blk, 0, stream>>>(x, lnfw, lnfb, hb);

    if (!big)
        cvt_k<<<2048, blk, 0, stream>>>(tok, tokb, NVOCAB * DMODEL / 4);

    // logits = lnf @ tok_emb^T  [2048,1024]x[32000,1024]^T -> f32
    gemm_k<128, 0, 0><<<dim3(NVOCAB / 128, 16, 1), blk, 0, stream>>>(
        hb, tokb, out, nullptr, nullptr,
        MTOK, NVOCAB, DMODEL, DMODEL, DMODEL, NVOCAB, 1,
        0, 0, 0, 0, 0, 0, 1.0f, 1);
}

// Round 4
// 2072.496 us; speedup vs baseline: 2.1461x; 1.1526x over previous
//
#include <hip/hip_runtime.h>
#include <hip/hip_bf16.h>
#include <math.h>

// ---------------------------------------------------------------------------
// GPT forward, round 4: round-3 structure with the gemm256_k last-tile vmcnt
// drain fixed (vmcnt(4) was a no-op on the final tile -> race under replay).
// ---------------------------------------------------------------------------

#define DEV_INLINE __device__ __forceinline__

typedef float  f32x4  __attribute__((ext_vector_type(4)));
typedef __bf16 bf16x8 __attribute__((ext_vector_type(8)));
typedef short  s16x4  __attribute__((ext_vector_type(4)));
typedef short  s16x8  __attribute__((ext_vector_type(8)));

#define BBATCH 2
#define TSEQ   1024
#define DMODEL 1024
#define NHEAD  16
#define HDIM   64
#define NLAYER 8
#define NVOCAB 32000
#define MTOK   (BBATCH*TSEQ)   // 2048

DEV_INLINE short f2bf(float f) {
    __bf16 h = (__bf16)f;
    union { __bf16 h; short s; } u; u.h = h; return u.s;
}
DEV_INLINE float bf2f(short s) {
    union { unsigned u; float f; } x; x.u = ((unsigned)(unsigned short)s) << 16;
    return x.f;
}

typedef const __attribute__((address_space(1))) unsigned int* gas_t;
typedef __attribute__((address_space(3))) unsigned int* las_t;
DEV_INLINE void llds16(const void* g, void* l) {
    __builtin_amdgcn_global_load_lds((gas_t)g, (las_t)l, 16, 0, 0);
}

#define BAR()  asm volatile("s_barrier" ::: "memory")
#define VMW4() asm volatile("s_waitcnt vmcnt(4)" ::: "memory")
#define VMW2() asm volatile("s_waitcnt vmcnt(2)" ::: "memory")
#define VMW0() asm volatile("s_waitcnt vmcnt(0)" ::: "memory")

DEV_INLINE float block_sum(float v) {
    __shared__ float sb[4];
    #pragma unroll
    for (int o = 32; o > 0; o >>= 1) v += __shfl_down(v, o, 64);
    if ((threadIdx.x & 63) == 0) sb[threadIdx.x >> 6] = v;
    __syncthreads();
    float r = sb[0] + sb[1] + sb[2] + sb[3];
    __syncthreads();
    return r;
}

// ---------------------------------------------------------------------------
// 256x256x(BK=64) 8-wave 8-phase GEMM, f32 output. A bf16 [M][K], B bf16
// [N][K]. LDS: 2 buffers x { A-half0, A-half1, B-half0, B-half1 } of
// 128x64 bf16 (16 KB) each = 128 KB dynamic. Staging order per K-tile:
// A0,B0,A1,B1 (one half per phase, 2 loads/thread each); counted vmcnt so
// each wait retires exactly the half the next phase reads. Last tile peeled:
// drain 4 -> 2 -> 0 (a uniform vmcnt(4) would retire nothing there -> race).
// Requires nk >= 1; K multiple of 64.
// ---------------------------------------------------------------------------
__global__ __launch_bounds__(512, 2) void gemm256_k(
    const short* __restrict__ A, const short* __restrict__ B,
    float* __restrict__ C, int K, int lda, int ldb, int ldc, int gx)
{
    extern __shared__ short smem[];

    // bijective XCD swizzle (gridDim.x % 8 == 0)
    const int nwg = gridDim.x;
    int wg = blockIdx.x;
    int sw = (wg & 7) * (nwg >> 3) + (wg >> 3);
    const int bx = sw % gx, by = sw / gx;
    const int bn0 = bx * 256, bm0 = by * 256;

    const int tid  = threadIdx.x;
    const int w    = tid >> 6, lane = tid & 63;
    const int wm   = w >> 2, wn = w & 3;
    const int lr   = lane & 15, kg = lane >> 4;

    // staging geometry: 2 issues per thread per half-tile (128 rows x 8 chunks)
    const int r0  = tid >> 3;            // rows 0..63
    const int pc  = tid & 7;
    const int lc0 = pc ^ (r0 & 7);
    const int r1  = r0 + 64;
    const int lc1 = pc ^ (r1 & 7);

    f32x4 acc[2][2][4][2] = {};
    const int nk = K >> 6;

    auto stage = [&](int buf, int isA, int h, int kk) {
        const short* gp = isA ? A : B;
        const int    ld = isA ? lda : ldb;
        const long long rb = (long long)((isA ? bm0 : bn0) + h * 128);
        short* lp = smem + buf * 32768 + (isA ? 0 : 16384) + h * 8192;
        llds16(gp + (rb + r0) * ld + kk + lc0 * 8, lp + w * 512);
        llds16(gp + (rb + r1) * ld + kk + lc1 * 8, lp + 4096 + w * 512);
    };

#define PHASE(BUF, QM, QN, ISA, H, DOWAIT)                                      \
    do {                                                                        \
        const short* Ah = smem + (BUF) * 32768 + (QM) * 8192;                   \
        const short* Bh = smem + (BUF) * 32768 + 16384 + (QN) * 8192;           \
        bf16x8 af[2][4], bfr[2][2];                                             \
        _Pragma("unroll")                                                       \
        for (int s2 = 0; s2 < 2; ++s2) {                                        \
            _Pragma("unroll")                                                   \
            for (int i = 0; i < 4; ++i) {                                       \
                const int ra = wm * 64 + i * 16 + lr;                           \
                af[s2][i] = *(const bf16x8*)                                    \
                    &Ah[ra * 64 + (((s2 * 4 + kg) ^ (ra & 7)) << 3)];           \
            }                                                                   \
            _Pragma("unroll")                                                   \
            for (int j = 0; j < 2; ++j) {                                       \
                const int rb2 = wn * 32 + j * 16 + lr;                          \
                bfr[s2][j] = *(const bf16x8*)                                   \
                    &Bh[rb2 * 64 + (((s2 * 4 + kg) ^ (rb2 & 7)) << 3)];         \
            }                                                                   \
        }                                                                       \
        if (pf) stage(nb, ISA, H, kk);                                          \
        BAR();                                                                  \
        __builtin_amdgcn_s_setprio(1);                                          \
        _Pragma("unroll")                                                       \
        for (int s2 = 0; s2 < 2; ++s2)                                          \
            _Pragma("unroll")                                                   \
            for (int i = 0; i < 4; ++i)                                         \
                _Pragma("unroll")                                               \
                for (int j = 0; j < 2; ++j)                                     \
                    acc[QM][QN][i][j] = __builtin_amdgcn_mfma_f32_16x16x32_bf16(\
                        af[s2][i], bfr[s2][j], acc[QM][QN][i][j], 0, 0, 0);     \
        __builtin_amdgcn_s_setprio(0);                                          \
        DOWAIT;                                                                 \
        BAR();                                                                  \
    } while (0)

    // prologue: tile 0, halves in consumption order A0,B0,A1,B1
    stage(0, 1, 0, 0);
    stage(0, 0, 0, 0);
    stage(0, 1, 1, 0);
    stage(0, 0, 1, 0);
    if (nk > 1) { VMW4(); } else { VMW0(); }
    BAR();

    for (int t = 0; t < nk - 1; ++t) {
        const int  buf = t & 1, nb = buf ^ 1;
        const int  kk  = (t + 1) << 6;
        const bool pf  = true;
        PHASE(buf, 0, 0, 1, 0, VMW4());   // compute (A0,B0), prefetch A0'
        PHASE(buf, 1, 0, 0, 0, VMW4());   // compute (A1,B0), prefetch B0'
        PHASE(buf, 1, 1, 1, 1, (void)0);  // compute (A1,B1), prefetch A1'
        PHASE(buf, 0, 1, 0, 1, VMW4());   // compute (A0,B1), prefetch B1'
    }
    {   // peeled last tile: no prefetch; drain 4 -> 2 -> 0
        const int  buf = (nk - 1) & 1, nb = buf ^ 1; (void)nb;
        const int  kk  = 0;
        const bool pf  = false;
        PHASE(buf, 0, 0, 1, 0, VMW2());   // retire A1
        PHASE(buf, 1, 0, 0, 0, VMW0());   // retire B1
        PHASE(buf, 1, 1, 1, 1, (void)0);
        PHASE(buf, 0, 1, 0, 1, (void)0);
    }
#undef PHASE

    // epilogue: C/D elem p -> row kg*4+p, col lr
    #pragma unroll
    for (int qm = 0; qm < 2; ++qm)
        #pragma unroll
        for (int qn = 0; qn < 2; ++qn)
            #pragma unroll
            for (int i = 0; i < 4; ++i)
                #pragma unroll
                for (int j = 0; j < 2; ++j) {
                    const int gr = bm0 + qm * 128 + wm * 64 + i * 16 + kg * 4;
                    const int gc = bn0 + qn * 128 + wn * 32 + j * 16 + lr;
                    #pragma unroll
                    for (int p = 0; p < 4; ++p)
                        C[(long long)(gr + p) * ldc + gc] = acc[qm][qn][i][j][p];
                }
}

// ---------------------------------------------------------------------------
// 128x(BN) 2-phase GEMM. A bf16 [M][K], B bf16 [N][K].
// EPI: 0=f32, 1=bf16*scale (causal mask to 0 above diagonal if CAUSAL==1),
//      2=f32+bias+resid, 3=bf16 gelu(acc+bias).
// CAUSAL: 0 none, 1 skip blocks above diagonal, 2 clip K to bm0+128.
// ---------------------------------------------------------------------------
template<int BN, int EPI, int CAUSAL>
__global__ __launch_bounds__(256) void gemm_k(
    const short* __restrict__ Ag, const short* __restrict__ Bg,
    void* __restrict__ Cg, const float* __restrict__ bias,
    const float* __restrict__ resid,
    int M, int N, int K, int lda, int ldb, int ldc, int Hdiv,
    long long sAb, long long sAh, long long sBb, long long sBh,
    long long sCb, long long sCh, float scale, int swz)
{
    int bx = blockIdx.x, by = blockIdx.y;
    if (swz) {
        const int gx = gridDim.x;
        const int nwg = gx * gridDim.y;
        if ((nwg & 7) == 0) {
            int wg = by * gx + bx;
            int wg2 = (wg & 7) * (nwg >> 3) + (wg >> 3);
            bx = wg2 % gx; by = wg2 / gx;
        }
    }
    const int bn0 = bx * BN, bm0 = by * 128;
    if (CAUSAL == 1 && bn0 > bm0 + 127) return;

    const int z  = blockIdx.z;
    const int zb = z / Hdiv, zh = z - zb * Hdiv;
    const short* A = Ag + zb * sAb + zh * sAh;
    const short* B = Bg + zb * sBb + zh * sBh;

    __shared__ short Als[128 * 64];
    __shared__ short Bls[BN * 64];

    const int tid  = threadIdx.x;
    const int lane = tid & 63;
    const int wave = tid >> 6;
    constexpr int WMS = (BN == 128) ? 64 : 32;
    constexpr int MI  = (BN == 128) ? 4 : 2;
    constexpr int NJ  = 4;
    const int wm = (BN == 128) ? (wave >> 1) : wave;
    const int wn = (BN == 128) ? (wave & 1) : 0;
    const int lr = lane & 15, kg = lane >> 4;
    const int xv = (lr & 7) << 4;

    const int sr = tid >> 3;
    const int sc = (tid & 7) ^ (sr & 7);
    const short* aP = A + (long long)(bm0 + sr) * lda + sc * 8;
    const short* bP = B + (long long)(bn0 + sr) * ldb + sc * 8;
    short* aL = &Als[wave * 512];
    short* bL = &Bls[wave * 512];

    f32x4 acc[MI][NJ] = {};

    int Keff = K;
    if (CAUSAL == 2) { int kl = bm0 + 128; Keff = (kl < K) ? kl : K; }
    const int nk = Keff >> 6;

    for (int kt = 0; kt < nk; ++kt) {
        const int k0 = kt << 6;
        #pragma unroll
        for (int it = 0; it < 4; ++it)
            llds16(aP + (long long)it * 32 * lda + k0, aL + it * 2048);
        #pragma unroll
        for (int it = 0; it < BN / 32; ++it)
            llds16(bP + (long long)it * 32 * ldb + k0, bL + it * 2048);
        __syncthreads();

        #pragma unroll
        for (int s = 0; s < 2; ++s) {
            const int ofs = (((s << 6) | (kg << 4)) ^ xv) >> 1;
            bf16x8 af[MI], bf[NJ];
            #pragma unroll
            for (int i = 0; i < MI; ++i)
                af[i] = *(const bf16x8*)&Als[(wm * WMS + i * 16 + lr) * 64 + ofs];
            #pragma unroll
            for (int j = 0; j < NJ; ++j)
                bf[j] = *(const bf16x8*)&Bls[(wn * 64 + j * 16 + lr) * 64 + ofs];
            #pragma unroll
            for (int i = 0; i < MI; ++i)
                #pragma unroll
                for (int j = 0; j < NJ; ++j)
                    acc[i][j] = __builtin_amdgcn_mfma_f32_16x16x32_bf16(
                        af[i], bf[j], acc[i][j], 0, 0, 0);
        }
        __syncthreads();
    }

    short* Cs = (short*)Cg + zb * sCb + zh * sCh;
    float* Cf = (float*)Cg + zb * sCb + zh * sCh;
    #pragma unroll
    for (int i = 0; i < MI; ++i) {
        #pragma unroll
        for (int j = 0; j < NJ; ++j) {
            const int gr = bm0 + wm * WMS + i * 16 + kg * 4;
            const int gc = bn0 + wn * 64 + j * 16 + lr;
            #pragma unroll
            for (int p = 0; p < 4; ++p) {
                const long long off = (long long)(gr + p) * ldc + gc;
                float v = acc[i][j][p];
                if (EPI == 0) {
                    Cf[off] = v;
                } else if (EPI == 1) {
                    float vv = v * scale;
                    if (CAUSAL == 1 && gc > gr + p) vv = 0.0f;
                    Cs[off] = f2bf(vv);
                } else if (EPI == 2) {
                    Cf[off] = v + bias[gc] + resid[off];
                } else {
                    v += bias[gc];
                    v = 0.5f * v * (1.0f + erff(v * 0.70710678118654752f));
                    Cs[off] = f2bf(v);
                }
            }
        }
    }
}

// ---------------------------------------------------------------------------
__global__ __launch_bounds__(256) void embed_k(
    const int* __restrict__ ids, const float* __restrict__ tok,
    const float* __restrict__ pos, float* __restrict__ x)
{
    const int gid = blockIdx.x * 256 + threadIdx.x;
    const int row = gid >> 8;
    const int c   = (gid & 255) << 2;
    const int t   = row & (TSEQ - 1);
    const int id  = ids[row];
    const float4 a = *(const float4*)&tok[(long long)id * DMODEL + c];
    const float4 p = *(const float4*)&pos[(long long)t * DMODEL + c];
    float4 o; o.x = a.x + p.x; o.y = a.y + p.y; o.z = a.z + p.z; o.w = a.w + p.w;
    *(float4*)&x[(long long)row * DMODEL + c] = o;
}

__global__ __launch_bounds__(256) void ln_k(
    const float* __restrict__ x, const float* __restrict__ w,
    const float* __restrict__ b, short* __restrict__ o)
{
    const int row = blockIdx.x;
    const float* xp = x + (long long)row * DMODEL;
    const int i = threadIdx.x * 4;
    float4 v = *(const float4*)&xp[i];
    float s  = v.x + v.y + v.z + v.w;
    float s2 = v.x * v.x + v.y * v.y + v.z * v.z + v.w * v.w;
    s  = block_sum(s);
    s2 = block_sum(s2);
    const float mean = s * (1.0f / DMODEL);
    const float var  = s2 * (1.0f / DMODEL) - mean * mean;
    const float rs   = rsqrtf(var + 1e-5f);
    float4 wv = *(const float4*)&w[i];
    float4 bv = *(const float4*)&b[i];
    s16x4 ov;
    ov[0] = f2bf((v.x - mean) * rs * wv.x + bv.x);
    ov[1] = f2bf((v.y - mean) * rs * wv.y + bv.y);
    ov[2] = f2bf((v.z - mean) * rs * wv.z + bv.z);
    ov[3] = f2bf((v.w - mean) * rs * wv.w + bv.w);
    *(s16x4*)&o[(long long)row * DMODEL + i] = ov;
}

// wave-per-row in-place causal softmax; lanes fully above the diagonal skip
// load/store (those S entries are 0 from the scores-GEMM in-block mask, and
// fully-masked blocks are never read downstream).
__global__ __launch_bounds__(256) void softmax_k(short* __restrict__ S)
{
    const int row  = blockIdx.x * 4 + (threadIdx.x >> 6);
    const int q    = row & (TSEQ - 1);
    const int lane = threadIdx.x & 63;
    const int c0   = lane * 16;
    short* sp = S + (long long)row * TSEQ + c0;
    const bool act = (c0 <= q);
    float f[16];
    float m = -1e30f;
    if (act) {
        s16x8 rA = *(const s16x8*)sp;
        s16x8 rB = *(const s16x8*)(sp + 8);
        #pragma unroll
        for (int i = 0; i < 16; ++i) {
            const short raw = (i < 8) ? rA[i] : rB[i - 8];
            f[i] = (c0 + i <= q) ? bf2f(raw) : -1e30f;
            m = fmaxf(m, f[i]);
        }
    } else {
        #pragma unroll
        for (int i = 0; i < 16; ++i) f[i] = -1e30f;
    }
    #pragma unroll
    for (int o = 1; o < 64; o <<= 1) m = fmaxf(m, __shfl_xor(m, o, 64));
    float sum = 0.f;
    if (act) {
        #pragma unroll
        for (int i = 0; i < 16; ++i) { f[i] = __expf(f[i] - m); sum += f[i]; }
    }
    #pragma unroll
    for (int o = 1; o < 64; o <<= 1) sum += __shfl_xor(sum, o, 64);
    if (act) {
        const float inv = 1.0f / sum;
        s16x8 w0, w1;
        #pragma unroll
        for (int i = 0; i < 8; ++i) {
            w0[i] = f2bf(f[i] * inv); w1[i] = f2bf(f[i + 8] * inv);
        }
        *(s16x8*)sp = w0;
        *(s16x8*)(sp + 8) = w1;
    }
}

// transpose-convert: src [R][C] (T = float|short) -> dst bf16 [C][R], 64x64 tiles
template<typename T>
__global__ __launch_bounds__(256) void tcvt_k(
    const T* __restrict__ src, short* __restrict__ dst,
    int lds_, int ldd, int Hdiv,
    long long sSb, long long sSh, long long sDb, long long sDh)
{
    __shared__ short ls[64][68];
    const int z = blockIdx.z, zb = z / Hdiv, zh = z - zb * Hdiv;
    const T* sp = src + zb * sSb + zh * sSh;
    short* dp = dst + zb * sDb + zh * sDh;
    const int tr0 = blockIdx.y * 64, tc0 = blockIdx.x * 64;
    const int t = threadIdx.x;
    const int rr = t >> 4, cc = (t & 15) * 4;
    #pragma unroll
    for (int q = 0; q < 4; ++q) {
        const int r = q * 16 + rr;
        if constexpr (sizeof(T) == 4) {
            float4 v = *(const float4*)&sp[(long long)(tr0 + r) * lds_ + tc0 + cc];
            ls[cc + 0][r] = f2bf(v.x); ls[cc + 1][r] = f2bf(v.y);
            ls[cc + 2][r] = f2bf(v.z); ls[cc + 3][r] = f2bf(v.w);
        } else {
            s16x4 v = *(const s16x4*)&sp[(long long)(tr0 + r) * lds_ + tc0 + cc];
            ls[cc + 0][r] = v[0]; ls[cc + 1][r] = v[1];
            ls[cc + 2][r] = v[2]; ls[cc + 3][r] = v[3];
        }
    }
    __syncthreads();
    #pragma unroll
    for (int q = 0; q < 4; ++q) {
        const int c = q * 16 + rr;
        s16x4 v;
        v[0] = ls[c][cc]; v[1] = ls[c][cc + 1]; v[2] = ls[c][cc + 2]; v[3] = ls[c][cc + 3];
        *(s16x4*)&dp[(long long)(tc0 + c) * ldd + tr0 + cc] = v;
    }
}

// plain fp32 -> bf16 convert (n4 = count/4)
__global__ __launch_bounds__(256) void cvt_k(
    const float* __restrict__ s, short* __restrict__ d, int n4)
{
    int i = blockIdx.x * 256 + threadIdx.x;
    const int stride = gridDim.x * 256;
    for (; i < n4; i += stride) {
        float4 v = *(const float4*)&s[(long long)i * 4];
        s16x4 o = { f2bf(v.x), f2bf(v.y), f2bf(v.z), f2bf(v.w) };
        *(s16x4*)&d[(long long)i * 4] = o;
    }
}

// ---------------------------------------------------------------------------
extern "C" void kernel_launch(void* const* d_in, const int* in_sizes, int n_in,
                              void* d_out, int out_size, void* d_ws, size_t ws_size,
                              hipStream_t stream)
{
    const int*   ids  = (const int*)  d_in[0];
    const float* tok  = (const float*)d_in[1];
    const float* pos  = (const float*)d_in[2];
    const float* ln1w = (const float*)d_in[3];
    const float* ln1b = (const float*)d_in[4];
    const float* qkvw = (const float*)d_in[5];
    const float* outw = (const float*)d_in[6];
    const float* outb = (const float*)d_in[7];
    const float* ln2w = (const float*)d_in[8];
    const float* ln2b = (const float*)d_in[9];
    const float* fc1w = (const float*)d_in[10];
    const float* fc1b = (const float*)d_in[11];
    const float* fc2w = (const float*)d_in[12];
    const float* fc2b = (const float*)d_in[13];
    const float* lnfw = (const float*)d_in[14];
    const float* lnfb = (const float*)d_in[15];
    float* out = (float*)d_out;

    char* ws = (char*)d_ws;
    const size_t MB = 1024 * 1024;
    float* x    = (float*)(ws);             //  8 MB f32 residual
    short* hb   = (short*)(ws + 8 * MB);    //  4 MB bf16 [2048][1024]
    short* qkvb = (short*)(ws + 12 * MB);   // 12 MB bf16 [2048][3072]
    short* S    = (short*)(ws + 24 * MB);   // 64 MB bf16 [32][1024][1024]
    short* g    = (short*)(ws + 24 * MB);   // 16 MB bf16 (aliases S)
    short* Vt   = (short*)(ws + 88 * MB);   //  4 MB bf16 [32][64][1024]

    const bool big = ws_size >= (size_t)352 * MB;
    short *wq, *wo, *w1, *w2, *tokb;
    if (big) {
        wq   = (short*)(ws + 92  * MB);
        wo   = (short*)(ws + 140 * MB);
        w1   = (short*)(ws + 156 * MB);
        w2   = (short*)(ws + 220 * MB);
        tokb = (short*)(ws + 284 * MB);
    } else {
        wq   = (short*)(ws + 92  * MB);
        wo   = (short*)(ws + 98  * MB);
        w1   = (short*)(ws + 100 * MB);
        w2   = (short*)(ws + 108 * MB);
        tokb = (short*)(ws + 24  * MB);     // aliases S (dead by lm_head)
    }

    const long long LWQ = 3072LL * 1024, LWO = 1024LL * 1024;
    const long long LW1 = 4096LL * 1024, LW2 = 1024LL * 4096;

    hipFuncSetAttribute((const void*)gemm256_k,
                        hipFuncAttributeMaxDynamicSharedMemorySize, 131072);

    dim3 blk(256);
    embed_k<<<MTOK, blk, 0, stream>>>(ids, tok, pos, x);

    if (big) {
        tcvt_k<float><<<dim3(48, 16, 8), blk, 0, stream>>>(qkvw, wq, 3072, 1024, 1, LWQ, 0, LWQ, 0);
        tcvt_k<float><<<dim3(16, 16, 8), blk, 0, stream>>>(outw, wo, 1024, 1024, 1, LWO, 0, LWO, 0);
        tcvt_k<float><<<dim3(64, 16, 8), blk, 0, stream>>>(fc1w, w1, 4096, 1024, 1, LW1, 0, LW1, 0);
        tcvt_k<float><<<dim3(16, 64, 8), blk, 0, stream>>>(fc2w, w2, 1024, 4096, 1, LW2, 0, LW2, 0);
        cvt_k<<<2048, blk, 0, stream>>>(tok, tokb, NVOCAB * DMODEL / 4);
    }

    for (int l = 0; l < NLAYER; ++l) {
        short* wql = wq + (big ? l * LWQ : 0);
        short* wol = wo + (big ? l * LWO : 0);
        short* w1l = w1 + (big ? l * LW1 : 0);
        short* w2l = w2 + (big ? l * LW2 : 0);
        if (!big) {
            tcvt_k<float><<<dim3(48, 16, 1), blk, 0, stream>>>(qkvw + l * LWQ, wql, 3072, 1024, 1, 0, 0, 0, 0);
            tcvt_k<float><<<dim3(16, 16, 1), blk, 0, stream>>>(outw + l * LWO, wol, 1024, 1024, 1, 0, 0, 0, 0);
            tcvt_k<float><<<dim3(64, 16, 1), blk, 0, stream>>>(fc1w + l * LW1, w1l, 4096, 1024, 1, 0, 0, 0, 0);
            tcvt_k<float><<<dim3(16, 64, 1), blk, 0, stream>>>(fc2w + l * LW2, w2l, 1024, 4096, 1, 0, 0, 0, 0);
        }

        ln_k<<<MTOK, blk, 0, stream>>>(x, ln1w + l * DMODEL, ln1b + l * DMODEL, hb);

        // qkv = ln1 @ Wqkv -> bf16
        gemm_k<128, 1, 0><<<dim3(24, 16, 1), blk, 0, stream>>>(
            hb, wql, qkvb, nullptr, nullptr,
            MTOK, 3 * DMODEL, DMODEL, DMODEL, DMODEL, 3 * DMODEL, 1,
            0, 0, 0, 0, 0, 0, 1.0f, 1);

        // S[z] = 0.125 * Q K^T (bf16, causal block skip + in-block mask to 0)
        gemm_k<128, 1, 1><<<dim3(8, 8, BBATCH * NHEAD), blk, 0, stream>>>(
            qkvb, qkvb + DMODEL, S, nullptr, nullptr,
            TSEQ, TSEQ, HDIM, 3 * DMODEL, 3 * DMODEL, TSEQ, NHEAD,
            (long long)TSEQ * 3 * DMODEL, HDIM,
            (long long)TSEQ * 3 * DMODEL, HDIM,
            (long long)NHEAD * TSEQ * TSEQ, (long long)TSEQ * TSEQ, 0.125f, 0);

        softmax_k<<<BBATCH * NHEAD * TSEQ / 4, blk, 0, stream>>>(S);

        // Vt[z] = V^T
        tcvt_k<short><<<dim3(1, 16, BBATCH * NHEAD), blk, 0, stream>>>(
            qkvb + 2 * DMODEL, Vt, 3 * DMODEL, TSEQ, NHEAD,
            (long long)TSEQ * 3 * DMODEL, HDIM,
            (long long)NHEAD * HDIM * TSEQ, (long long)HDIM * TSEQ);

        // attn = P V -> hb (bf16), K clipped at diagonal
        gemm_k<64, 1, 2><<<dim3(1, 8, BBATCH * NHEAD), blk, 0, stream>>>(
            S, Vt, hb, nullptr, nullptr,
            TSEQ, HDIM, TSEQ, TSEQ, TSEQ, DMODEL, NHEAD,
            (long long)NHEAD * TSEQ * TSEQ, (long long)TSEQ * TSEQ,
            (long long)NHEAD * HDIM * TSEQ, (long long)HDIM * TSEQ,
            (long long)TSEQ * DMODEL, HDIM, 1.0f, 0);

        // x += attn @ Wout + b   (BN=64: 256 blocks)
        gemm_k<64, 2, 0><<<dim3(16, 16, 1), blk, 0, stream>>>(
            hb, wol, x, outb + l * DMODEL, x,
            MTOK, DMODEL, DMODEL, DMODEL, DMODEL, DMODEL, 1,
            0, 0, 0, 0, 0, 0, 1.0f, 1);

        ln_k<<<MTOK, blk, 0, stream>>>(x, ln2w + l * DMODEL, ln2b + l * DMODEL, hb);

        // g = gelu(ln2 @ Wfc1 + b) -> bf16
        gemm_k<128, 3, 0><<<dim3(32, 16, 1), blk, 0, stream>>>(
            hb, w1l, g, fc1b + (long long)l * 4 * DMODEL, nullptr,
            MTOK, 4 * DMODEL, DMODEL, DMODEL, DMODEL, 4 * DMODEL, 1,
            0, 0, 0, 0, 0, 0, 1.0f, 1);

        // x += g @ Wfc2 + b   (BN=64: 256 blocks)
        gemm_k<64, 2, 0><<<dim3(16, 16, 1), blk, 0, stream>>>(
            g, w2l, x, fc2b + l * DMODEL, x,
            MTOK, DMODEL, 4 * DMODEL, 4 * DMODEL, 4 * DMODEL, DMODEL, 1,
            0, 0, 0, 0, 0, 0, 1.0f, 1);
    }

    ln_k<<<MTOK, blk, 0, stream>>>(x, lnfw, lnfb, hb);

    if (!big)
        cvt_k<<<2048, blk, 0, stream>>>(tok, tokb, NVOCAB * DMODEL / 4);

    // logits = lnf @ tok_emb^T via 256x256 8-phase kernel
    gemm256_k<<<dim3((NVOCAB / 256) * (MTOK / 256)), dim3(512), 131072, stream>>>(
        hb, tokb, out, DMODEL, DMODEL, DMODEL, NVOCAB, NVOCAB / 256);
}

// Round 5
// 1993.560 us; speedup vs baseline: 2.2311x; 1.0396x over previous
//
#include <hip/hip_runtime.h>
#include <hip/hip_bf16.h>
#include <math.h>

// ---------------------------------------------------------------------------
// GPT forward, round 5: flash attention (fused scores+softmax+PV), lm_head
// column-major-within-XCD swizzle for B-panel L2 reuse.
// ---------------------------------------------------------------------------

#define DEV_INLINE __device__ __forceinline__

typedef float  f32x4  __attribute__((ext_vector_type(4)));
typedef __bf16 bf16x8 __attribute__((ext_vector_type(8)));
typedef short  s16x4  __attribute__((ext_vector_type(4)));
typedef short  s16x8  __attribute__((ext_vector_type(8)));

#define BBATCH 2
#define TSEQ   1024
#define DMODEL 1024
#define NHEAD  16
#define HDIM   64
#define NLAYER 8
#define NVOCAB 32000
#define MTOK   (BBATCH*TSEQ)   // 2048

DEV_INLINE short f2bf(float f) {
    __bf16 h = (__bf16)f;
    union { __bf16 h; short s; } u; u.h = h; return u.s;
}
DEV_INLINE float bf2f(short s) {
    union { unsigned u; float f; } x; x.u = ((unsigned)(unsigned short)s) << 16;
    return x.f;
}

typedef const __attribute__((address_space(1))) unsigned int* gas_t;
typedef __attribute__((address_space(3))) unsigned int* las_t;
DEV_INLINE void llds16(const void* g, void* l) {
    __builtin_amdgcn_global_load_lds((gas_t)g, (las_t)l, 16, 0, 0);
}

#define BAR()  asm volatile("s_barrier" ::: "memory")
#define VMW4() asm volatile("s_waitcnt vmcnt(4)" ::: "memory")
#define VMW2() asm volatile("s_waitcnt vmcnt(2)" ::: "memory")
#define VMW0() asm volatile("s_waitcnt vmcnt(0)" ::: "memory")

DEV_INLINE float block_sum(float v) {
    __shared__ float sb[4];
    #pragma unroll
    for (int o = 32; o > 0; o >>= 1) v += __shfl_down(v, o, 64);
    if ((threadIdx.x & 63) == 0) sb[threadIdx.x >> 6] = v;
    __syncthreads();
    float r = sb[0] + sb[1] + sb[2] + sb[3];
    __syncthreads();
    return r;
}

// ---------------------------------------------------------------------------
// Flash attention: grid (8 q-blocks, 32 bh), 256 threads (4 waves x 32 rows).
// Q,K from qkvb [2048][3072] bf16; V^T from Vt [32][64][1024] bf16.
// KV tiles of 128, online softmax in f32 registers, P via LDS (overlays the
// dead K tile). A/B fragments use the same k-permutation (chunk XOR + kg*8+e
// consecutive layout) on both operands, which cancels inside MFMA.
// ---------------------------------------------------------------------------
__global__ __launch_bounds__(256) void flash_k(
    const short* __restrict__ qkv, const short* __restrict__ Vt,
    short* __restrict__ O)
{
    const int qb = blockIdx.x;          // 0..7
    const int z  = blockIdx.y;          // 0..31
    const int zb = z >> 4, zh = z & 15;

    __shared__ short Qs[128 * 64];      // 16 KB
    __shared__ short KP[128 * 136];     // 34 KB: K tile [128][64], then P [128][136]
    __shared__ short Vs[64 * 128];      // 16 KB: V^T tile [64][128]

    const int tid  = threadIdx.x;
    const int w    = tid >> 6, lane = tid & 63;
    const int lr   = lane & 15, kg = lane >> 4;

    const long long qbase = (long long)zb * TSEQ * 3072;
    const short* Qg = qkv + qbase + zh * HDIM;
    const short* Kg = qkv + qbase + DMODEL + zh * HDIM;
    const short* Vg = Vt + (long long)z * (HDIM * TSEQ);

    // ---- stage Q tile (128x64) once
    {
        const int sr = tid >> 3, pc = tid & 7;
        const int lc = pc ^ (sr & 7);
        const short* qp = Qg + (long long)(qb * 128 + sr) * 3072 + lc * 8;
        short* dst = Qs + tid * 8;
        #pragma unroll
        for (int it = 0; it < 4; ++it)
            llds16(qp + (long long)it * 32 * 3072, dst + it * 2048);
    }
    __syncthreads();
    bf16x8 afq[2][2];
    #pragma unroll
    for (int s = 0; s < 2; ++s)
        #pragma unroll
        for (int i = 0; i < 2; ++i) {
            const int r = w * 32 + i * 16 + lr;
            afq[s][i] = *(const bf16x8*)&Qs[r * 64 + (((s * 4 + kg) ^ (r & 7)) << 3)];
        }

    f32x4 aco[2][4] = {};
    float m_[2][4], l_[2][4];
    #pragma unroll
    for (int i = 0; i < 2; ++i)
        #pragma unroll
        for (int p = 0; p < 4; ++p) { m_[i][p] = -1e30f; l_[i][p] = 0.f; }

    const int nt = qb + 1;
    for (int t = 0; t < nt; ++t) {
        const int kv0 = t * 128;
        // ---- stage K (128x64) and V^T (64x128)
        {
            const int sr = tid >> 3, pc = tid & 7;
            const int lc = pc ^ (sr & 7);
            const short* kp = Kg + (long long)(kv0 + sr) * 3072 + lc * 8;
            short* kdst = KP + tid * 8;
            #pragma unroll
            for (int it = 0; it < 4; ++it)
                llds16(kp + (long long)it * 32 * 3072, kdst + it * 2048);
            const int sr16 = tid >> 4, pc16 = tid & 15;
            short* vdst = Vs + tid * 8;
            #pragma unroll
            for (int it = 0; it < 4; ++it) {
                const int r = it * 16 + sr16;
                const int lc2 = pc16 ^ (r & 7);
                llds16(Vg + (long long)r * TSEQ + kv0 + lc2 * 8, vdst + it * 2048);
            }
        }
        __syncthreads();

        // ---- S = Q K^T  (f32 frags)
        f32x4 acs[2][8] = {};
        #pragma unroll
        for (int s = 0; s < 2; ++s)
            #pragma unroll
            for (int j = 0; j < 8; ++j) {
                const int rk = j * 16 + lr;
                bf16x8 bk = *(const bf16x8*)&KP[rk * 64 + (((s * 4 + kg) ^ (rk & 7)) << 3)];
                #pragma unroll
                for (int i = 0; i < 2; ++i)
                    acs[i][j] = __builtin_amdgcn_mfma_f32_16x16x32_bf16(
                        afq[s][i], bk, acs[i][j], 0, 0, 0);
            }

        // causal mask (diagonal tile only), scale by 1/8
        #pragma unroll
        for (int i = 0; i < 2; ++i)
            #pragma unroll
            for (int j = 0; j < 8; ++j)
                #pragma unroll
                for (int p = 0; p < 4; ++p) {
                    float v = acs[i][j][p] * 0.125f;
                    if (t == qb && (j * 16 + lr) > (w * 32 + i * 16 + kg * 4 + p))
                        v = -1e30f;
                    acs[i][j][p] = v;
                }

        // ---- online softmax (registers)
        float sc[2][4];
        #pragma unroll
        for (int i = 0; i < 2; ++i)
            #pragma unroll
            for (int p = 0; p < 4; ++p) {
                float r = acs[i][0][p];
                #pragma unroll
                for (int j = 1; j < 8; ++j) r = fmaxf(r, acs[i][j][p]);
                r = fmaxf(r, __shfl_xor(r, 1, 64));
                r = fmaxf(r, __shfl_xor(r, 2, 64));
                r = fmaxf(r, __shfl_xor(r, 4, 64));
                r = fmaxf(r, __shfl_xor(r, 8, 64));
                const float mn = fmaxf(m_[i][p], r);
                sc[i][p] = __expf(m_[i][p] - mn);
                m_[i][p] = mn;
            }
        #pragma unroll
        for (int i = 0; i < 2; ++i)
            #pragma unroll
            for (int j = 0; j < 8; ++j)
                #pragma unroll
                for (int p = 0; p < 4; ++p)
                    acs[i][j][p] = __expf(acs[i][j][p] - m_[i][p]);
        #pragma unroll
        for (int i = 0; i < 2; ++i)
            #pragma unroll
            for (int p = 0; p < 4; ++p) {
                float s = 0.f;
                #pragma unroll
                for (int j = 0; j < 8; ++j) s += acs[i][j][p];
                s += __shfl_xor(s, 1, 64);
                s += __shfl_xor(s, 2, 64);
                s += __shfl_xor(s, 4, 64);
                s += __shfl_xor(s, 8, 64);
                l_[i][p] = l_[i][p] * sc[i][p] + s;
            }
        #pragma unroll
        for (int i = 0; i < 2; ++i)
            #pragma unroll
            for (int j2 = 0; j2 < 4; ++j2)
                #pragma unroll
                for (int p = 0; p < 4; ++p)
                    aco[i][j2][p] *= sc[i][p];

        __syncthreads();   // all waves done reading K before P overwrites it

        // ---- write P (bf16) into KP as [q][136]
        #pragma unroll
        for (int i = 0; i < 2; ++i)
            #pragma unroll
            for (int j = 0; j < 8; ++j)
                #pragma unroll
                for (int p = 0; p < 4; ++p)
                    KP[(w * 32 + i * 16 + kg * 4 + p) * 136 + j * 16 + lr] =
                        f2bf(acs[i][j][p]);
        __syncthreads();

        // ---- O += P V   (A from P [q][136], B from Vs [d][128])
        #pragma unroll
        for (int ks = 0; ks < 4; ++ks) {
            bf16x8 pa[2], pb[4];
            #pragma unroll
            for (int i = 0; i < 2; ++i)
                pa[i] = *(const bf16x8*)&KP[(w * 32 + i * 16 + lr) * 136 + ks * 32 + kg * 8];
            #pragma unroll
            for (int j2 = 0; j2 < 4; ++j2) {
                const int d = j2 * 16 + lr;
                pb[j2] = *(const bf16x8*)&Vs[d * 128 + (((ks * 4 + kg) ^ (d & 7)) << 3)];
            }
            #pragma unroll
            for (int i = 0; i < 2; ++i)
                #pragma unroll
                for (int j2 = 0; j2 < 4; ++j2)
                    aco[i][j2] = __builtin_amdgcn_mfma_f32_16x16x32_bf16(
                        pa[i], pb[j2], aco[i][j2], 0, 0, 0);
        }
        __syncthreads();   // before next tile's staging overwrites KP/Vs
    }

    // ---- epilogue: O / l -> bf16
    #pragma unroll
    for (int i = 0; i < 2; ++i)
        #pragma unroll
        for (int j2 = 0; j2 < 4; ++j2)
            #pragma unroll
            for (int p = 0; p < 4; ++p) {
                const int row = zb * TSEQ + qb * 128 + w * 32 + i * 16 + kg * 4 + p;
                const int col = zh * HDIM + j2 * 16 + lr;
                O[(long long)row * DMODEL + col] = f2bf(aco[i][j2][p] / l_[i][p]);
            }
}

// ---------------------------------------------------------------------------
// 256x256x(BK=64) 8-wave 8-phase GEMM, f32 output (lm_head). Grid must be
// gx * 8 blocks (8 m-rows). Column-major within XCD chunk: the 8 blocks
// sharing a B panel run together on one XCD.
// ---------------------------------------------------------------------------
__global__ __launch_bounds__(512, 2) void gemm256_k(
    const short* __restrict__ A, const short* __restrict__ B,
    float* __restrict__ C, int K, int lda, int ldb, int ldc, int gx)
{
    extern __shared__ short smem[];

    const int nwg = gridDim.x;
    int wg = blockIdx.x;
    int sw = (wg & 7) * (nwg >> 3) + (wg >> 3);   // XCD-contiguous
    const int bx = sw >> 3, by = sw & 7;          // column-major within XCD
    const int bn0 = bx * 256, bm0 = by * 256;

    const int tid  = threadIdx.x;
    const int w    = tid >> 6, lane = tid & 63;
    const int wm   = w >> 2, wn = w & 3;
    const int lr   = lane & 15, kg = lane >> 4;

    const int r0  = tid >> 3;
    const int pc  = tid & 7;
    const int lc0 = pc ^ (r0 & 7);
    const int r1  = r0 + 64;
    const int lc1 = pc ^ (r1 & 7);

    f32x4 acc[2][2][4][2] = {};
    const int nk = K >> 6;

    auto stage = [&](int buf, int isA, int h, int kk) {
        const short* gp = isA ? A : B;
        const int    ld = isA ? lda : ldb;
        const long long rb = (long long)((isA ? bm0 : bn0) + h * 128);
        short* lp = smem + buf * 32768 + (isA ? 0 : 16384) + h * 8192;
        llds16(gp + (rb + r0) * ld + kk + lc0 * 8, lp + w * 512);
        llds16(gp + (rb + r1) * ld + kk + lc1 * 8, lp + 4096 + w * 512);
    };

#define PHASE(BUF, QM, QN, ISA, H, DOWAIT)                                      \
    do {                                                                        \
        const short* Ah = smem + (BUF) * 32768 + (QM) * 8192;                   \
        const short* Bh = smem + (BUF) * 32768 + 16384 + (QN) * 8192;           \
        bf16x8 af[2][4], bfr[2][2];                                             \
        _Pragma("unroll")                                                       \
        for (int s2 = 0; s2 < 2; ++s2) {                                        \
            _Pragma("unroll")                                                   \
            for (int i = 0; i < 4; ++i) {                                       \
                const int ra = wm * 64 + i * 16 + lr;                           \
                af[s2][i] = *(const bf16x8*)                                    \
                    &Ah[ra * 64 + (((s2 * 4 + kg) ^ (ra & 7)) << 3)];           \
            }                                                                   \
            _Pragma("unroll")                                                   \
            for (int j = 0; j < 2; ++j) {                                       \
                const int rb2 = wn * 32 + j * 16 + lr;                          \
                bfr[s2][j] = *(const bf16x8*)                                   \
                    &Bh[rb2 * 64 + (((s2 * 4 + kg) ^ (rb2 & 7)) << 3)];         \
            }                                                                   \
        }                                                                       \
        if (pf) stage(nb, ISA, H, kk);                                          \
        BAR();                                                                  \
        __builtin_amdgcn_s_setprio(1);                                          \
        _Pragma("unroll")                                                       \
        for (int s2 = 0; s2 < 2; ++s2)                                          \
            _Pragma("unroll")                                                   \
            for (int i = 0; i < 4; ++i)                                         \
                _Pragma("unroll")                                               \
                for (int j = 0; j < 2; ++j)                                     \
                    acc[QM][QN][i][j] = __builtin_amdgcn_mfma_f32_16x16x32_bf16(\
                        af[s2][i], bfr[s2][j], acc[QM][QN][i][j], 0, 0, 0);     \
        __builtin_amdgcn_s_setprio(0);                                          \
        DOWAIT;                                                                 \
        BAR();                                                                  \
    } while (0)

    stage(0, 1, 0, 0);
    stage(0, 0, 0, 0);
    stage(0, 1, 1, 0);
    stage(0, 0, 1, 0);
    if (nk > 1) { VMW4(); } else { VMW0(); }
    BAR();

    for (int t = 0; t < nk - 1; ++t) {
        const int  buf = t & 1, nb = buf ^ 1;
        const int  kk  = (t + 1) << 6;
        const bool pf  = true;
        PHASE(buf, 0, 0, 1, 0, VMW4());
        PHASE(buf, 1, 0, 0, 0, VMW4());
        PHASE(buf, 1, 1, 1, 1, (void)0);
        PHASE(buf, 0, 1, 0, 1, VMW4());
    }
    {   // peeled last tile: drain 4 -> 2 -> 0
        const int  buf = (nk - 1) & 1, nb = buf ^ 1; (void)nb;
        const int  kk  = 0;
        const bool pf  = false;
        PHASE(buf, 0, 0, 1, 0, VMW2());
        PHASE(buf, 1, 0, 0, 0, VMW0());
        PHASE(buf, 1, 1, 1, 1, (void)0);
        PHASE(buf, 0, 1, 0, 1, (void)0);
    }
#undef PHASE

    #pragma unroll
    for (int qm = 0; qm < 2; ++qm)
        #pragma unroll
        for (int qn = 0; qn < 2; ++qn)
            #pragma unroll
            for (int i = 0; i < 4; ++i)
                #pragma unroll
                for (int j = 0; j < 2; ++j) {
                    const int gr = bm0 + qm * 128 + wm * 64 + i * 16 + kg * 4;
                    const int gc = bn0 + qn * 128 + wn * 32 + j * 16 + lr;
                    #pragma unroll
                    for (int p = 0; p < 4; ++p)
                        C[(long long)(gr + p) * ldc + gc] = acc[qm][qn][i][j][p];
                }
}

// ---------------------------------------------------------------------------
// 128x(BN) 2-phase GEMM. A bf16 [M][K], B bf16 [N][K].
// EPI: 0=f32, 1=bf16*scale, 2=f32+bias+resid, 3=bf16 gelu(acc+bias).
// ---------------------------------------------------------------------------
template<int BN, int EPI>
__global__ __launch_bounds__(256) void gemm_k(
    const short* __restrict__ Ag, const short* __restrict__ Bg,
    void* __restrict__ Cg, const float* __restrict__ bias,
    const float* __restrict__ resid,
    int M, int N, int K, int lda, int ldb, int ldc,
    float scale, int swz)
{
    int bx = blockIdx.x, by = blockIdx.y;
    if (swz) {
        const int gx = gridDim.x;
        const int nwg = gx * gridDim.y;
        if ((nwg & 7) == 0) {
            int wg = by * gx + bx;
            int wg2 = (wg & 7) * (nwg >> 3) + (wg >> 3);
            bx = wg2 % gx; by = wg2 / gx;
        }
    }
    const int bn0 = bx * BN, bm0 = by * 128;

    const short* A = Ag;
    const short* B = Bg;

    __shared__ short Als[128 * 64];
    __shared__ short Bls[BN * 64];

    const int tid  = threadIdx.x;
    const int lane = tid & 63;
    const int wave = tid >> 6;
    constexpr int WMS = (BN == 128) ? 64 : 32;
    constexpr int MI  = (BN == 128) ? 4 : 2;
    constexpr int NJ  = 4;
    const int wm = (BN == 128) ? (wave >> 1) : wave;
    const int wn = (BN == 128) ? (wave & 1) : 0;
    const int lr = lane & 15, kg = lane >> 4;
    const int xv = (lr & 7) << 4;

    const int sr = tid >> 3;
    const int sc = (tid & 7) ^ (sr & 7);
    const short* aP = A + (long long)(bm0 + sr) * lda + sc * 8;
    const short* bP = B + (long long)(bn0 + sr) * ldb + sc * 8;
    short* aL = &Als[wave * 512];
    short* bL = &Bls[wave * 512];

    f32x4 acc[MI][NJ] = {};
    const int nk = K >> 6;

    for (int kt = 0; kt < nk; ++kt) {
        const int k0 = kt << 6;
        #pragma unroll
        for (int it = 0; it < 4; ++it)
            llds16(aP + (long long)it * 32 * lda + k0, aL + it * 2048);
        #pragma unroll
        for (int it = 0; it < BN / 32; ++it)
            llds16(bP + (long long)it * 32 * ldb + k0, bL + it * 2048);
        __syncthreads();

        #pragma unroll
        for (int s = 0; s < 2; ++s) {
            const int ofs = (((s << 6) | (kg << 4)) ^ xv) >> 1;
            bf16x8 af[MI], bf[NJ];
            #pragma unroll
            for (int i = 0; i < MI; ++i)
                af[i] = *(const bf16x8*)&Als[(wm * WMS + i * 16 + lr) * 64 + ofs];
            #pragma unroll
            for (int j = 0; j < NJ; ++j)
                bf[j] = *(const bf16x8*)&Bls[(wn * 64 + j * 16 + lr) * 64 + ofs];
            #pragma unroll
            for (int i = 0; i < MI; ++i)
                #pragma unroll
                for (int j = 0; j < NJ; ++j)
                    acc[i][j] = __builtin_amdgcn_mfma_f32_16x16x32_bf16(
                        af[i], bf[j], acc[i][j], 0, 0, 0);
        }
        __syncthreads();
    }

    short* Cs = (short*)Cg;
    float* Cf = (float*)Cg;
    #pragma unroll
    for (int i = 0; i < MI; ++i) {
        #pragma unroll
        for (int j = 0; j < NJ; ++j) {
            const int gr = bm0 + wm * WMS + i * 16 + kg * 4;
            const int gc = bn0 + wn * 64 + j * 16 + lr;
            #pragma unroll
            for (int p = 0; p < 4; ++p) {
                const long long off = (long long)(gr + p) * ldc + gc;
                float v = acc[i][j][p];
                if (EPI == 0) {
                    Cf[off] = v;
                } else if (EPI == 1) {
                    Cs[off] = f2bf(v * scale);
                } else if (EPI == 2) {
                    Cf[off] = v + bias[gc] + resid[off];
                } else {
                    v += bias[gc];
                    v = 0.5f * v * (1.0f + erff(v * 0.70710678118654752f));
                    Cs[off] = f2bf(v);
                }
            }
        }
    }
}

// ---------------------------------------------------------------------------
__global__ __launch_bounds__(256) void embed_k(
    const int* __restrict__ ids, const float* __restrict__ tok,
    const float* __restrict__ pos, float* __restrict__ x)
{
    const int gid = blockIdx.x * 256 + threadIdx.x;
    const int row = gid >> 8;
    const int c   = (gid & 255) << 2;
    const int t   = row & (TSEQ - 1);
    const int id  = ids[row];
    const float4 a = *(const float4*)&tok[(long long)id * DMODEL + c];
    const float4 p = *(const float4*)&pos[(long long)t * DMODEL + c];
    float4 o; o.x = a.x + p.x; o.y = a.y + p.y; o.z = a.z + p.z; o.w = a.w + p.w;
    *(float4*)&x[(long long)row * DMODEL + c] = o;
}

__global__ __launch_bounds__(256) void ln_k(
    const float* __restrict__ x, const float* __restrict__ w,
    const float* __restrict__ b, short* __restrict__ o)
{
    const int row = blockIdx.x;
    const float* xp = x + (long long)row * DMODEL;
    const int i = threadIdx.x * 4;
    float4 v = *(const float4*)&xp[i];
    float s  = v.x + v.y + v.z + v.w;
    float s2 = v.x * v.x + v.y * v.y + v.z * v.z + v.w * v.w;
    s  = block_sum(s);
    s2 = block_sum(s2);
    const float mean = s * (1.0f / DMODEL);
    const float var  = s2 * (1.0f / DMODEL) - mean * mean;
    const float rs   = rsqrtf(var + 1e-5f);
    float4 wv = *(const float4*)&w[i];
    float4 bv = *(const float4*)&b[i];
    s16x4 ov;
    ov[0] = f2bf((v.x - mean) * rs * wv.x + bv.x);
    ov[1] = f2bf((v.y - mean) * rs * wv.y + bv.y);
    ov[2] = f2bf((v.z - mean) * rs * wv.z + bv.z);
    ov[3] = f2bf((v.w - mean) * rs * wv.w + bv.w);
    *(s16x4*)&o[(long long)row * DMODEL + i] = ov;
}

// transpose-convert: src [R][C] (T = float|short) -> dst bf16 [C][R], 64x64 tiles
template<typename T>
__global__ __launch_bounds__(256) void tcvt_k(
    const T* __restrict__ src, short* __restrict__ dst,
    int lds_, int ldd, int Hdiv,
    long long sSb, long long sSh, long long sDb, long long sDh)
{
    __shared__ short ls[64][68];
    const int z = blockIdx.z, zb = z / Hdiv, zh = z - zb * Hdiv;
    const T* sp = src + zb * sSb + zh * sSh;
    short* dp = dst + zb * sDb + zh * sDh;
    const int tr0 = blockIdx.y * 64, tc0 = blockIdx.x * 64;
    const int t = threadIdx.x;
    const int rr = t >> 4, cc = (t & 15) * 4;
    #pragma unroll
    for (int q = 0; q < 4; ++q) {
        const int r = q * 16 + rr;
        if constexpr (sizeof(T) == 4) {
            float4 v = *(const float4*)&sp[(long long)(tr0 + r) * lds_ + tc0 + cc];
            ls[cc + 0][r] = f2bf(v.x); ls[cc + 1][r] = f2bf(v.y);
            ls[cc + 2][r] = f2bf(v.z); ls[cc + 3][r] = f2bf(v.w);
        } else {
            s16x4 v = *(const s16x4*)&sp[(long long)(tr0 + r) * lds_ + tc0 + cc];
            ls[cc + 0][r] = v[0]; ls[cc + 1][r] = v[1];
            ls[cc + 2][r] = v[2]; ls[cc + 3][r] = v[3];
        }
    }
    __syncthreads();
    #pragma unroll
    for (int q = 0; q < 4; ++q) {
        const int c = q * 16 + rr;
        s16x4 v;
        v[0] = ls[c][cc]; v[1] = ls[c][cc + 1]; v[2] = ls[c][cc + 2]; v[3] = ls[c][cc + 3];
        *(s16x4*)&dp[(long long)(tc0 + c) * ldd + tr0 + cc] = v;
    }
}

// plain fp32 -> bf16 convert (n4 = count/4)
__global__ __launch_bounds__(256) void cvt_k(
    const float* __restrict__ s, short* __restrict__ d, int n4)
{
    int i = blockIdx.x * 256 + threadIdx.x;
    const int stride = gridDim.x * 256;
    for (; i < n4; i += stride) {
        float4 v = *(const float4*)&s[(long long)i * 4];
        s16x4 o = { f2bf(v.x), f2bf(v.y), f2bf(v.z), f2bf(v.w) };
        *(s16x4*)&d[(long long)i * 4] = o;
    }
}

// ---------------------------------------------------------------------------
extern "C" void kernel_launch(void* const* d_in, const int* in_sizes, int n_in,
                              void* d_out, int out_size, void* d_ws, size_t ws_size,
                              hipStream_t stream)
{
    const int*   ids  = (const int*)  d_in[0];
    const float* tok  = (const float*)d_in[1];
    const float* pos  = (const float*)d_in[2];
    const float* ln1w = (const float*)d_in[3];
    const float* ln1b = (const float*)d_in[4];
    const float* qkvw = (const float*)d_in[5];
    const float* outw = (const float*)d_in[6];
    const float* outb = (const float*)d_in[7];
    const float* ln2w = (const float*)d_in[8];
    const float* ln2b = (const float*)d_in[9];
    const float* fc1w = (const float*)d_in[10];
    const float* fc1b = (const float*)d_in[11];
    const float* fc2w = (const float*)d_in[12];
    const float* fc2b = (const float*)d_in[13];
    const float* lnfw = (const float*)d_in[14];
    const float* lnfb = (const float*)d_in[15];
    float* out = (float*)d_out;

    char* ws = (char*)d_ws;
    const size_t MB = 1024 * 1024;
    float* x    = (float*)(ws);             //  8 MB f32 residual
    short* hb   = (short*)(ws + 8 * MB);    //  4 MB bf16 [2048][1024]
    short* qkvb = (short*)(ws + 12 * MB);   // 12 MB bf16 [2048][3072]
    short* g    = (short*)(ws + 24 * MB);   // 16 MB bf16 [2048][4096]
    short* Vt   = (short*)(ws + 88 * MB);   //  4 MB bf16 [32][64][1024]

    const bool big = ws_size >= (size_t)352 * MB;
    short *wq, *wo, *w1, *w2, *tokb;
    if (big) {
        wq   = (short*)(ws + 92  * MB);
        wo   = (short*)(ws + 140 * MB);
        w1   = (short*)(ws + 156 * MB);
        w2   = (short*)(ws + 220 * MB);
        tokb = (short*)(ws + 284 * MB);
    } else {
        wq   = (short*)(ws + 92  * MB);
        wo   = (short*)(ws + 98  * MB);
        w1   = (short*)(ws + 100 * MB);
        w2   = (short*)(ws + 108 * MB);
        tokb = (short*)(ws + 24  * MB);     // aliases g (dead by lm_head)
    }

    const long long LWQ = 3072LL * 1024, LWO = 1024LL * 1024;
    const long long LW1 = 4096LL * 1024, LW2 = 1024LL * 4096;

    hipFuncSetAttribute((const void*)gemm256_k,
                        hipFuncAttributeMaxDynamicSharedMemorySize, 131072);

    dim3 blk(256);
    embed_k<<<MTOK, blk, 0, stream>>>(ids, tok, pos, x);

    if (big) {
        tcvt_k<float><<<dim3(48, 16, 8), blk, 0, stream>>>(qkvw, wq, 3072, 1024, 1, LWQ, 0, LWQ, 0);
        tcvt_k<float><<<dim3(16, 16, 8), blk, 0, stream>>>(outw, wo, 1024, 1024, 1, LWO, 0, LWO, 0);
        tcvt_k<float><<<dim3(64, 16, 8), blk, 0, stream>>>(fc1w, w1, 4096, 1024, 1, LW1, 0, LW1, 0);
        tcvt_k<float><<<dim3(16, 64, 8), blk, 0, stream>>>(fc2w, w2, 1024, 4096, 1, LW2, 0, LW2, 0);
        cvt_k<<<2048, blk, 0, stream>>>(tok, tokb, NVOCAB * DMODEL / 4);
    }

    for (int l = 0; l < NLAYER; ++l) {
        short* wql = wq + (big ? l * LWQ : 0);
        short* wol = wo + (big ? l * LWO : 0);
        short* w1l = w1 + (big ? l * LW1 : 0);
        short* w2l = w2 + (big ? l * LW2 : 0);
        if (!big) {
            tcvt_k<float><<<dim3(48, 16, 1), blk, 0, stream>>>(qkvw + l * LWQ, wql, 3072, 1024, 1, 0, 0, 0, 0);
            tcvt_k<float><<<dim3(16, 16, 1), blk, 0, stream>>>(outw + l * LWO, wol, 1024, 1024, 1, 0, 0, 0, 0);
            tcvt_k<float><<<dim3(64, 16, 1), blk, 0, stream>>>(fc1w + l * LW1, w1l, 4096, 1024, 1, 0, 0, 0, 0);
            tcvt_k<float><<<dim3(16, 64, 1), blk, 0, stream>>>(fc2w + l * LW2, w2l, 1024, 4096, 1, 0, 0, 0, 0);
        }

        ln_k<<<MTOK, blk, 0, stream>>>(x, ln1w + l * DMODEL, ln1b + l * DMODEL, hb);

        // qkv = ln1 @ Wqkv -> bf16
        gemm_k<128, 1><<<dim3(24, 16, 1), blk, 0, stream>>>(
            hb, wql, qkvb, nullptr, nullptr,
            MTOK, 3 * DMODEL, DMODEL, DMODEL, DMODEL, 3 * DMODEL, 1.0f, 1);

        // Vt[z] = V^T
        tcvt_k<short><<<dim3(1, 16, BBATCH * NHEAD), blk, 0, stream>>>(
            qkvb + 2 * DMODEL, Vt, 3 * DMODEL, TSEQ, NHEAD,
            (long long)TSEQ * 3 * DMODEL, HDIM,
            (long long)NHEAD * HDIM * TSEQ, (long long)HDIM * TSEQ);

        // fused attention -> hb (bf16)
        flash_k<<<dim3(8, BBATCH * NHEAD), blk, 0, stream>>>(qkvb, Vt, hb);

        // x += attn @ Wout + b
        gemm_k<64, 2><<<dim3(16, 16, 1), blk, 0, stream>>>(
            hb, wol, x, outb + l * DMODEL, x,
            MTOK, DMODEL, DMODEL, DMODEL, DMODEL, DMODEL, 1.0f, 1);

        ln_k<<<MTOK, blk, 0, stream>>>(x, ln2w + l * DMODEL, ln2b + l * DMODEL, hb);

        // g = gelu(ln2 @ Wfc1 + b) -> bf16
        gemm_k<128, 3><<<dim3(32, 16, 1), blk, 0, stream>>>(
            hb, w1l, g, fc1b + (long long)l * 4 * DMODEL, nullptr,
            MTOK, 4 * DMODEL, DMODEL, DMODEL, DMODEL, 4 * DMODEL, 1.0f, 1);

        // x += g @ Wfc2 + b
        gemm_k<64, 2><<<dim3(16, 16, 1), blk, 0, stream>>>(
            g, w2l, x, fc2b + l * DMODEL, x,
            MTOK, DMODEL, 4 * DMODEL, 4 * DMODEL, 4 * DMODEL, DMODEL, 1.0f, 1);
    }

    ln_k<<<MTOK, blk, 0, stream>>>(x, lnfw, lnfb, hb);

    if (!big)
        cvt_k<<<2048, blk, 0, stream>>>(tok, tokb, NVOCAB * DMODEL / 4);

    // logits = lnf @ tok_emb^T via 256x256 8-phase kernel (grid = 125*8)
    gemm256_k<<<dim3((NVOCAB / 256) * (MTOK / 256)), dim3(512), 131072, stream>>>(
        hb, tokb, out, DMODEL, DMODEL, DMODEL, NVOCAB, NVOCAB / 256);
}

// Round 6
// 1785.577 us; speedup vs baseline: 2.4909x; 1.1165x over previous
//
#include <hip/hip_runtime.h>
#include <hip/hip_bf16.h>
#include <math.h>

// ---------------------------------------------------------------------------
// GPT forward, round 6: fc2 split-K (BN=128, z=2, fused reduce), flash with
// T14 register prefetch of next K/V tile, wave-per-row LN, merged per-layer
// weight-convert kernel, ws repack (big path at 267 MB).
// ---------------------------------------------------------------------------

#define DEV_INLINE __device__ __forceinline__

typedef float  f32x4  __attribute__((ext_vector_type(4)));
typedef __bf16 bf16x8 __attribute__((ext_vector_type(8)));
typedef short  s16x4  __attribute__((ext_vector_type(4)));
typedef short  s16x8  __attribute__((ext_vector_type(8)));
typedef unsigned int u32x4 __attribute__((ext_vector_type(4)));

#define BBATCH 2
#define TSEQ   1024
#define DMODEL 1024
#define NHEAD  16
#define HDIM   64
#define NLAYER 8
#define NVOCAB 32000
#define MTOK   (BBATCH*TSEQ)   // 2048

DEV_INLINE short f2bf(float f) {
    __bf16 h = (__bf16)f;
    union { __bf16 h; short s; } u; u.h = h; return u.s;
}

typedef const __attribute__((address_space(1))) unsigned int* gas_t;
typedef __attribute__((address_space(3))) unsigned int* las_t;
DEV_INLINE void llds16(const void* g, void* l) {
    __builtin_amdgcn_global_load_lds((gas_t)g, (las_t)l, 16, 0, 0);
}

#define BAR()  asm volatile("s_barrier" ::: "memory")
#define VMW4() asm volatile("s_waitcnt vmcnt(4)" ::: "memory")
#define VMW2() asm volatile("s_waitcnt vmcnt(2)" ::: "memory")
#define VMW0() asm volatile("s_waitcnt vmcnt(0)" ::: "memory")

// ---------------------------------------------------------------------------
// Flash attention: grid (8 q-blocks, 32 bh), 256 threads (4 waves x 32 rows).
// KV tiles of 128; online softmax in registers; next tile's K/V prefetched
// into registers during compute (T14), ds_write'd after the PV barrier.
// ---------------------------------------------------------------------------
__global__ __launch_bounds__(256) void flash_k(
    const short* __restrict__ qkv, const short* __restrict__ Vt,
    short* __restrict__ O)
{
    const int qb = blockIdx.x;          // 0..7
    const int z  = blockIdx.y;          // 0..31
    const int zb = z >> 4, zh = z & 15;

    __shared__ short Qs[128 * 64];      // 16 KB
    __shared__ short KP[128 * 136];     // 34 KB: K tile [128][64], then P [128][136]
    __shared__ short Vs[64 * 128];      // 16 KB: V^T tile [64][128]

    const int tid  = threadIdx.x;
    const int w    = tid >> 6, lane = tid & 63;
    const int lr   = lane & 15, kg = lane >> 4;

    const long long qbase = (long long)zb * TSEQ * 3072;
    const short* Qg = qkv + qbase + zh * HDIM;
    const short* Kg = qkv + qbase + DMODEL + zh * HDIM;
    const short* Vg = Vt + (long long)z * (HDIM * TSEQ);

    const int sr   = tid >> 3, pc = tid & 7;
    const int lc   = pc ^ (sr & 7);
    const int sr16 = tid >> 4, pc16 = tid & 15;

    // ---- stage Q tile (128x64) once + K/V tile 0
    {
        const short* qp = Qg + (long long)(qb * 128 + sr) * 3072 + lc * 8;
        const short* kp = Kg + (long long)(0 + sr) * 3072 + lc * 8;
        #pragma unroll
        for (int it = 0; it < 4; ++it) {
            llds16(qp + (long long)it * 32 * 3072, Qs + tid * 8 + it * 2048);
            llds16(kp + (long long)it * 32 * 3072, KP + tid * 8 + it * 2048);
        }
        #pragma unroll
        for (int it = 0; it < 4; ++it) {
            const int r = it * 16 + sr16;
            const int lc2 = pc16 ^ (r & 7);
            llds16(Vg + (long long)r * TSEQ + 0 + lc2 * 8, Vs + tid * 8 + it * 2048);
        }
    }
    __syncthreads();
    bf16x8 afq[2][2];
    #pragma unroll
    for (int s = 0; s < 2; ++s)
        #pragma unroll
        for (int i = 0; i < 2; ++i) {
            const int r = w * 32 + i * 16 + lr;
            afq[s][i] = *(const bf16x8*)&Qs[r * 64 + (((s * 4 + kg) ^ (r & 7)) << 3)];
        }

    f32x4 aco[2][4] = {};
    float m_[2][4], l_[2][4];
    #pragma unroll
    for (int i = 0; i < 2; ++i)
        #pragma unroll
        for (int p = 0; p < 4; ++p) { m_[i][p] = -1e30f; l_[i][p] = 0.f; }

    const int nt = qb + 1;
    for (int t = 0; t < nt; ++t) {
        // ---- prefetch next K/V tile into registers (issued before compute)
        u32x4 kpre[4], vpre[4];
        const bool nx = (t + 1 < nt);
        if (nx) {
            const int kn = (t + 1) * 128;
            #pragma unroll
            for (int it = 0; it < 4; ++it)
                kpre[it] = *(const u32x4*)(Kg + (long long)(kn + sr + it * 32) * 3072 + lc * 8);
            #pragma unroll
            for (int it = 0; it < 4; ++it) {
                const int r = it * 16 + sr16;
                const int lc2 = pc16 ^ (r & 7);
                vpre[it] = *(const u32x4*)(Vg + (long long)r * TSEQ + kn + lc2 * 8);
            }
            __builtin_amdgcn_sched_barrier(0);   // pin issue point (don't sink)
        }

        // ---- S = Q K^T  (f32 frags)
        f32x4 acs[2][8] = {};
        #pragma unroll
        for (int s = 0; s < 2; ++s)
            #pragma unroll
            for (int j = 0; j < 8; ++j) {
                const int rk = j * 16 + lr;
                bf16x8 bk = *(const bf16x8*)&KP[rk * 64 + (((s * 4 + kg) ^ (rk & 7)) << 3)];
                #pragma unroll
                for (int i = 0; i < 2; ++i)
                    acs[i][j] = __builtin_amdgcn_mfma_f32_16x16x32_bf16(
                        afq[s][i], bk, acs[i][j], 0, 0, 0);
            }

        // causal mask (diagonal tile only), scale by 1/8
        #pragma unroll
        for (int i = 0; i < 2; ++i)
            #pragma unroll
            for (int j = 0; j < 8; ++j)
                #pragma unroll
                for (int p = 0; p < 4; ++p) {
                    float v = acs[i][j][p] * 0.125f;
                    if (t == qb && (j * 16 + lr) > (w * 32 + i * 16 + kg * 4 + p))
                        v = -1e30f;
                    acs[i][j][p] = v;
                }

        // ---- online softmax (registers)
        float sc[2][4];
        #pragma unroll
        for (int i = 0; i < 2; ++i)
            #pragma unroll
            for (int p = 0; p < 4; ++p) {
                float r = acs[i][0][p];
                #pragma unroll
                for (int j = 1; j < 8; ++j) r = fmaxf(r, acs[i][j][p]);
                r = fmaxf(r, __shfl_xor(r, 1, 64));
                r = fmaxf(r, __shfl_xor(r, 2, 64));
                r = fmaxf(r, __shfl_xor(r, 4, 64));
                r = fmaxf(r, __shfl_xor(r, 8, 64));
                const float mn = fmaxf(m_[i][p], r);
                sc[i][p] = __expf(m_[i][p] - mn);
                m_[i][p] = mn;
            }
        #pragma unroll
        for (int i = 0; i < 2; ++i)
            #pragma unroll
            for (int j = 0; j < 8; ++j)
                #pragma unroll
                for (int p = 0; p < 4; ++p)
                    acs[i][j][p] = __expf(acs[i][j][p] - m_[i][p]);
        #pragma unroll
        for (int i = 0; i < 2; ++i)
            #pragma unroll
            for (int p = 0; p < 4; ++p) {
                float s = 0.f;
                #pragma unroll
                for (int j = 0; j < 8; ++j) s += acs[i][j][p];
                s += __shfl_xor(s, 1, 64);
                s += __shfl_xor(s, 2, 64);
                s += __shfl_xor(s, 4, 64);
                s += __shfl_xor(s, 8, 64);
                l_[i][p] = l_[i][p] * sc[i][p] + s;
            }
        #pragma unroll
        for (int i = 0; i < 2; ++i)
            #pragma unroll
            for (int j2 = 0; j2 < 4; ++j2)
                #pragma unroll
                for (int p = 0; p < 4; ++p)
                    aco[i][j2][p] *= sc[i][p];

        __syncthreads();   // all waves done reading K before P overwrites it

        // ---- write P (bf16) into KP as [q][136]
        #pragma unroll
        for (int i = 0; i < 2; ++i)
            #pragma unroll
            for (int j = 0; j < 8; ++j)
                #pragma unroll
                for (int p = 0; p < 4; ++p)
                    KP[(w * 32 + i * 16 + kg * 4 + p) * 136 + j * 16 + lr] =
                        f2bf(acs[i][j][p]);
        __syncthreads();

        // ---- O += P V
        #pragma unroll
        for (int ks = 0; ks < 4; ++ks) {
            bf16x8 pa[2], pb[4];
            #pragma unroll
            for (int i = 0; i < 2; ++i)
                pa[i] = *(const bf16x8*)&KP[(w * 32 + i * 16 + lr) * 136 + ks * 32 + kg * 8];
            #pragma unroll
            for (int j2 = 0; j2 < 4; ++j2) {
                const int d = j2 * 16 + lr;
                pb[j2] = *(const bf16x8*)&Vs[d * 128 + (((ks * 4 + kg) ^ (d & 7)) << 3)];
            }
            #pragma unroll
            for (int i = 0; i < 2; ++i)
                #pragma unroll
                for (int j2 = 0; j2 < 4; ++j2)
                    aco[i][j2] = __builtin_amdgcn_mfma_f32_16x16x32_bf16(
                        pa[i], pb[j2], aco[i][j2], 0, 0, 0);
        }
        __syncthreads();   // done reading P and Vs

        // ---- commit prefetched K/V for next tile
        if (nx) {
            #pragma unroll
            for (int it = 0; it < 4; ++it)
                *(u32x4*)(KP + tid * 8 + it * 2048) = kpre[it];
            #pragma unroll
            for (int it = 0; it < 4; ++it)
                *(u32x4*)(Vs + tid * 8 + it * 2048) = vpre[it];
            __syncthreads();
        }
    }

    // ---- epilogue: O / l -> bf16
    #pragma unroll
    for (int i = 0; i < 2; ++i)
        #pragma unroll
        for (int j2 = 0; j2 < 4; ++j2)
            #pragma unroll
            for (int p = 0; p < 4; ++p) {
                const int row = zb * TSEQ + qb * 128 + w * 32 + i * 16 + kg * 4 + p;
                const int col = zh * HDIM + j2 * 16 + lr;
                O[(long long)row * DMODEL + col] = f2bf(aco[i][j2][p] / l_[i][p]);
            }
}

// ---------------------------------------------------------------------------
// 256x256x(BK=64) 8-wave 8-phase GEMM, f32 output (lm_head).
// ---------------------------------------------------------------------------
__global__ __launch_bounds__(512, 2) void gemm256_k(
    const short* __restrict__ A, const short* __restrict__ B,
    float* __restrict__ C, int K, int lda, int ldb, int ldc, int gx)
{
    extern __shared__ short smem[];

    const int nwg = gridDim.x;
    int wg = blockIdx.x;
    int sw = (wg & 7) * (nwg >> 3) + (wg >> 3);   // XCD-contiguous
    const int bx = sw >> 3, by = sw & 7;          // column-major within XCD
    const int bn0 = bx * 256, bm0 = by * 256;

    const int tid  = threadIdx.x;
    const int w    = tid >> 6, lane = tid & 63;
    const int wm   = w >> 2, wn = w & 3;
    const int lr   = lane & 15, kg = lane >> 4;

    const int r0  = tid >> 3;
    const int pc  = tid & 7;
    const int lc0 = pc ^ (r0 & 7);
    const int r1  = r0 + 64;
    const int lc1 = pc ^ (r1 & 7);

    f32x4 acc[2][2][4][2] = {};
    const int nk = K >> 6;

    auto stage = [&](int buf, int isA, int h, int kk) {
        const short* gp = isA ? A : B;
        const int    ld = isA ? lda : ldb;
        const long long rb = (long long)((isA ? bm0 : bn0) + h * 128);
        short* lp = smem + buf * 32768 + (isA ? 0 : 16384) + h * 8192;
        llds16(gp + (rb + r0) * ld + kk + lc0 * 8, lp + w * 512);
        llds16(gp + (rb + r1) * ld + kk + lc1 * 8, lp + 4096 + w * 512);
    };

#define PHASE(BUF, QM, QN, ISA, H, DOWAIT)                                      \
    do {                                                                        \
        const short* Ah = smem + (BUF) * 32768 + (QM) * 8192;                   \
        const short* Bh = smem + (BUF) * 32768 + 16384 + (QN) * 8192;           \
        bf16x8 af[2][4], bfr[2][2];                                             \
        _Pragma("unroll")                                                       \
        for (int s2 = 0; s2 < 2; ++s2) {                                        \
            _Pragma("unroll")                                                   \
            for (int i = 0; i < 4; ++i) {                                       \
                const int ra = wm * 64 + i * 16 + lr;                           \
                af[s2][i] = *(const bf16x8*)                                    \
                    &Ah[ra * 64 + (((s2 * 4 + kg) ^ (ra & 7)) << 3)];           \
            }                                                                   \
            _Pragma("unroll")                                                   \
            for (int j = 0; j < 2; ++j) {                                       \
                const int rb2 = wn * 32 + j * 16 + lr;                          \
                bfr[s2][j] = *(const bf16x8*)                                   \
                    &Bh[rb2 * 64 + (((s2 * 4 + kg) ^ (rb2 & 7)) << 3)];         \
            }                                                                   \
        }                                                                       \
        if (pf) stage(nb, ISA, H, kk);                                          \
        BAR();                                                                  \
        __builtin_amdgcn_s_setprio(1);                                          \
        _Pragma("unroll")                                                       \
        for (int s2 = 0; s2 < 2; ++s2)                                          \
            _Pragma("unroll")                                                   \
            for (int i = 0; i < 4; ++i)                                         \
                _Pragma("unroll")                                               \
                for (int j = 0; j < 2; ++j)                                     \
                    acc[QM][QN][i][j] = __builtin_amdgcn_mfma_f32_16x16x32_bf16(\
                        af[s2][i], bfr[s2][j], acc[QM][QN][i][j], 0, 0, 0);     \
        __builtin_amdgcn_s_setprio(0);                                          \
        DOWAIT;                                                                 \
        BAR();                                                                  \
    } while (0)

    stage(0, 1, 0, 0);
    stage(0, 0, 0, 0);
    stage(0, 1, 1, 0);
    stage(0, 0, 1, 0);
    if (nk > 1) { VMW4(); } else { VMW0(); }
    BAR();

    for (int t = 0; t < nk - 1; ++t) {
        const int  buf = t & 1, nb = buf ^ 1;
        const int  kk  = (t + 1) << 6;
        const bool pf  = true;
        PHASE(buf, 0, 0, 1, 0, VMW4());
        PHASE(buf, 1, 0, 0, 0, VMW4());
        PHASE(buf, 1, 1, 1, 1, (void)0);
        PHASE(buf, 0, 1, 0, 1, VMW4());
    }
    {   // peeled last tile: drain 4 -> 2 -> 0
        const int  buf = (nk - 1) & 1, nb = buf ^ 1; (void)nb;
        const int  kk  = 0;
        const bool pf  = false;
        PHASE(buf, 0, 0, 1, 0, VMW2());
        PHASE(buf, 1, 0, 0, 0, VMW0());
        PHASE(buf, 1, 1, 1, 1, (void)0);
        PHASE(buf, 0, 1, 0, 1, (void)0);
    }
#undef PHASE

    #pragma unroll
    for (int qm = 0; qm < 2; ++qm)
        #pragma unroll
        for (int qn = 0; qn < 2; ++qn)
            #pragma unroll
            for (int i = 0; i < 4; ++i)
                #pragma unroll
                for (int j = 0; j < 2; ++j) {
                    const int gr = bm0 + qm * 128 + wm * 64 + i * 16 + kg * 4;
                    const int gc = bn0 + qn * 128 + wn * 32 + j * 16 + lr;
                    #pragma unroll
                    for (int p = 0; p < 4; ++p)
                        C[(long long)(gr + p) * ldc + gc] = acc[qm][qn][i][j][p];
                }
}

// ---------------------------------------------------------------------------
// 128x(BN) 2-phase GEMM. A bf16 [M][K], B bf16 [N][K]. blockIdx.z batches
// via element strides sAz/sBz/sCz (used for fc2 split-K).
// EPI: 0=f32, 1=bf16*scale, 2=f32+bias+resid, 3=bf16 gelu(acc+bias).
// ---------------------------------------------------------------------------
template<int BN, int EPI>
__global__ __launch_bounds__(256) void gemm_k(
    const short* __restrict__ Ag, const short* __restrict__ Bg,
    void* __restrict__ Cg, const float* __restrict__ bias,
    const float* __restrict__ resid,
    int M, int N, int K, int lda, int ldb, int ldc,
    long long sAz, long long sBz, long long sCz,
    float scale, int swz)
{
    int bx = blockIdx.x, by = blockIdx.y;
    if (swz) {
        const int gx = gridDim.x;
        const int nwg = gx * gridDim.y;
        if ((nwg & 7) == 0) {
            int wg = by * gx + bx;
            int wg2 = (wg & 7) * (nwg >> 3) + (wg >> 3);
            bx = wg2 % gx; by = wg2 / gx;
        }
    }
    const int bn0 = bx * BN, bm0 = by * 128;
    const int zz = blockIdx.z;

    const short* A = Ag + zz * sAz;
    const short* B = Bg + zz * sBz;

    __shared__ short Als[128 * 64];
    __shared__ short Bls[BN * 64];

    const int tid  = threadIdx.x;
    const int lane = tid & 63;
    const int wave = tid >> 6;
    constexpr int WMS = (BN == 128) ? 64 : 32;
    constexpr int MI  = (BN == 128) ? 4 : 2;
    constexpr int NJ  = 4;
    const int wm = (BN == 128) ? (wave >> 1) : wave;
    const int wn = (BN == 128) ? (wave & 1) : 0;
    const int lr = lane & 15, kg = lane >> 4;
    const int xv = (lr & 7) << 4;

    const int sr = tid >> 3;
    const int sc = (tid & 7) ^ (sr & 7);
    const short* aP = A + (long long)(bm0 + sr) * lda + sc * 8;
    const short* bP = B + (long long)(bn0 + sr) * ldb + sc * 8;
    short* aL = &Als[wave * 512];
    short* bL = &Bls[wave * 512];

    f32x4 acc[MI][NJ] = {};
    const int nk = K >> 6;

    for (int kt = 0; kt < nk; ++kt) {
        const int k0 = kt << 6;
        #pragma unroll
        for (int it = 0; it < 4; ++it)
            llds16(aP + (long long)it * 32 * lda + k0, aL + it * 2048);
        #pragma unroll
        for (int it = 0; it < BN / 32; ++it)
            llds16(bP + (long long)it * 32 * ldb + k0, bL + it * 2048);
        __syncthreads();

        #pragma unroll
        for (int s = 0; s < 2; ++s) {
            const int ofs = (((s << 6) | (kg << 4)) ^ xv) >> 1;
            bf16x8 af[MI], bf[NJ];
            #pragma unroll
            for (int i = 0; i < MI; ++i)
                af[i] = *(const bf16x8*)&Als[(wm * WMS + i * 16 + lr) * 64 + ofs];
            #pragma unroll
            for (int j = 0; j < NJ; ++j)
                bf[j] = *(const bf16x8*)&Bls[(wn * 64 + j * 16 + lr) * 64 + ofs];
            #pragma unroll
            for (int i = 0; i < MI; ++i)
                #pragma unroll
                for (int j = 0; j < NJ; ++j)
                    acc[i][j] = __builtin_amdgcn_mfma_f32_16x16x32_bf16(
                        af[i], bf[j], acc[i][j], 0, 0, 0);
        }
        __syncthreads();
    }

    short* Cs = (short*)Cg + zz * sCz;
    float* Cf = (float*)Cg + zz * sCz;
    #pragma unroll
    for (int i = 0; i < MI; ++i) {
        #pragma unroll
        for (int j = 0; j < NJ; ++j) {
            const int gr = bm0 + wm * WMS + i * 16 + kg * 4;
            const int gc = bn0 + wn * 64 + j * 16 + lr;
            #pragma unroll
            for (int p = 0; p < 4; ++p) {
                const long long off = (long long)(gr + p) * ldc + gc;
                float v = acc[i][j][p];
                if (EPI == 0) {
                    Cf[off] = v;
                } else if (EPI == 1) {
                    Cs[off] = f2bf(v * scale);
                } else if (EPI == 2) {
                    Cf[off] = v + bias[gc] + resid[off];
                } else {
                    v += bias[gc];
                    v = 0.5f * v * (1.0f + erff(v * 0.70710678118654752f));
                    Cs[off] = f2bf(v);
                }
            }
        }
    }
}

// split-K reduce: x[row][col] += p0 + p1 + bias[col]
__global__ __launch_bounds__(256) void freduce_k(
    const float* __restrict__ p0, const float* __restrict__ p1,
    const float* __restrict__ bias, float* __restrict__ x)
{
    const long long idx = ((long long)blockIdx.x * 256 + threadIdx.x) * 4;
    const int col = (int)(idx & (DMODEL - 1));
    float4 a = *(const float4*)&p0[idx];
    float4 b = *(const float4*)&p1[idx];
    float4 c = *(const float4*)&x[idx];
    float4 bb = *(const float4*)&bias[col];
    float4 o;
    o.x = c.x + a.x + b.x + bb.x;
    o.y = c.y + a.y + b.y + bb.y;
    o.z = c.z + a.z + b.z + bb.z;
    o.w = c.w + a.w + b.w + bb.w;
    *(float4*)&x[idx] = o;
}

// ---------------------------------------------------------------------------
__global__ __launch_bounds__(256) void embed_k(
    const int* __restrict__ ids, const float* __restrict__ tok,
    const float* __restrict__ pos, float* __restrict__ x)
{
    const int gid = blockIdx.x * 256 + threadIdx.x;
    const int row = gid >> 8;
    const int c   = (gid & 255) << 2;
    const int t   = row & (TSEQ - 1);
    const int id  = ids[row];
    const float4 a = *(const float4*)&tok[(long long)id * DMODEL + c];
    const float4 p = *(const float4*)&pos[(long long)t * DMODEL + c];
    float4 o; o.x = a.x + p.x; o.y = a.y + p.y; o.z = a.z + p.z; o.w = a.w + p.w;
    *(float4*)&x[(long long)row * DMODEL + c] = o;
}

// wave-per-row LN (no barriers): grid MTOK/4, 256 threads = 4 waves
__global__ __launch_bounds__(256) void ln_k(
    const float* __restrict__ x, const float* __restrict__ w,
    const float* __restrict__ b, short* __restrict__ o)
{
    const int row  = blockIdx.x * 4 + (threadIdx.x >> 6);
    const int lane = threadIdx.x & 63;
    const float* xp = x + (long long)row * DMODEL + lane * 16;
    float4 v[4];
    #pragma unroll
    for (int q = 0; q < 4; ++q) v[q] = *(const float4*)(xp + q * 4);
    float s = 0.f, s2 = 0.f;
    #pragma unroll
    for (int q = 0; q < 4; ++q) {
        s  += v[q].x + v[q].y + v[q].z + v[q].w;
        s2 += v[q].x * v[q].x + v[q].y * v[q].y + v[q].z * v[q].z + v[q].w * v[q].w;
    }
    #pragma unroll
    for (int d = 1; d < 64; d <<= 1) {
        s  += __shfl_xor(s, d, 64);
        s2 += __shfl_xor(s2, d, 64);
    }
    const float mean = s * (1.0f / DMODEL);
    const float var  = s2 * (1.0f / DMODEL) - mean * mean;
    const float rs   = rsqrtf(var + 1e-5f);
    const float* wp = w + lane * 16;
    const float* bp = b + lane * 16;
    short ov[16];
    #pragma unroll
    for (int q = 0; q < 4; ++q) {
        float4 wv = *(const float4*)(wp + q * 4);
        float4 bv = *(const float4*)(bp + q * 4);
        ov[q * 4 + 0] = f2bf((v[q].x - mean) * rs * wv.x + bv.x);
        ov[q * 4 + 1] = f2bf((v[q].y - mean) * rs * wv.y + bv.y);
        ov[q * 4 + 2] = f2bf((v[q].z - mean) * rs * wv.z + bv.z);
        ov[q * 4 + 3] = f2bf((v[q].w - mean) * rs * wv.w + bv.w);
    }
    short* op = o + (long long)row * DMODEL + lane * 16;
    *(s16x8*)op       = *(s16x8*)&ov[0];
    *(s16x8*)(op + 8) = *(s16x8*)&ov[8];
}

// transpose-convert core (64x64 tile)
template<typename T>
DEV_INLINE void tcvt_body(const T* sp, short* dp, int lds_, int ldd,
                          int bx, int by, short (*ls)[68], int t)
{
    const int tr0 = by * 64, tc0 = bx * 64;
    const int rr = t >> 4, cc = (t & 15) * 4;
    #pragma unroll
    for (int q = 0; q < 4; ++q) {
        const int r = q * 16 + rr;
        if constexpr (sizeof(T) == 4) {
            float4 v = *(const float4*)&sp[(long long)(tr0 + r) * lds_ + tc0 + cc];
            ls[cc + 0][r] = f2bf(v.x); ls[cc + 1][r] = f2bf(v.y);
            ls[cc + 2][r] = f2bf(v.z); ls[cc + 3][r] = f2bf(v.w);
        } else {
            s16x4 v = *(const s16x4*)&sp[(long long)(tr0 + r) * lds_ + tc0 + cc];
            ls[cc + 0][r] = v[0]; ls[cc + 1][r] = v[1];
            ls[cc + 2][r] = v[2]; ls[cc + 3][r] = v[3];
        }
    }
    __syncthreads();
    #pragma unroll
    for (int q = 0; q < 4; ++q) {
        const int c = q * 16 + rr;
        s16x4 v;
        v[0] = ls[c][cc]; v[1] = ls[c][cc + 1]; v[2] = ls[c][cc + 2]; v[3] = ls[c][cc + 3];
        *(s16x4*)&dp[(long long)(tc0 + c) * ldd + tr0 + cc] = v;
    }
}

template<typename T>
__global__ __launch_bounds__(256) void tcvt_k(
    const T* __restrict__ src, short* __restrict__ dst,
    int lds_, int ldd, int Hdiv,
    long long sSb, long long sSh, long long sDb, long long sDh)
{
    __shared__ short ls[64][68];
    const int z = blockIdx.z, zb = z / Hdiv, zh = z - zb * Hdiv;
    tcvt_body<T>(src + zb * sSb + zh * sSh, dst + zb * sDb + zh * sDh,
                 lds_, ldd, blockIdx.x, blockIdx.y, ls, threadIdx.x);
}

// merged per-layer weight convert (!big path): 3072 blocks
__global__ __launch_bounds__(256) void wcvt_k(
    const float* __restrict__ qw, const float* __restrict__ ow,
    const float* __restrict__ f1, const float* __restrict__ f2,
    short* __restrict__ wq, short* __restrict__ wo,
    short* __restrict__ w1, short* __restrict__ w2)
{
    __shared__ short ls[64][68];
    const int id = blockIdx.x;
    const float* src; short* dst; int lds_, ldd, bx, by;
    if (id < 768)       { src = qw; dst = wq; lds_ = 3072; ldd = 1024; bx = id % 48;  by = id / 48; }
    else if (id < 1024) { int i = id - 768;  src = ow; dst = wo; lds_ = 1024; ldd = 1024; bx = i % 16; by = i / 16; }
    else if (id < 2048) { int i = id - 1024; src = f1; dst = w1; lds_ = 4096; ldd = 1024; bx = i % 64; by = i / 64; }
    else                { int i = id - 2048; src = f2; dst = w2; lds_ = 1024; ldd = 4096; bx = i % 16; by = i / 16; }
    tcvt_body<float>(src, dst, lds_, ldd, bx, by, ls, threadIdx.x);
}

// plain fp32 -> bf16 convert (n4 = count/4)
__global__ __launch_bounds__(256) void cvt_k(
    const float* __restrict__ s, short* __restrict__ d, int n4)
{
    int i = blockIdx.x * 256 + threadIdx.x;
    const int stride = gridDim.x * 256;
    for (; i < n4; i += stride) {
        float4 v = *(const float4*)&s[(long long)i * 4];
        s16x4 o = { f2bf(v.x), f2bf(v.y), f2bf(v.z), f2bf(v.w) };
        *(s16x4*)&d[(long long)i * 4] = o;
    }
}

// ---------------------------------------------------------------------------
extern "C" void kernel_launch(void* const* d_in, const int* in_sizes, int n_in,
                              void* d_out, int out_size, void* d_ws, size_t ws_size,
                              hipStream_t stream)
{
    const int*   ids  = (const int*)  d_in[0];
    const float* tok  = (const float*)d_in[1];
    const float* pos  = (const float*)d_in[2];
    const float* ln1w = (const float*)d_in[3];
    const float* ln1b = (const float*)d_in[4];
    const float* qkvw = (const float*)d_in[5];
    const float* outw = (const float*)d_in[6];
    const float* outb = (const float*)d_in[7];
    const float* ln2w = (const float*)d_in[8];
    const float* ln2b = (const float*)d_in[9];
    const float* fc1w = (const float*)d_in[10];
    const float* fc1b = (const float*)d_in[11];
    const float* fc2w = (const float*)d_in[12];
    const float* fc2b = (const float*)d_in[13];
    const float* lnfw = (const float*)d_in[14];
    const float* lnfb = (const float*)d_in[15];
    float* out = (float*)d_out;

    char* ws = (char*)d_ws;
    const size_t MB = 1024 * 1024;
    // activations
    float* x    = (float*)(ws);             //  0-8   f32 residual
    short* hb   = (short*)(ws + 8  * MB);   //  8-12  bf16 [2048][1024]
    short* qkvb = (short*)(ws + 12 * MB);   // 12-24  bf16 [2048][3072]
    short* g    = (short*)(ws + 24 * MB);   // 24-40  bf16 [2048][4096]
    short* Vt   = (short*)(ws + 40 * MB);   // 40-44  bf16 [32][64][1024]
    float* fp   = (float*)(ws + 44 * MB);   // 44-60  f32 [2][2048][1024] fc2 partials
    short* tokb = (short*)(ws + 12 * MB);   // 12-74.5 (lm_head phase only; aliases dead bufs)

    // weights at 75 MB
    const bool big = ws_size >= (size_t)267 * MB;
    short* wq = (short*)(ws + 75 * MB);
    short *wo, *w1, *w2;
    if (big) {
        wo = (short*)(ws + 123 * MB);       // wq 48 MB (8 layers)
        w1 = (short*)(ws + 139 * MB);       // wo 16
        w2 = (short*)(ws + 203 * MB);       // w1 64, w2 64 -> ends 267
    } else {
        wo = (short*)(ws + 81 * MB);        // wq 6 MB (1 layer)
        w1 = (short*)(ws + 83 * MB);        // wo 2
        w2 = (short*)(ws + 91 * MB);        // w1 8, w2 8 -> ends 99
    }

    const long long LWQ = 3072LL * 1024, LWO = 1024LL * 1024;
    const long long LW1 = 4096LL * 1024, LW2 = 1024LL * 4096;

    hipFuncSetAttribute((const void*)gemm256_k,
                        hipFuncAttributeMaxDynamicSharedMemorySize, 131072);

    dim3 blk(256);
    embed_k<<<MTOK, blk, 0, stream>>>(ids, tok, pos, x);

    if (big) {
        tcvt_k<float><<<dim3(48, 16, 8), blk, 0, stream>>>(qkvw, wq, 3072, 1024, 1, LWQ, 0, LWQ, 0);
        tcvt_k<float><<<dim3(16, 16, 8), blk, 0, stream>>>(outw, wo, 1024, 1024, 1, LWO, 0, LWO, 0);
        tcvt_k<float><<<dim3(64, 16, 8), blk, 0, stream>>>(fc1w, w1, 4096, 1024, 1, LW1, 0, LW1, 0);
        tcvt_k<float><<<dim3(16, 64, 8), blk, 0, stream>>>(fc2w, w2, 1024, 4096, 1, LW2, 0, LW2, 0);
    }

    for (int l = 0; l < NLAYER; ++l) {
        short* wql = wq + (big ? l * LWQ : 0);
        short* wol = wo + (big ? l * LWO : 0);
        short* w1l = w1 + (big ? l * LW1 : 0);
        short* w2l = w2 + (big ? l * LW2 : 0);
        if (!big)
            wcvt_k<<<3072, blk, 0, stream>>>(
                qkvw + l * LWQ, outw + l * LWO, fc1w + l * LW1, fc2w + l * LW2,
                wql, wol, w1l, w2l);

        ln_k<<<MTOK / 4, blk, 0, stream>>>(x, ln1w + l * DMODEL, ln1b + l * DMODEL, hb);

        // qkv = ln1 @ Wqkv -> bf16
        gemm_k<128, 1><<<dim3(24, 16, 1), blk, 0, stream>>>(
            hb, wql, qkvb, nullptr, nullptr,
            MTOK, 3 * DMODEL, DMODEL, DMODEL, DMODEL, 3 * DMODEL,
            0, 0, 0, 1.0f, 1);

        // Vt[z] = V^T
        tcvt_k<short><<<dim3(1, 16, BBATCH * NHEAD), blk, 0, stream>>>(
            qkvb + 2 * DMODEL, Vt, 3 * DMODEL, TSEQ, NHEAD,
            (long long)TSEQ * 3 * DMODEL, HDIM,
            (long long)NHEAD * HDIM * TSEQ, (long long)HDIM * TSEQ);

        // fused attention -> hb (bf16)
        flash_k<<<dim3(8, BBATCH * NHEAD), blk, 0, stream>>>(qkvb, Vt, hb);

        // x += attn @ Wout + b
        gemm_k<64, 2><<<dim3(16, 16, 1), blk, 0, stream>>>(
            hb, wol, x, outb + l * DMODEL, x,
            MTOK, DMODEL, DMODEL, DMODEL, DMODEL, DMODEL,
            0, 0, 0, 1.0f, 1);

        ln_k<<<MTOK / 4, blk, 0, stream>>>(x, ln2w + l * DMODEL, ln2b + l * DMODEL, hb);

        // g = gelu(ln2 @ Wfc1 + b) -> bf16
        gemm_k<128, 3><<<dim3(32, 16, 1), blk, 0, stream>>>(
            hb, w1l, g, fc1b + (long long)l * 4 * DMODEL, nullptr,
            MTOK, 4 * DMODEL, DMODEL, DMODEL, DMODEL, 4 * DMODEL,
            0, 0, 0, 1.0f, 1);

        // fc2 split-K=2: partials, then fused reduce (x += p0+p1+bias)
        gemm_k<128, 0><<<dim3(8, 16, 2), blk, 0, stream>>>(
            g, w2l, fp, nullptr, nullptr,
            MTOK, DMODEL, 2048, 4 * DMODEL, 4 * DMODEL, DMODEL,
            2048, 2048, (long long)MTOK * DMODEL, 1.0f, 1);
        freduce_k<<<MTOK, blk, 0, stream>>>(
            fp, fp + (long long)MTOK * DMODEL, fc2b + l * DMODEL, x);
    }

    ln_k<<<MTOK / 4, blk, 0, stream>>>(x, lnfw, lnfb, hb);

    // tok_emb -> bf16 (tokb aliases dead activation buffers)
    cvt_k<<<2048, blk, 0, stream>>>(tok, tokb, NVOCAB * DMODEL / 4);

    // logits = lnf @ tok_emb^T via 256x256 8-phase kernel (grid = 125*8)
    gemm256_k<<<dim3((NVOCAB / 256) * (MTOK / 256)), dim3(512), 131072, stream>>>(
        hb, tokb, out, DMODEL, DMODEL, DMODEL, NVOCAB, NVOCAB / 256);
}

// Round 7
// 1675.488 us; speedup vs baseline: 2.6546x; 1.0657x over previous
//
#include <hip/hip_runtime.h>
#include <hip/hip_bf16.h>
#include <math.h>

// ---------------------------------------------------------------------------
// GPT forward, round 7: double-buffered 2-phase gemm_k (stage t+1 overlaps
// compute t, one barrier/tile), out-proj split-K=2 @BN=128, fused
// reduce+residual+LayerNorm kernel (kills all standalone LN launches),
// embed+LN fusion.
// ---------------------------------------------------------------------------

#define DEV_INLINE __device__ __forceinline__

typedef float  f32x4  __attribute__((ext_vector_type(4)));
typedef __bf16 bf16x8 __attribute__((ext_vector_type(8)));
typedef short  s16x4  __attribute__((ext_vector_type(4)));
typedef short  s16x8  __attribute__((ext_vector_type(8)));
typedef unsigned int u32x4 __attribute__((ext_vector_type(4)));

#define BBATCH 2
#define TSEQ   1024
#define DMODEL 1024
#define NHEAD  16
#define HDIM   64
#define NLAYER 8
#define NVOCAB 32000
#define MTOK   (BBATCH*TSEQ)   // 2048

DEV_INLINE short f2bf(float f) {
    __bf16 h = (__bf16)f;
    union { __bf16 h; short s; } u; u.h = h; return u.s;
}

typedef const __attribute__((address_space(1))) unsigned int* gas_t;
typedef __attribute__((address_space(3))) unsigned int* las_t;
DEV_INLINE void llds16(const void* g, void* l) {
    __builtin_amdgcn_global_load_lds((gas_t)g, (las_t)l, 16, 0, 0);
}

#define BAR()  asm volatile("s_barrier" ::: "memory")
#define VMW4() asm volatile("s_waitcnt vmcnt(4)" ::: "memory")
#define VMW2() asm volatile("s_waitcnt vmcnt(2)" ::: "memory")
#define VMW0() asm volatile("s_waitcnt vmcnt(0)" ::: "memory")

DEV_INLINE float block_sum(float v) {
    __shared__ float sb[4];
    #pragma unroll
    for (int o = 32; o > 0; o >>= 1) v += __shfl_down(v, o, 64);
    if ((threadIdx.x & 63) == 0) sb[threadIdx.x >> 6] = v;
    __syncthreads();
    float r = sb[0] + sb[1] + sb[2] + sb[3];
    __syncthreads();
    return r;
}

// ---------------------------------------------------------------------------
// Flash attention (unchanged from round 6): grid (8 q-blocks, 32 bh),
// 256 threads; KV tiles 128; reg-prefetch of next K/V tile.
// ---------------------------------------------------------------------------
__global__ __launch_bounds__(256) void flash_k(
    const short* __restrict__ qkv, const short* __restrict__ Vt,
    short* __restrict__ O)
{
    const int qb = blockIdx.x;          // 0..7
    const int z  = blockIdx.y;          // 0..31
    const int zb = z >> 4, zh = z & 15;

    __shared__ short Qs[128 * 64];
    __shared__ short KP[128 * 136];
    __shared__ short Vs[64 * 128];

    const int tid  = threadIdx.x;
    const int w    = tid >> 6, lane = tid & 63;
    const int lr   = lane & 15, kg = lane >> 4;

    const long long qbase = (long long)zb * TSEQ * 3072;
    const short* Qg = qkv + qbase + zh * HDIM;
    const short* Kg = qkv + qbase + DMODEL + zh * HDIM;
    const short* Vg = Vt + (long long)z * (HDIM * TSEQ);

    const int sr   = tid >> 3, pc = tid & 7;
    const int lc   = pc ^ (sr & 7);
    const int sr16 = tid >> 4, pc16 = tid & 15;

    {
        const short* qp = Qg + (long long)(qb * 128 + sr) * 3072 + lc * 8;
        const short* kp = Kg + (long long)(0 + sr) * 3072 + lc * 8;
        #pragma unroll
        for (int it = 0; it < 4; ++it) {
            llds16(qp + (long long)it * 32 * 3072, Qs + tid * 8 + it * 2048);
            llds16(kp + (long long)it * 32 * 3072, KP + tid * 8 + it * 2048);
        }
        #pragma unroll
        for (int it = 0; it < 4; ++it) {
            const int r = it * 16 + sr16;
            const int lc2 = pc16 ^ (r & 7);
            llds16(Vg + (long long)r * TSEQ + 0 + lc2 * 8, Vs + tid * 8 + it * 2048);
        }
    }
    __syncthreads();
    bf16x8 afq[2][2];
    #pragma unroll
    for (int s = 0; s < 2; ++s)
        #pragma unroll
        for (int i = 0; i < 2; ++i) {
            const int r = w * 32 + i * 16 + lr;
            afq[s][i] = *(const bf16x8*)&Qs[r * 64 + (((s * 4 + kg) ^ (r & 7)) << 3)];
        }

    f32x4 aco[2][4] = {};
    float m_[2][4], l_[2][4];
    #pragma unroll
    for (int i = 0; i < 2; ++i)
        #pragma unroll
        for (int p = 0; p < 4; ++p) { m_[i][p] = -1e30f; l_[i][p] = 0.f; }

    const int nt = qb + 1;
    for (int t = 0; t < nt; ++t) {
        u32x4 kpre[4], vpre[4];
        const bool nx = (t + 1 < nt);
        if (nx) {
            const int kn = (t + 1) * 128;
            #pragma unroll
            for (int it = 0; it < 4; ++it)
                kpre[it] = *(const u32x4*)(Kg + (long long)(kn + sr + it * 32) * 3072 + lc * 8);
            #pragma unroll
            for (int it = 0; it < 4; ++it) {
                const int r = it * 16 + sr16;
                const int lc2 = pc16 ^ (r & 7);
                vpre[it] = *(const u32x4*)(Vg + (long long)r * TSEQ + kn + lc2 * 8);
            }
            __builtin_amdgcn_sched_barrier(0);
        }

        f32x4 acs[2][8] = {};
        #pragma unroll
        for (int s = 0; s < 2; ++s)
            #pragma unroll
            for (int j = 0; j < 8; ++j) {
                const int rk = j * 16 + lr;
                bf16x8 bk = *(const bf16x8*)&KP[rk * 64 + (((s * 4 + kg) ^ (rk & 7)) << 3)];
                #pragma unroll
                for (int i = 0; i < 2; ++i)
                    acs[i][j] = __builtin_amdgcn_mfma_f32_16x16x32_bf16(
                        afq[s][i], bk, acs[i][j], 0, 0, 0);
            }

        #pragma unroll
        for (int i = 0; i < 2; ++i)
            #pragma unroll
            for (int j = 0; j < 8; ++j)
                #pragma unroll
                for (int p = 0; p < 4; ++p) {
                    float v = acs[i][j][p] * 0.125f;
                    if (t == qb && (j * 16 + lr) > (w * 32 + i * 16 + kg * 4 + p))
                        v = -1e30f;
                    acs[i][j][p] = v;
                }

        float sc[2][4];
        #pragma unroll
        for (int i = 0; i < 2; ++i)
            #pragma unroll
            for (int p = 0; p < 4; ++p) {
                float r = acs[i][0][p];
                #pragma unroll
                for (int j = 1; j < 8; ++j) r = fmaxf(r, acs[i][j][p]);
                r = fmaxf(r, __shfl_xor(r, 1, 64));
                r = fmaxf(r, __shfl_xor(r, 2, 64));
                r = fmaxf(r, __shfl_xor(r, 4, 64));
                r = fmaxf(r, __shfl_xor(r, 8, 64));
                const float mn = fmaxf(m_[i][p], r);
                sc[i][p] = __expf(m_[i][p] - mn);
                m_[i][p] = mn;
            }
        #pragma unroll
        for (int i = 0; i < 2; ++i)
            #pragma unroll
            for (int j = 0; j < 8; ++j)
                #pragma unroll
                for (int p = 0; p < 4; ++p)
                    acs[i][j][p] = __expf(acs[i][j][p] - m_[i][p]);
        #pragma unroll
        for (int i = 0; i < 2; ++i)
            #pragma unroll
            for (int p = 0; p < 4; ++p) {
                float s = 0.f;
                #pragma unroll
                for (int j = 0; j < 8; ++j) s += acs[i][j][p];
                s += __shfl_xor(s, 1, 64);
                s += __shfl_xor(s, 2, 64);
                s += __shfl_xor(s, 4, 64);
                s += __shfl_xor(s, 8, 64);
                l_[i][p] = l_[i][p] * sc[i][p] + s;
            }
        #pragma unroll
        for (int i = 0; i < 2; ++i)
            #pragma unroll
            for (int j2 = 0; j2 < 4; ++j2)
                #pragma unroll
                for (int p = 0; p < 4; ++p)
                    aco[i][j2][p] *= sc[i][p];

        __syncthreads();

        #pragma unroll
        for (int i = 0; i < 2; ++i)
            #pragma unroll
            for (int j = 0; j < 8; ++j)
                #pragma unroll
                for (int p = 0; p < 4; ++p)
                    KP[(w * 32 + i * 16 + kg * 4 + p) * 136 + j * 16 + lr] =
                        f2bf(acs[i][j][p]);
        __syncthreads();

        #pragma unroll
        for (int ks = 0; ks < 4; ++ks) {
            bf16x8 pa[2], pb[4];
            #pragma unroll
            for (int i = 0; i < 2; ++i)
                pa[i] = *(const bf16x8*)&KP[(w * 32 + i * 16 + lr) * 136 + ks * 32 + kg * 8];
            #pragma unroll
            for (int j2 = 0; j2 < 4; ++j2) {
                const int d = j2 * 16 + lr;
                pb[j2] = *(const bf16x8*)&Vs[d * 128 + (((ks * 4 + kg) ^ (d & 7)) << 3)];
            }
            #pragma unroll
            for (int i = 0; i < 2; ++i)
                #pragma unroll
                for (int j2 = 0; j2 < 4; ++j2)
                    aco[i][j2] = __builtin_amdgcn_mfma_f32_16x16x32_bf16(
                        pa[i], pb[j2], aco[i][j2], 0, 0, 0);
        }
        __syncthreads();

        if (nx) {
            #pragma unroll
            for (int it = 0; it < 4; ++it)
                *(u32x4*)(KP + tid * 8 + it * 2048) = kpre[it];
            #pragma unroll
            for (int it = 0; it < 4; ++it)
                *(u32x4*)(Vs + tid * 8 + it * 2048) = vpre[it];
            __syncthreads();
        }
    }

    #pragma unroll
    for (int i = 0; i < 2; ++i)
        #pragma unroll
        for (int j2 = 0; j2 < 4; ++j2)
            #pragma unroll
            for (int p = 0; p < 4; ++p) {
                const int row = zb * TSEQ + qb * 128 + w * 32 + i * 16 + kg * 4 + p;
                const int col = zh * HDIM + j2 * 16 + lr;
                O[(long long)row * DMODEL + col] = f2bf(aco[i][j2][p] / l_[i][p]);
            }
}

// ---------------------------------------------------------------------------
// 256x256x(BK=64) 8-wave 8-phase GEMM, f32 output (lm_head). Unchanged.
// ---------------------------------------------------------------------------
__global__ __launch_bounds__(512, 2) void gemm256_k(
    const short* __restrict__ A, const short* __restrict__ B,
    float* __restrict__ C, int K, int lda, int ldb, int ldc, int gx)
{
    extern __shared__ short smem[];

    const int nwg = gridDim.x;
    int wg = blockIdx.x;
    int sw = (wg & 7) * (nwg >> 3) + (wg >> 3);
    const int bx = sw >> 3, by = sw & 7;
    const int bn0 = bx * 256, bm0 = by * 256;

    const int tid  = threadIdx.x;
    const int w    = tid >> 6, lane = tid & 63;
    const int wm   = w >> 2, wn = w & 3;
    const int lr   = lane & 15, kg = lane >> 4;

    const int r0  = tid >> 3;
    const int pc  = tid & 7;
    const int lc0 = pc ^ (r0 & 7);
    const int r1  = r0 + 64;
    const int lc1 = pc ^ (r1 & 7);

    f32x4 acc[2][2][4][2] = {};
    const int nk = K >> 6;

    auto stage = [&](int buf, int isA, int h, int kk) {
        const short* gp = isA ? A : B;
        const int    ld = isA ? lda : ldb;
        const long long rb = (long long)((isA ? bm0 : bn0) + h * 128);
        short* lp = smem + buf * 32768 + (isA ? 0 : 16384) + h * 8192;
        llds16(gp + (rb + r0) * ld + kk + lc0 * 8, lp + w * 512);
        llds16(gp + (rb + r1) * ld + kk + lc1 * 8, lp + 4096 + w * 512);
    };

#define PHASE(BUF, QM, QN, ISA, H, DOWAIT)                                      \
    do {                                                                        \
        const short* Ah = smem + (BUF) * 32768 + (QM) * 8192;                   \
        const short* Bh = smem + (BUF) * 32768 + 16384 + (QN) * 8192;           \
        bf16x8 af[2][4], bfr[2][2];                                             \
        _Pragma("unroll")                                                       \
        for (int s2 = 0; s2 < 2; ++s2) {                                        \
            _Pragma("unroll")                                                   \
            for (int i = 0; i < 4; ++i) {                                       \
                const int ra = wm * 64 + i * 16 + lr;                           \
                af[s2][i] = *(const bf16x8*)                                    \
                    &Ah[ra * 64 + (((s2 * 4 + kg) ^ (ra & 7)) << 3)];           \
            }                                                                   \
            _Pragma("unroll")                                                   \
            for (int j = 0; j < 2; ++j) {                                       \
                const int rb2 = wn * 32 + j * 16 + lr;                          \
                bfr[s2][j] = *(const bf16x8*)                                   \
                    &Bh[rb2 * 64 + (((s2 * 4 + kg) ^ (rb2 & 7)) << 3)];         \
            }                                                                   \
        }                                                                       \
        if (pf) stage(nb, ISA, H, kk);                                          \
        BAR();                                                                  \
        __builtin_amdgcn_s_setprio(1);                                          \
        _Pragma("unroll")                                                       \
        for (int s2 = 0; s2 < 2; ++s2)                                          \
            _Pragma("unroll")                                                   \
            for (int i = 0; i < 4; ++i)                                         \
                _Pragma("unroll")                                               \
                for (int j = 0; j < 2; ++j)                                     \
                    acc[QM][QN][i][j] = __builtin_amdgcn_mfma_f32_16x16x32_bf16(\
                        af[s2][i], bfr[s2][j], acc[QM][QN][i][j], 0, 0, 0);     \
        __builtin_amdgcn_s_setprio(0);                                          \
        DOWAIT;                                                                 \
        BAR();                                                                  \
    } while (0)

    stage(0, 1, 0, 0);
    stage(0, 0, 0, 0);
    stage(0, 1, 1, 0);
    stage(0, 0, 1, 0);
    if (nk > 1) { VMW4(); } else { VMW0(); }
    BAR();

    for (int t = 0; t < nk - 1; ++t) {
        const int  buf = t & 1, nb = buf ^ 1;
        const int  kk  = (t + 1) << 6;
        const bool pf  = true;
        PHASE(buf, 0, 0, 1, 0, VMW4());
        PHASE(buf, 1, 0, 0, 0, VMW4());
        PHASE(buf, 1, 1, 1, 1, (void)0);
        PHASE(buf, 0, 1, 0, 1, VMW4());
    }
    {
        const int  buf = (nk - 1) & 1, nb = buf ^ 1; (void)nb;
        const int  kk  = 0;
        const bool pf  = false;
        PHASE(buf, 0, 0, 1, 0, VMW2());
        PHASE(buf, 1, 0, 0, 0, VMW0());
        PHASE(buf, 1, 1, 1, 1, (void)0);
        PHASE(buf, 0, 1, 0, 1, (void)0);
    }
#undef PHASE

    #pragma unroll
    for (int qm = 0; qm < 2; ++qm)
        #pragma unroll
        for (int qn = 0; qn < 2; ++qn)
            #pragma unroll
            for (int i = 0; i < 4; ++i)
                #pragma unroll
                for (int j = 0; j < 2; ++j) {
                    const int gr = bm0 + qm * 128 + wm * 64 + i * 16 + kg * 4;
                    const int gc = bn0 + qn * 128 + wn * 32 + j * 16 + lr;
                    #pragma unroll
                    for (int p = 0; p < 4; ++p)
                        C[(long long)(gr + p) * ldc + gc] = acc[qm][qn][i][j][p];
                }
}

// ---------------------------------------------------------------------------
// 128x(BN) DOUBLE-BUFFERED 2-phase GEMM: stage(t+1) issued before compute(t),
// one __syncthreads per tile (its implicit vmcnt(0) drain is exactly the
// required wait). A bf16 [M][K], B bf16 [N][K]; z batches via sAz/sBz/sCz.
// EPI: 0=f32, 1=bf16*scale, 3=bf16 gelu(acc+bias).
// ---------------------------------------------------------------------------
template<int BN, int EPI>
__global__ __launch_bounds__(256) void gemm_k(
    const short* __restrict__ Ag, const short* __restrict__ Bg,
    void* __restrict__ Cg, const float* __restrict__ bias,
    int M, int N, int K, int lda, int ldb, int ldc,
    long long sAz, long long sBz, long long sCz,
    float scale, int swz)
{
    int bx = blockIdx.x, by = blockIdx.y;
    if (swz) {
        const int gx = gridDim.x;
        const int nwg = gx * gridDim.y;
        if ((nwg & 7) == 0) {
            int wg = by * gx + bx;
            int wg2 = (wg & 7) * (nwg >> 3) + (wg >> 3);
            bx = wg2 % gx; by = wg2 / gx;
        }
    }
    const int bn0 = bx * BN, bm0 = by * 128;
    const int zz = blockIdx.z;

    const short* A = Ag + zz * sAz;
    const short* B = Bg + zz * sBz;

    __shared__ short Als[2][128 * 64];
    __shared__ short Bls[2][BN * 64];

    const int tid  = threadIdx.x;
    const int lane = tid & 63;
    const int wave = tid >> 6;
    constexpr int WMS = (BN == 128) ? 64 : 32;
    constexpr int MI  = (BN == 128) ? 4 : 2;
    constexpr int NJ  = 4;
    const int wm = (BN == 128) ? (wave >> 1) : wave;
    const int wn = (BN == 128) ? (wave & 1) : 0;
    const int lr = lane & 15, kg = lane >> 4;
    const int xv = (lr & 7) << 4;

    const int sr = tid >> 3;
    const int sc = (tid & 7) ^ (sr & 7);
    const short* aP = A + (long long)(bm0 + sr) * lda + sc * 8;
    const short* bP = B + (long long)(bn0 + sr) * ldb + sc * 8;

    f32x4 acc[MI][NJ] = {};
    const int nk = K >> 6;

    auto stage = [&](int buf, int kt) {
        const int k0 = kt << 6;
        short* aL = &Als[buf][wave * 512];
        short* bL = &Bls[buf][wave * 512];
        #pragma unroll
        for (int it = 0; it < 4; ++it)
            llds16(aP + (long long)it * 32 * lda + k0, aL + it * 2048);
        #pragma unroll
        for (int it = 0; it < BN / 32; ++it)
            llds16(bP + (long long)it * 32 * ldb + k0, bL + it * 2048);
    };

    stage(0, 0);
    __syncthreads();                      // drains vmcnt(0) + barrier

    for (int kt = 0; kt < nk; ++kt) {
        const int cb = kt & 1;
        if (kt + 1 < nk) stage(cb ^ 1, kt + 1);

        #pragma unroll
        for (int s = 0; s < 2; ++s) {
            const int ofs = (((s << 6) | (kg << 4)) ^ xv) >> 1;
            bf16x8 af[MI], bf[NJ];
            #pragma unroll
            for (int i = 0; i < MI; ++i)
                af[i] = *(const bf16x8*)&Als[cb][(wm * WMS + i * 16 + lr) * 64 + ofs];
            #pragma unroll
            for (int j = 0; j < NJ; ++j)
                bf[j] = *(const bf16x8*)&Bls[cb][(wn * 64 + j * 16 + lr) * 64 + ofs];
            #pragma unroll
            for (int i = 0; i < MI; ++i)
                #pragma unroll
                for (int j = 0; j < NJ; ++j)
                    acc[i][j] = __builtin_amdgcn_mfma_f32_16x16x32_bf16(
                        af[i], bf[j], acc[i][j], 0, 0, 0);
        }
        __syncthreads();                  // implicit vmcnt(0): stage landed;
                                          // barrier: reads of cb done
    }

    short* Cs = (short*)Cg + zz * sCz;
    float* Cf = (float*)Cg + zz * sCz;
    #pragma unroll
    for (int i = 0; i < MI; ++i) {
        #pragma unroll
        for (int j = 0; j < NJ; ++j) {
            const int gr = bm0 + wm * WMS + i * 16 + kg * 4;
            const int gc = bn0 + wn * 64 + j * 16 + lr;
            #pragma unroll
            for (int p = 0; p < 4; ++p) {
                const long long off = (long long)(gr + p) * ldc + gc;
                float v = acc[i][j][p];
                if (EPI == 0) {
                    Cf[off] = v;
                } else if (EPI == 1) {
                    Cs[off] = f2bf(v * scale);
                } else {
                    v += bias[gc];
                    v = 0.5f * v * (1.0f + erff(v * 0.70710678118654752f));
                    Cs[off] = f2bf(v);
                }
            }
        }
    }
}

// ---------------------------------------------------------------------------
// fused split-K reduce + residual + LayerNorm. One block per row:
//   v = x + p0 + p1 + bias;  x = v;  o = LN(v; lw, lb) -> bf16
// ---------------------------------------------------------------------------
__global__ __launch_bounds__(256) void fredln_k(
    const float* __restrict__ p0, const float* __restrict__ p1,
    const float* __restrict__ bias, float* __restrict__ x,
    const float* __restrict__ lw, const float* __restrict__ lb,
    short* __restrict__ o)
{
    const int row = blockIdx.x;
    const long long base = (long long)row * DMODEL;
    const int i = threadIdx.x * 4;
    float4 a  = *(const float4*)&p0[base + i];
    float4 b  = *(const float4*)&p1[base + i];
    float4 c  = *(const float4*)&x[base + i];
    float4 bb = *(const float4*)&bias[i];
    float4 v;
    v.x = c.x + a.x + b.x + bb.x;
    v.y = c.y + a.y + b.y + bb.y;
    v.z = c.z + a.z + b.z + bb.z;
    v.w = c.w + a.w + b.w + bb.w;
    *(float4*)&x[base + i] = v;
    float s  = v.x + v.y + v.z + v.w;
    float s2 = v.x * v.x + v.y * v.y + v.z * v.z + v.w * v.w;
    s  = block_sum(s);
    s2 = block_sum(s2);
    const float mean = s * (1.0f / DMODEL);
    const float var  = s2 * (1.0f / DMODEL) - mean * mean;
    const float rs   = rsqrtf(var + 1e-5f);
    float4 wv = *(const float4*)&lw[i];
    float4 bv = *(const float4*)&lb[i];
    s16x4 ov;
    ov[0] = f2bf((v.x - mean) * rs * wv.x + bv.x);
    ov[1] = f2bf((v.y - mean) * rs * wv.y + bv.y);
    ov[2] = f2bf((v.z - mean) * rs * wv.z + bv.z);
    ov[3] = f2bf((v.w - mean) * rs * wv.w + bv.w);
    *(s16x4*)&o[base + i] = ov;
}

// embed + LN(layer-0 ln1). One block per row.
__global__ __launch_bounds__(256) void embedln_k(
    const int* __restrict__ ids, const float* __restrict__ tok,
    const float* __restrict__ pos, float* __restrict__ x,
    const float* __restrict__ lw, const float* __restrict__ lb,
    short* __restrict__ o)
{
    const int row = blockIdx.x;
    const int t   = row & (TSEQ - 1);
    const int id  = ids[row];
    const int i   = threadIdx.x * 4;
    const long long base = (long long)row * DMODEL;
    float4 a = *(const float4*)&tok[(long long)id * DMODEL + i];
    float4 p = *(const float4*)&pos[(long long)t * DMODEL + i];
    float4 v;
    v.x = a.x + p.x; v.y = a.y + p.y; v.z = a.z + p.z; v.w = a.w + p.w;
    *(float4*)&x[base + i] = v;
    float s  = v.x + v.y + v.z + v.w;
    float s2 = v.x * v.x + v.y * v.y + v.z * v.z + v.w * v.w;
    s  = block_sum(s);
    s2 = block_sum(s2);
    const float mean = s * (1.0f / DMODEL);
    const float var  = s2 * (1.0f / DMODEL) - mean * mean;
    const float rs   = rsqrtf(var + 1e-5f);
    float4 wv = *(const float4*)&lw[i];
    float4 bv = *(const float4*)&lb[i];
    s16x4 ov;
    ov[0] = f2bf((v.x - mean) * rs * wv.x + bv.x);
    ov[1] = f2bf((v.y - mean) * rs * wv.y + bv.y);
    ov[2] = f2bf((v.z - mean) * rs * wv.z + bv.z);
    ov[3] = f2bf((v.w - mean) * rs * wv.w + bv.w);
    *(s16x4*)&o[base + i] = ov;
}

// ---------------------------------------------------------------------------
// transpose-convert core (64x64 tile)
template<typename T>
DEV_INLINE void tcvt_body(const T* sp, short* dp, int lds_, int ldd,
                          int bx, int by, short (*ls)[68], int t)
{
    const int tr0 = by * 64, tc0 = bx * 64;
    const int rr = t >> 4, cc = (t & 15) * 4;
    #pragma unroll
    for (int q = 0; q < 4; ++q) {
        const int r = q * 16 + rr;
        if constexpr (sizeof(T) == 4) {
            float4 v = *(const float4*)&sp[(long long)(tr0 + r) * lds_ + tc0 + cc];
            ls[cc + 0][r] = f2bf(v.x); ls[cc + 1][r] = f2bf(v.y);
            ls[cc + 2][r] = f2bf(v.z); ls[cc + 3][r] = f2bf(v.w);
        } else {
            s16x4 v = *(const s16x4*)&sp[(long long)(tr0 + r) * lds_ + tc0 + cc];
            ls[cc + 0][r] = v[0]; ls[cc + 1][r] = v[1];
            ls[cc + 2][r] = v[2]; ls[cc + 3][r] = v[3];
        }
    }
    __syncthreads();
    #pragma unroll
    for (int q = 0; q < 4; ++q) {
        const int c = q * 16 + rr;
        s16x4 v;
        v[0] = ls[c][cc]; v[1] = ls[c][cc + 1]; v[2] = ls[c][cc + 2]; v[3] = ls[c][cc + 3];
        *(s16x4*)&dp[(long long)(tc0 + c) * ldd + tr0 + cc] = v;
    }
}

template<typename T>
__global__ __launch_bounds__(256) void tcvt_k(
    const T* __restrict__ src, short* __restrict__ dst,
    int lds_, int ldd, int Hdiv,
    long long sSb, long long sSh, long long sDb, long long sDh)
{
    __shared__ short ls[64][68];
    const int z = blockIdx.z, zb = z / Hdiv, zh = z - zb * Hdiv;
    tcvt_body<T>(src + zb * sSb + zh * sSh, dst + zb * sDb + zh * sDh,
                 lds_, ldd, blockIdx.x, blockIdx.y, ls, threadIdx.x);
}

// merged per-layer weight convert (!big path): 3072 blocks
__global__ __launch_bounds__(256) void wcvt_k(
    const float* __restrict__ qw, const float* __restrict__ ow,
    const float* __restrict__ f1, const float* __restrict__ f2,
    short* __restrict__ wq, short* __restrict__ wo,
    short* __restrict__ w1, short* __restrict__ w2)
{
    __shared__ short ls[64][68];
    const int id = blockIdx.x;
    const float* src; short* dst; int lds_, ldd, bx, by;
    if (id < 768)       { src = qw; dst = wq; lds_ = 3072; ldd = 1024; bx = id % 48;  by = id / 48; }
    else if (id < 1024) { int i = id - 768;  src = ow; dst = wo; lds_ = 1024; ldd = 1024; bx = i % 16; by = i / 16; }
    else if (id < 2048) { int i = id - 1024; src = f1; dst = w1; lds_ = 4096; ldd = 1024; bx = i % 64; by = i / 64; }
    else                { int i = id - 2048; src = f2; dst = w2; lds_ = 1024; ldd = 4096; bx = i % 16; by = i / 16; }
    tcvt_body<float>(src, dst, lds_, ldd, bx, by, ls, threadIdx.x);
}

// plain fp32 -> bf16 convert (n4 = count/4)
__global__ __launch_bounds__(256) void cvt_k(
    const float* __restrict__ s, short* __restrict__ d, int n4)
{
    int i = blockIdx.x * 256 + threadIdx.x;
    const int stride = gridDim.x * 256;
    for (; i < n4; i += stride) {
        float4 v = *(const float4*)&s[(long long)i * 4];
        s16x4 o = { f2bf(v.x), f2bf(v.y), f2bf(v.z), f2bf(v.w) };
        *(s16x4*)&d[(long long)i * 4] = o;
    }
}

// ---------------------------------------------------------------------------
extern "C" void kernel_launch(void* const* d_in, const int* in_sizes, int n_in,
                              void* d_out, int out_size, void* d_ws, size_t ws_size,
                              hipStream_t stream)
{
    const int*   ids  = (const int*)  d_in[0];
    const float* tok  = (const float*)d_in[1];
    const float* pos  = (const float*)d_in[2];
    const float* ln1w = (const float*)d_in[3];
    const float* ln1b = (const float*)d_in[4];
    const float* qkvw = (const float*)d_in[5];
    const float* outw = (const float*)d_in[6];
    const float* outb = (const float*)d_in[7];
    const float* ln2w = (const float*)d_in[8];
    const float* ln2b = (const float*)d_in[9];
    const float* fc1w = (const float*)d_in[10];
    const float* fc1b = (const float*)d_in[11];
    const float* fc2w = (const float*)d_in[12];
    const float* fc2b = (const float*)d_in[13];
    const float* lnfw = (const float*)d_in[14];
    const float* lnfb = (const float*)d_in[15];
    float* out = (float*)d_out;

    char* ws = (char*)d_ws;
    const size_t MB = 1024 * 1024;
    float* x    = (float*)(ws);             //  0-8   f32 residual
    short* hb   = (short*)(ws + 8  * MB);   //  8-12  bf16 [2048][1024]
    short* qkvb = (short*)(ws + 12 * MB);   // 12-24  bf16 [2048][3072]
    short* g    = (short*)(ws + 24 * MB);   // 24-40  bf16 [2048][4096]
    short* Vt   = (short*)(ws + 40 * MB);   // 40-44  bf16 [32][64][1024]
    float* fp   = (float*)(ws + 44 * MB);   // 44-60  f32 [2][2048][1024] partials
    short* tokb = (short*)(ws + 12 * MB);   // lm_head phase only (aliases dead bufs)

    const bool big = ws_size >= (size_t)267 * MB;
    short* wq = (short*)(ws + 75 * MB);
    short *wo, *w1, *w2;
    if (big) {
        wo = (short*)(ws + 123 * MB);
        w1 = (short*)(ws + 139 * MB);
        w2 = (short*)(ws + 203 * MB);
    } else {
        wo = (short*)(ws + 81 * MB);
        w1 = (short*)(ws + 83 * MB);
        w2 = (short*)(ws + 91 * MB);
    }

    const long long LWQ = 3072LL * 1024, LWO = 1024LL * 1024;
    const long long LW1 = 4096LL * 1024, LW2 = 1024LL * 4096;
    const long long MD  = (long long)MTOK * DMODEL;

    hipFuncSetAttribute((const void*)gemm256_k,
                        hipFuncAttributeMaxDynamicSharedMemorySize, 131072);

    dim3 blk(256);
    // x = tok_emb[ids] + pos ; hb = LN1_0(x)
    embedln_k<<<MTOK, blk, 0, stream>>>(ids, tok, pos, x, ln1w, ln1b, hb);

    if (big) {
        tcvt_k<float><<<dim3(48, 16, 8), blk, 0, stream>>>(qkvw, wq, 3072, 1024, 1, LWQ, 0, LWQ, 0);
        tcvt_k<float><<<dim3(16, 16, 8), blk, 0, stream>>>(outw, wo, 1024, 1024, 1, LWO, 0, LWO, 0);
        tcvt_k<float><<<dim3(64, 16, 8), blk, 0, stream>>>(fc1w, w1, 4096, 1024, 1, LW1, 0, LW1, 0);
        tcvt_k<float><<<dim3(16, 64, 8), blk, 0, stream>>>(fc2w, w2, 1024, 4096, 1, LW2, 0, LW2, 0);
    }

    for (int l = 0; l < NLAYER; ++l) {
        short* wql = wq + (big ? l * LWQ : 0);
        short* wol = wo + (big ? l * LWO : 0);
        short* w1l = w1 + (big ? l * LW1 : 0);
        short* w2l = w2 + (big ? l * LW2 : 0);
        if (!big)
            wcvt_k<<<3072, blk, 0, stream>>>(
                qkvw + l * LWQ, outw + l * LWO, fc1w + l * LW1, fc2w + l * LW2,
                wql, wol, w1l, w2l);

        // qkv = ln1 @ Wqkv -> bf16
        gemm_k<128, 1><<<dim3(24, 16, 1), blk, 0, stream>>>(
            hb, wql, qkvb, nullptr,
            MTOK, 3 * DMODEL, DMODEL, DMODEL, DMODEL, 3 * DMODEL,
            0, 0, 0, 1.0f, 1);

        // Vt[z] = V^T
        tcvt_k<short><<<dim3(1, 16, BBATCH * NHEAD), blk, 0, stream>>>(
            qkvb + 2 * DMODEL, Vt, 3 * DMODEL, TSEQ, NHEAD,
            (long long)TSEQ * 3 * DMODEL, HDIM,
            (long long)NHEAD * HDIM * TSEQ, (long long)HDIM * TSEQ);

        // fused attention -> hb (bf16)
        flash_k<<<dim3(8, BBATCH * NHEAD), blk, 0, stream>>>(qkvb, Vt, hb);

        // out-proj split-K=2 -> partials; then x += sum + bias, hb = LN2(x)
        gemm_k<128, 0><<<dim3(8, 16, 2), blk, 0, stream>>>(
            hb, wol, fp, nullptr,
            MTOK, DMODEL, 512, DMODEL, DMODEL, DMODEL,
            512, 512, MD, 1.0f, 1);
        fredln_k<<<MTOK, blk, 0, stream>>>(
            fp, fp + MD, outb + l * DMODEL, x,
            ln2w + l * DMODEL, ln2b + l * DMODEL, hb);

        // g = gelu(ln2 @ Wfc1 + b) -> bf16
        gemm_k<128, 3><<<dim3(32, 16, 1), blk, 0, stream>>>(
            hb, w1l, g, fc1b + (long long)l * 4 * DMODEL,
            MTOK, 4 * DMODEL, DMODEL, DMODEL, DMODEL, 4 * DMODEL,
            0, 0, 0, 1.0f, 1);

        // fc2 split-K=2 -> partials; then x += sum + bias, hb = LN1_{l+1}(x)
        // (for l==7 the "next LN" is the final lnf)
        gemm_k<128, 0><<<dim3(8, 16, 2), blk, 0, stream>>>(
            g, w2l, fp, nullptr,
            MTOK, DMODEL, 2048, 4 * DMODEL, 4 * DMODEL, DMODEL,
            2048, 2048, MD, 1.0f, 1);
        const float* nlw = (l < 7) ? ln1w + (l + 1) * DMODEL : lnfw;
        const float* nlb = (l < 7) ? ln1b + (l + 1) * DMODEL : lnfb;
        fredln_k<<<MTOK, blk, 0, stream>>>(
            fp, fp + MD, fc2b + l * DMODEL, x, nlw, nlb, hb);
    }

    // tok_emb -> bf16 (tokb aliases dead activation buffers)
    cvt_k<<<2048, blk, 0, stream>>>(tok, tokb, NVOCAB * DMODEL / 4);

    // logits = lnf @ tok_emb^T via 256x256 8-phase kernel (grid = 125*8)
    gemm256_k<<<dim3((NVOCAB / 256) * (MTOK / 256)), dim3(512), 131072, stream>>>(
        hb, tokb, out, DMODEL, DMODEL, DMODEL, NVOCAB, NVOCAB / 256);
}

// Round 8
// 1584.775 us; speedup vs baseline: 2.8066x; 1.0572x over previous
//
#include <hip/hip_runtime.h>
#include <hip/hip_bf16.h>
#include <math.h>

// ---------------------------------------------------------------------------
// GPT forward, round 8: qkv GEMM epilogue writes V transposed (kills tcvt),
// fc2 split-K=4 (2 blocks/CU), wave-per-row fused reduce+residual+LN.
// ---------------------------------------------------------------------------

#define DEV_INLINE __device__ __forceinline__

typedef float  f32x4  __attribute__((ext_vector_type(4)));
typedef __bf16 bf16x8 __attribute__((ext_vector_type(8)));
typedef short  s16x4  __attribute__((ext_vector_type(4)));
typedef short  s16x8  __attribute__((ext_vector_type(8)));
typedef unsigned int u32x4 __attribute__((ext_vector_type(4)));

#define BBATCH 2
#define TSEQ   1024
#define DMODEL 1024
#define NHEAD  16
#define HDIM   64
#define NLAYER 8
#define NVOCAB 32000
#define MTOK   (BBATCH*TSEQ)   // 2048

DEV_INLINE short f2bf(float f) {
    __bf16 h = (__bf16)f;
    union { __bf16 h; short s; } u; u.h = h; return u.s;
}

typedef const __attribute__((address_space(1))) unsigned int* gas_t;
typedef __attribute__((address_space(3))) unsigned int* las_t;
DEV_INLINE void llds16(const void* g, void* l) {
    __builtin_amdgcn_global_load_lds((gas_t)g, (las_t)l, 16, 0, 0);
}

#define BAR()  asm volatile("s_barrier" ::: "memory")
#define VMW4() asm volatile("s_waitcnt vmcnt(4)" ::: "memory")
#define VMW2() asm volatile("s_waitcnt vmcnt(2)" ::: "memory")
#define VMW0() asm volatile("s_waitcnt vmcnt(0)" ::: "memory")

DEV_INLINE float block_sum(float v) {
    __shared__ float sb[4];
    #pragma unroll
    for (int o = 32; o > 0; o >>= 1) v += __shfl_down(v, o, 64);
    if ((threadIdx.x & 63) == 0) sb[threadIdx.x >> 6] = v;
    __syncthreads();
    float r = sb[0] + sb[1] + sb[2] + sb[3];
    __syncthreads();
    return r;
}

// ---------------------------------------------------------------------------
// Flash attention (round-6 structure): grid (8 q-blocks, 32 bh), 256 threads;
// KV tiles 128; reg-prefetch of next K/V tile.
// ---------------------------------------------------------------------------
__global__ __launch_bounds__(256) void flash_k(
    const short* __restrict__ qkv, const short* __restrict__ Vt,
    short* __restrict__ O)
{
    const int qb = blockIdx.x;          // 0..7
    const int z  = blockIdx.y;          // 0..31
    const int zb = z >> 4, zh = z & 15;

    __shared__ short Qs[128 * 64];
    __shared__ short KP[128 * 136];
    __shared__ short Vs[64 * 128];

    const int tid  = threadIdx.x;
    const int w    = tid >> 6, lane = tid & 63;
    const int lr   = lane & 15, kg = lane >> 4;

    const long long qbase = (long long)zb * TSEQ * 3072;
    const short* Qg = qkv + qbase + zh * HDIM;
    const short* Kg = qkv + qbase + DMODEL + zh * HDIM;
    const short* Vg = Vt + (long long)z * (HDIM * TSEQ);

    const int sr   = tid >> 3, pc = tid & 7;
    const int lc   = pc ^ (sr & 7);
    const int sr16 = tid >> 4, pc16 = tid & 15;

    {
        const short* qp = Qg + (long long)(qb * 128 + sr) * 3072 + lc * 8;
        const short* kp = Kg + (long long)(0 + sr) * 3072 + lc * 8;
        #pragma unroll
        for (int it = 0; it < 4; ++it) {
            llds16(qp + (long long)it * 32 * 3072, Qs + tid * 8 + it * 2048);
            llds16(kp + (long long)it * 32 * 3072, KP + tid * 8 + it * 2048);
        }
        #pragma unroll
        for (int it = 0; it < 4; ++it) {
            const int r = it * 16 + sr16;
            const int lc2 = pc16 ^ (r & 7);
            llds16(Vg + (long long)r * TSEQ + 0 + lc2 * 8, Vs + tid * 8 + it * 2048);
        }
    }
    __syncthreads();
    bf16x8 afq[2][2];
    #pragma unroll
    for (int s = 0; s < 2; ++s)
        #pragma unroll
        for (int i = 0; i < 2; ++i) {
            const int r = w * 32 + i * 16 + lr;
            afq[s][i] = *(const bf16x8*)&Qs[r * 64 + (((s * 4 + kg) ^ (r & 7)) << 3)];
        }

    f32x4 aco[2][4] = {};
    float m_[2][4], l_[2][4];
    #pragma unroll
    for (int i = 0; i < 2; ++i)
        #pragma unroll
        for (int p = 0; p < 4; ++p) { m_[i][p] = -1e30f; l_[i][p] = 0.f; }

    const int nt = qb + 1;
    for (int t = 0; t < nt; ++t) {
        u32x4 kpre[4], vpre[4];
        const bool nx = (t + 1 < nt);
        if (nx) {
            const int kn = (t + 1) * 128;
            #pragma unroll
            for (int it = 0; it < 4; ++it)
                kpre[it] = *(const u32x4*)(Kg + (long long)(kn + sr + it * 32) * 3072 + lc * 8);
            #pragma unroll
            for (int it = 0; it < 4; ++it) {
                const int r = it * 16 + sr16;
                const int lc2 = pc16 ^ (r & 7);
                vpre[it] = *(const u32x4*)(Vg + (long long)r * TSEQ + kn + lc2 * 8);
            }
            __builtin_amdgcn_sched_barrier(0);
        }

        f32x4 acs[2][8] = {};
        #pragma unroll
        for (int s = 0; s < 2; ++s)
            #pragma unroll
            for (int j = 0; j < 8; ++j) {
                const int rk = j * 16 + lr;
                bf16x8 bk = *(const bf16x8*)&KP[rk * 64 + (((s * 4 + kg) ^ (rk & 7)) << 3)];
                #pragma unroll
                for (int i = 0; i < 2; ++i)
                    acs[i][j] = __builtin_amdgcn_mfma_f32_16x16x32_bf16(
                        afq[s][i], bk, acs[i][j], 0, 0, 0);
            }

        #pragma unroll
        for (int i = 0; i < 2; ++i)
            #pragma unroll
            for (int j = 0; j < 8; ++j)
                #pragma unroll
                for (int p = 0; p < 4; ++p) {
                    float v = acs[i][j][p] * 0.125f;
                    if (t == qb && (j * 16 + lr) > (w * 32 + i * 16 + kg * 4 + p))
                        v = -1e30f;
                    acs[i][j][p] = v;
                }

        float sc[2][4];
        #pragma unroll
        for (int i = 0; i < 2; ++i)
            #pragma unroll
            for (int p = 0; p < 4; ++p) {
                float r = acs[i][0][p];
                #pragma unroll
                for (int j = 1; j < 8; ++j) r = fmaxf(r, acs[i][j][p]);
                r = fmaxf(r, __shfl_xor(r, 1, 64));
                r = fmaxf(r, __shfl_xor(r, 2, 64));
                r = fmaxf(r, __shfl_xor(r, 4, 64));
                r = fmaxf(r, __shfl_xor(r, 8, 64));
                const float mn = fmaxf(m_[i][p], r);
                sc[i][p] = __expf(m_[i][p] - mn);
                m_[i][p] = mn;
            }
        #pragma unroll
        for (int i = 0; i < 2; ++i)
            #pragma unroll
            for (int j = 0; j < 8; ++j)
                #pragma unroll
                for (int p = 0; p < 4; ++p)
                    acs[i][j][p] = __expf(acs[i][j][p] - m_[i][p]);
        #pragma unroll
        for (int i = 0; i < 2; ++i)
            #pragma unroll
            for (int p = 0; p < 4; ++p) {
                float s = 0.f;
                #pragma unroll
                for (int j = 0; j < 8; ++j) s += acs[i][j][p];
                s += __shfl_xor(s, 1, 64);
                s += __shfl_xor(s, 2, 64);
                s += __shfl_xor(s, 4, 64);
                s += __shfl_xor(s, 8, 64);
                l_[i][p] = l_[i][p] * sc[i][p] + s;
            }
        #pragma unroll
        for (int i = 0; i < 2; ++i)
            #pragma unroll
            for (int j2 = 0; j2 < 4; ++j2)
                #pragma unroll
                for (int p = 0; p < 4; ++p)
                    aco[i][j2][p] *= sc[i][p];

        __syncthreads();

        #pragma unroll
        for (int i = 0; i < 2; ++i)
            #pragma unroll
            for (int j = 0; j < 8; ++j)
                #pragma unroll
                for (int p = 0; p < 4; ++p)
                    KP[(w * 32 + i * 16 + kg * 4 + p) * 136 + j * 16 + lr] =
                        f2bf(acs[i][j][p]);
        __syncthreads();

        #pragma unroll
        for (int ks = 0; ks < 4; ++ks) {
            bf16x8 pa[2], pb[4];
            #pragma unroll
            for (int i = 0; i < 2; ++i)
                pa[i] = *(const bf16x8*)&KP[(w * 32 + i * 16 + lr) * 136 + ks * 32 + kg * 8];
            #pragma unroll
            for (int j2 = 0; j2 < 4; ++j2) {
                const int d = j2 * 16 + lr;
                pb[j2] = *(const bf16x8*)&Vs[d * 128 + (((ks * 4 + kg) ^ (d & 7)) << 3)];
            }
            #pragma unroll
            for (int i = 0; i < 2; ++i)
                #pragma unroll
                for (int j2 = 0; j2 < 4; ++j2)
                    aco[i][j2] = __builtin_amdgcn_mfma_f32_16x16x32_bf16(
                        pa[i], pb[j2], aco[i][j2], 0, 0, 0);
        }
        __syncthreads();

        if (nx) {
            #pragma unroll
            for (int it = 0; it < 4; ++it)
                *(u32x4*)(KP + tid * 8 + it * 2048) = kpre[it];
            #pragma unroll
            for (int it = 0; it < 4; ++it)
                *(u32x4*)(Vs + tid * 8 + it * 2048) = vpre[it];
            __syncthreads();
        }
    }

    #pragma unroll
    for (int i = 0; i < 2; ++i)
        #pragma unroll
        for (int j2 = 0; j2 < 4; ++j2)
            #pragma unroll
            for (int p = 0; p < 4; ++p) {
                const int row = zb * TSEQ + qb * 128 + w * 32 + i * 16 + kg * 4 + p;
                const int col = zh * HDIM + j2 * 16 + lr;
                O[(long long)row * DMODEL + col] = f2bf(aco[i][j2][p] / l_[i][p]);
            }
}

// ---------------------------------------------------------------------------
// 256x256x(BK=64) 8-wave 8-phase GEMM, f32 output (lm_head). Unchanged.
// ---------------------------------------------------------------------------
__global__ __launch_bounds__(512, 2) void gemm256_k(
    const short* __restrict__ A, const short* __restrict__ B,
    float* __restrict__ C, int K, int lda, int ldb, int ldc, int gx)
{
    extern __shared__ short smem[];

    const int nwg = gridDim.x;
    int wg = blockIdx.x;
    int sw = (wg & 7) * (nwg >> 3) + (wg >> 3);
    const int bx = sw >> 3, by = sw & 7;
    const int bn0 = bx * 256, bm0 = by * 256;

    const int tid  = threadIdx.x;
    const int w    = tid >> 6, lane = tid & 63;
    const int wm   = w >> 2, wn = w & 3;
    const int lr   = lane & 15, kg = lane >> 4;

    const int r0  = tid >> 3;
    const int pc  = tid & 7;
    const int lc0 = pc ^ (r0 & 7);
    const int r1  = r0 + 64;
    const int lc1 = pc ^ (r1 & 7);

    f32x4 acc[2][2][4][2] = {};
    const int nk = K >> 6;

    auto stage = [&](int buf, int isA, int h, int kk) {
        const short* gp = isA ? A : B;
        const int    ld = isA ? lda : ldb;
        const long long rb = (long long)((isA ? bm0 : bn0) + h * 128);
        short* lp = smem + buf * 32768 + (isA ? 0 : 16384) + h * 8192;
        llds16(gp + (rb + r0) * ld + kk + lc0 * 8, lp + w * 512);
        llds16(gp + (rb + r1) * ld + kk + lc1 * 8, lp + 4096 + w * 512);
    };

#define PHASE(BUF, QM, QN, ISA, H, DOWAIT)                                      \
    do {                                                                        \
        const short* Ah = smem + (BUF) * 32768 + (QM) * 8192;                   \
        const short* Bh = smem + (BUF) * 32768 + 16384 + (QN) * 8192;           \
        bf16x8 af[2][4], bfr[2][2];                                             \
        _Pragma("unroll")                                                       \
        for (int s2 = 0; s2 < 2; ++s2) {                                        \
            _Pragma("unroll")                                                   \
            for (int i = 0; i < 4; ++i) {                                       \
                const int ra = wm * 64 + i * 16 + lr;                           \
                af[s2][i] = *(const bf16x8*)                                    \
                    &Ah[ra * 64 + (((s2 * 4 + kg) ^ (ra & 7)) << 3)];           \
            }                                                                   \
            _Pragma("unroll")                                                   \
            for (int j = 0; j < 2; ++j) {                                       \
                const int rb2 = wn * 32 + j * 16 + lr;                          \
                bfr[s2][j] = *(const bf16x8*)                                   \
                    &Bh[rb2 * 64 + (((s2 * 4 + kg) ^ (rb2 & 7)) << 3)];         \
            }                                                                   \
        }                                                                       \
        if (pf) stage(nb, ISA, H, kk);                                          \
        BAR();                                                                  \
        __builtin_amdgcn_s_setprio(1);                                          \
        _Pragma("unroll")                                                       \
        for (int s2 = 0; s2 < 2; ++s2)                                          \
            _Pragma("unroll")                                                   \
            for (int i = 0; i < 4; ++i)                                         \
                _Pragma("unroll")                                               \
                for (int j = 0; j < 2; ++j)                                     \
                    acc[QM][QN][i][j] = __builtin_amdgcn_mfma_f32_16x16x32_bf16(\
                        af[s2][i], bfr[s2][j], acc[QM][QN][i][j], 0, 0, 0);     \
        __builtin_amdgcn_s_setprio(0);                                          \
        DOWAIT;                                                                 \
        BAR();                                                                  \
    } while (0)

    stage(0, 1, 0, 0);
    stage(0, 0, 0, 0);
    stage(0, 1, 1, 0);
    stage(0, 0, 1, 0);
    if (nk > 1) { VMW4(); } else { VMW0(); }
    BAR();

    for (int t = 0; t < nk - 1; ++t) {
        const int  buf = t & 1, nb = buf ^ 1;
        const int  kk  = (t + 1) << 6;
        const bool pf  = true;
        PHASE(buf, 0, 0, 1, 0, VMW4());
        PHASE(buf, 1, 0, 0, 0, VMW4());
        PHASE(buf, 1, 1, 1, 1, (void)0);
        PHASE(buf, 0, 1, 0, 1, VMW4());
    }
    {
        const int  buf = (nk - 1) & 1, nb = buf ^ 1; (void)nb;
        const int  kk  = 0;
        const bool pf  = false;
        PHASE(buf, 0, 0, 1, 0, VMW2());
        PHASE(buf, 1, 0, 0, 0, VMW0());
        PHASE(buf, 1, 1, 1, 1, (void)0);
        PHASE(buf, 0, 1, 0, 1, (void)0);
    }
#undef PHASE

    #pragma unroll
    for (int qm = 0; qm < 2; ++qm)
        #pragma unroll
        for (int qn = 0; qn < 2; ++qn)
            #pragma unroll
            for (int i = 0; i < 4; ++i)
                #pragma unroll
                for (int j = 0; j < 2; ++j) {
                    const int gr = bm0 + qm * 128 + wm * 64 + i * 16 + kg * 4;
                    const int gc = bn0 + qn * 128 + wn * 32 + j * 16 + lr;
                    #pragma unroll
                    for (int p = 0; p < 4; ++p)
                        C[(long long)(gr + p) * ldc + gc] = acc[qm][qn][i][j][p];
                }
}

// ---------------------------------------------------------------------------
// 128x(BN) double-buffered 2-phase GEMM. A bf16 [M][K], B bf16 [N][K].
// EPI: 0=f32, 1=bf16*scale, 3=bf16 gelu(acc+bias),
//      4=qkv: Q,K cols -> bf16 to Cg; V cols (>=2048) -> transposed s16x4 to
//        aux as Vt[(b*16+h)*64+d][t] (4 consecutive tokens per store).
// z batches via sAz/sBz/sCz (split-K partials).
// ---------------------------------------------------------------------------
template<int BN, int EPI>
__global__ __launch_bounds__(256) void gemm_k(
    const short* __restrict__ Ag, const short* __restrict__ Bg,
    void* __restrict__ Cg, const float* __restrict__ bias,
    short* __restrict__ aux,
    int M, int N, int K, int lda, int ldb, int ldc,
    long long sAz, long long sBz, long long sCz,
    float scale, int swz)
{
    int bx = blockIdx.x, by = blockIdx.y;
    if (swz) {
        const int gx = gridDim.x;
        const int nwg = gx * gridDim.y;
        if ((nwg & 7) == 0) {
            int wg = by * gx + bx;
            int wg2 = (wg & 7) * (nwg >> 3) + (wg >> 3);
            bx = wg2 % gx; by = wg2 / gx;
        }
    }
    const int bn0 = bx * BN, bm0 = by * 128;
    const int zz = blockIdx.z;

    const short* A = Ag + zz * sAz;
    const short* B = Bg + zz * sBz;

    __shared__ short Als[2][128 * 64];
    __shared__ short Bls[2][BN * 64];

    const int tid  = threadIdx.x;
    const int lane = tid & 63;
    const int wave = tid >> 6;
    constexpr int WMS = (BN == 128) ? 64 : 32;
    constexpr int MI  = (BN == 128) ? 4 : 2;
    constexpr int NJ  = 4;
    const int wm = (BN == 128) ? (wave >> 1) : wave;
    const int wn = (BN == 128) ? (wave & 1) : 0;
    const int lr = lane & 15, kg = lane >> 4;
    const int xv = (lr & 7) << 4;

    const int sr = tid >> 3;
    const int sc = (tid & 7) ^ (sr & 7);
    const short* aP = A + (long long)(bm0 + sr) * lda + sc * 8;
    const short* bP = B + (long long)(bn0 + sr) * ldb + sc * 8;

    f32x4 acc[MI][NJ] = {};
    const int nk = K >> 6;

    auto stage = [&](int buf, int kt) {
        const int k0 = kt << 6;
        short* aL = &Als[buf][wave * 512];
        short* bL = &Bls[buf][wave * 512];
        #pragma unroll
        for (int it = 0; it < 4; ++it)
            llds16(aP + (long long)it * 32 * lda + k0, aL + it * 2048);
        #pragma unroll
        for (int it = 0; it < BN / 32; ++it)
            llds16(bP + (long long)it * 32 * ldb + k0, bL + it * 2048);
    };

    stage(0, 0);
    __syncthreads();

    for (int kt = 0; kt < nk; ++kt) {
        const int cb = kt & 1;
        if (kt + 1 < nk) stage(cb ^ 1, kt + 1);

        #pragma unroll
        for (int s = 0; s < 2; ++s) {
            const int ofs = (((s << 6) | (kg << 4)) ^ xv) >> 1;
            bf16x8 af[MI], bf[NJ];
            #pragma unroll
            for (int i = 0; i < MI; ++i)
                af[i] = *(const bf16x8*)&Als[cb][(wm * WMS + i * 16 + lr) * 64 + ofs];
            #pragma unroll
            for (int j = 0; j < NJ; ++j)
                bf[j] = *(const bf16x8*)&Bls[cb][(wn * 64 + j * 16 + lr) * 64 + ofs];
            #pragma unroll
            for (int i = 0; i < MI; ++i)
                #pragma unroll
                for (int j = 0; j < NJ; ++j)
                    acc[i][j] = __builtin_amdgcn_mfma_f32_16x16x32_bf16(
                        af[i], bf[j], acc[i][j], 0, 0, 0);
        }
        __syncthreads();
    }

    short* Cs = (short*)Cg + zz * sCz;
    float* Cf = (float*)Cg + zz * sCz;
    #pragma unroll
    for (int i = 0; i < MI; ++i) {
        #pragma unroll
        for (int j = 0; j < NJ; ++j) {
            const int gr = bm0 + wm * WMS + i * 16 + kg * 4;
            const int gc = bn0 + wn * 64 + j * 16 + lr;
            if (EPI == 4 && gc >= 2 * DMODEL) {
                // V column -> transposed write into Vt[(b*16+h)*64+d][t]
                const int b = gr >> 10, t0 = gr & (TSEQ - 1);
                const int h = (gc - 2 * DMODEL) >> 6, d = gc & 63;
                s16x4 vv;
                #pragma unroll
                for (int p = 0; p < 4; ++p) vv[p] = f2bf(acc[i][j][p]);
                *(s16x4*)&aux[((long long)(b * NHEAD + h) * HDIM + d) * TSEQ + t0] = vv;
            } else {
                #pragma unroll
                for (int p = 0; p < 4; ++p) {
                    const long long off = (long long)(gr + p) * ldc + gc;
                    float v = acc[i][j][p];
                    if (EPI == 0) {
                        Cf[off] = v;
                    } else if (EPI == 1 || EPI == 4) {
                        Cs[off] = f2bf(v * scale);
                    } else {
                        v += bias[gc];
                        v = 0.5f * v * (1.0f + erff(v * 0.70710678118654752f));
                        Cs[off] = f2bf(v);
                    }
                }
            }
        }
    }
}

// ---------------------------------------------------------------------------
// wave-per-row fused split-K reduce + residual + LayerNorm (no barriers):
//   v = x + sum_{k<NP} fp[k] + bias;  x = v;  o = LN(v) -> bf16
// ---------------------------------------------------------------------------
template<int NP>
__global__ __launch_bounds__(256) void fredln_k(
    const float* __restrict__ fp, long long pstride,
    const float* __restrict__ bias, float* __restrict__ x,
    const float* __restrict__ lw, const float* __restrict__ lb,
    short* __restrict__ o)
{
    const int row  = blockIdx.x * 4 + (threadIdx.x >> 6);
    const int lane = threadIdx.x & 63;
    const long long base = (long long)row * DMODEL + lane * 16;
    const int cb = lane * 16;
    float4 v[4];
    #pragma unroll
    for (int q = 0; q < 4; ++q) {
        v[q] = *(const float4*)&x[base + q * 4];
        float4 bb = *(const float4*)&bias[cb + q * 4];
        v[q].x += bb.x; v[q].y += bb.y; v[q].z += bb.z; v[q].w += bb.w;
        #pragma unroll
        for (int k = 0; k < NP; ++k) {
            float4 pp = *(const float4*)&fp[k * pstride + base + q * 4];
            v[q].x += pp.x; v[q].y += pp.y; v[q].z += pp.z; v[q].w += pp.w;
        }
        *(float4*)&x[base + q * 4] = v[q];
    }
    float s = 0.f, s2 = 0.f;
    #pragma unroll
    for (int q = 0; q < 4; ++q) {
        s  += v[q].x + v[q].y + v[q].z + v[q].w;
        s2 += v[q].x * v[q].x + v[q].y * v[q].y + v[q].z * v[q].z + v[q].w * v[q].w;
    }
    #pragma unroll
    for (int d = 1; d < 64; d <<= 1) {
        s  += __shfl_xor(s, d, 64);
        s2 += __shfl_xor(s2, d, 64);
    }
    const float mean = s * (1.0f / DMODEL);
    const float var  = s2 * (1.0f / DMODEL) - mean * mean;
    const float rs   = rsqrtf(var + 1e-5f);
    short ov[16];
    #pragma unroll
    for (int q = 0; q < 4; ++q) {
        float4 wv = *(const float4*)&lw[cb + q * 4];
        float4 bv = *(const float4*)&lb[cb + q * 4];
        ov[q * 4 + 0] = f2bf((v[q].x - mean) * rs * wv.x + bv.x);
        ov[q * 4 + 1] = f2bf((v[q].y - mean) * rs * wv.y + bv.y);
        ov[q * 4 + 2] = f2bf((v[q].z - mean) * rs * wv.z + bv.z);
        ov[q * 4 + 3] = f2bf((v[q].w - mean) * rs * wv.w + bv.w);
    }
    short* op = o + base;
    *(s16x8*)op       = *(s16x8*)&ov[0];
    *(s16x8*)(op + 8) = *(s16x8*)&ov[8];
}

// embed + LN(layer-0 ln1). One block per row.
__global__ __launch_bounds__(256) void embedln_k(
    const int* __restrict__ ids, const float* __restrict__ tok,
    const float* __restrict__ pos, float* __restrict__ x,
    const float* __restrict__ lw, const float* __restrict__ lb,
    short* __restrict__ o)
{
    const int row = blockIdx.x;
    const int t   = row & (TSEQ - 1);
    const int id  = ids[row];
    const int i   = threadIdx.x * 4;
    const long long base = (long long)row * DMODEL;
    float4 a = *(const float4*)&tok[(long long)id * DMODEL + i];
    float4 p = *(const float4*)&pos[(long long)t * DMODEL + i];
    float4 v;
    v.x = a.x + p.x; v.y = a.y + p.y; v.z = a.z + p.z; v.w = a.w + p.w;
    *(float4*)&x[base + i] = v;
    float s  = v.x + v.y + v.z + v.w;
    float s2 = v.x * v.x + v.y * v.y + v.z * v.z + v.w * v.w;
    s  = block_sum(s);
    s2 = block_sum(s2);
    const float mean = s * (1.0f / DMODEL);
    const float var  = s2 * (1.0f / DMODEL) - mean * mean;
    const float rs   = rsqrtf(var + 1e-5f);
    float4 wv = *(const float4*)&lw[i];
    float4 bv = *(const float4*)&lb[i];
    s16x4 ov;
    ov[0] = f2bf((v.x - mean) * rs * wv.x + bv.x);
    ov[1] = f2bf((v.y - mean) * rs * wv.y + bv.y);
    ov[2] = f2bf((v.z - mean) * rs * wv.z + bv.z);
    ov[3] = f2bf((v.w - mean) * rs * wv.w + bv.w);
    *(s16x4*)&o[base + i] = ov;
}

// ---------------------------------------------------------------------------
// transpose-convert core (64x64 tile) — weight conversion only
template<typename T>
DEV_INLINE void tcvt_body(const T* sp, short* dp, int lds_, int ldd,
                          int bx, int by, short (*ls)[68], int t)
{
    const int tr0 = by * 64, tc0 = bx * 64;
    const int rr = t >> 4, cc = (t & 15) * 4;
    #pragma unroll
    for (int q = 0; q < 4; ++q) {
        const int r = q * 16 + rr;
        if constexpr (sizeof(T) == 4) {
            float4 v = *(const float4*)&sp[(long long)(tr0 + r) * lds_ + tc0 + cc];
            ls[cc + 0][r] = f2bf(v.x); ls[cc + 1][r] = f2bf(v.y);
            ls[cc + 2][r] = f2bf(v.z); ls[cc + 3][r] = f2bf(v.w);
        } else {
            s16x4 v = *(const s16x4*)&sp[(long long)(tr0 + r) * lds_ + tc0 + cc];
            ls[cc + 0][r] = v[0]; ls[cc + 1][r] = v[1];
            ls[cc + 2][r] = v[2]; ls[cc + 3][r] = v[3];
        }
    }
    __syncthreads();
    #pragma unroll
    for (int q = 0; q < 4; ++q) {
        const int c = q * 16 + rr;
        s16x4 v;
        v[0] = ls[c][cc]; v[1] = ls[c][cc + 1]; v[2] = ls[c][cc + 2]; v[3] = ls[c][cc + 3];
        *(s16x4*)&dp[(long long)(tc0 + c) * ldd + tr0 + cc] = v;
    }
}

template<typename T>
__global__ __launch_bounds__(256) void tcvt_k(
    const T* __restrict__ src, short* __restrict__ dst,
    int lds_, int ldd, int Hdiv,
    long long sSb, long long sSh, long long sDb, long long sDh)
{
    __shared__ short ls[64][68];
    const int z = blockIdx.z, zb = z / Hdiv, zh = z - zb * Hdiv;
    tcvt_body<T>(src + zb * sSb + zh * sSh, dst + zb * sDb + zh * sDh,
                 lds_, ldd, blockIdx.x, blockIdx.y, ls, threadIdx.x);
}

// merged per-layer weight convert (!big path): 3072 blocks
__global__ __launch_bounds__(256) void wcvt_k(
    const float* __restrict__ qw, const float* __restrict__ ow,
    const float* __restrict__ f1, const float* __restrict__ f2,
    short* __restrict__ wq, short* __restrict__ wo,
    short* __restrict__ w1, short* __restrict__ w2)
{
    __shared__ short ls[64][68];
    const int id = blockIdx.x;
    const float* src; short* dst; int lds_, ldd, bx, by;
    if (id < 768)       { src = qw; dst = wq; lds_ = 3072; ldd = 1024; bx = id % 48;  by = id / 48; }
    else if (id < 1024) { int i = id - 768;  src = ow; dst = wo; lds_ = 1024; ldd = 1024; bx = i % 16; by = i / 16; }
    else if (id < 2048) { int i = id - 1024; src = f1; dst = w1; lds_ = 4096; ldd = 1024; bx = i % 64; by = i / 64; }
    else                { int i = id - 2048; src = f2; dst = w2; lds_ = 1024; ldd = 4096; bx = i % 16; by = i / 16; }
    tcvt_body<float>(src, dst, lds_, ldd, bx, by, ls, threadIdx.x);
}

// plain fp32 -> bf16 convert (n4 = count/4)
__global__ __launch_bounds__(256) void cvt_k(
    const float* __restrict__ s, short* __restrict__ d, int n4)
{
    int i = blockIdx.x * 256 + threadIdx.x;
    const int stride = gridDim.x * 256;
    for (; i < n4; i += stride) {
        float4 v = *(const float4*)&s[(long long)i * 4];
        s16x4 o = { f2bf(v.x), f2bf(v.y), f2bf(v.z), f2bf(v.w) };
        *(s16x4*)&d[(long long)i * 4] = o;
    }
}

// ---------------------------------------------------------------------------
extern "C" void kernel_launch(void* const* d_in, const int* in_sizes, int n_in,
                              void* d_out, int out_size, void* d_ws, size_t ws_size,
                              hipStream_t stream)
{
    const int*   ids  = (const int*)  d_in[0];
    const float* tok  = (const float*)d_in[1];
    const float* pos  = (const float*)d_in[2];
    const float* ln1w = (const float*)d_in[3];
    const float* ln1b = (const float*)d_in[4];
    const float* qkvw = (const float*)d_in[5];
    const float* outw = (const float*)d_in[6];
    const float* outb = (const float*)d_in[7];
    const float* ln2w = (const float*)d_in[8];
    const float* ln2b = (const float*)d_in[9];
    const float* fc1w = (const float*)d_in[10];
    const float* fc1b = (const float*)d_in[11];
    const float* fc2w = (const float*)d_in[12];
    const float* fc2b = (const float*)d_in[13];
    const float* lnfw = (const float*)d_in[14];
    const float* lnfb = (const float*)d_in[15];
    float* out = (float*)d_out;

    char* ws = (char*)d_ws;
    const size_t MB = 1024 * 1024;
    float* x    = (float*)(ws);             //  0-8   f32 residual
    short* hb   = (short*)(ws + 8  * MB);   //  8-12  bf16 [2048][1024]
    short* qkvb = (short*)(ws + 12 * MB);   // 12-24  bf16 [2048][3072] (V region unused)
    short* g    = (short*)(ws + 24 * MB);   // 24-40  bf16 [2048][4096]
    short* Vt   = (short*)(ws + 40 * MB);   // 40-44  bf16 [32][64][1024]
    float* fp   = (float*)(ws + 44 * MB);   // 44-76  f32 [4][2048][1024] partials
    short* tokb = (short*)(ws + 12 * MB);   // lm_head phase only (aliases dead bufs)

    const bool big = ws_size >= (size_t)272 * MB;
    short* wq = (short*)(ws + 80 * MB);
    short *wo, *w1, *w2;
    if (big) {
        wo = (short*)(ws + 128 * MB);
        w1 = (short*)(ws + 144 * MB);
        w2 = (short*)(ws + 208 * MB);       // ends 272
    } else {
        wo = (short*)(ws + 86 * MB);
        w1 = (short*)(ws + 88 * MB);
        w2 = (short*)(ws + 96 * MB);        // ends 104
    }

    const long long LWQ = 3072LL * 1024, LWO = 1024LL * 1024;
    const long long LW1 = 4096LL * 1024, LW2 = 1024LL * 4096;
    const long long MD  = (long long)MTOK * DMODEL;

    hipFuncSetAttribute((const void*)gemm256_k,
                        hipFuncAttributeMaxDynamicSharedMemorySize, 131072);

    dim3 blk(256);
    // x = tok_emb[ids] + pos ; hb = LN1_0(x)
    embedln_k<<<MTOK, blk, 0, stream>>>(ids, tok, pos, x, ln1w, ln1b, hb);

    if (big) {
        tcvt_k<float><<<dim3(48, 16, 8), blk, 0, stream>>>(qkvw, wq, 3072, 1024, 1, LWQ, 0, LWQ, 0);
        tcvt_k<float><<<dim3(16, 16, 8), blk, 0, stream>>>(outw, wo, 1024, 1024, 1, LWO, 0, LWO, 0);
        tcvt_k<float><<<dim3(64, 16, 8), blk, 0, stream>>>(fc1w, w1, 4096, 1024, 1, LW1, 0, LW1, 0);
        tcvt_k<float><<<dim3(16, 64, 8), blk, 0, stream>>>(fc2w, w2, 1024, 4096, 1, LW2, 0, LW2, 0);
    }

    for (int l = 0; l < NLAYER; ++l) {
        short* wql = wq + (big ? l * LWQ : 0);
        short* wol = wo + (big ? l * LWO : 0);
        short* w1l = w1 + (big ? l * LW1 : 0);
        short* w2l = w2 + (big ? l * LW2 : 0);
        if (!big)
            wcvt_k<<<3072, blk, 0, stream>>>(
                qkvw + l * LWQ, outw + l * LWO, fc1w + l * LW1, fc2w + l * LW2,
                wql, wol, w1l, w2l);

        // qkv = ln1 @ Wqkv -> Q,K bf16 to qkvb; V transposed to Vt (EPI=4)
        gemm_k<128, 4><<<dim3(24, 16, 1), blk, 0, stream>>>(
            hb, wql, qkvb, nullptr, Vt,
            MTOK, 3 * DMODEL, DMODEL, DMODEL, DMODEL, 3 * DMODEL,
            0, 0, 0, 1.0f, 1);

        // fused attention -> hb (bf16)
        flash_k<<<dim3(8, BBATCH * NHEAD), blk, 0, stream>>>(qkvb, Vt, hb);

        // out-proj split-K=2 -> partials; then x += sum + bias, hb = LN2(x)
        gemm_k<128, 0><<<dim3(8, 16, 2), blk, 0, stream>>>(
            hb, wol, fp, nullptr, nullptr,
            MTOK, DMODEL, 512, DMODEL, DMODEL, DMODEL,
            512, 512, MD, 1.0f, 1);
        fredln_k<2><<<MTOK / 4, blk, 0, stream>>>(
            fp, MD, outb + l * DMODEL, x,
            ln2w + l * DMODEL, ln2b + l * DMODEL, hb);

        // g = gelu(ln2 @ Wfc1 + b) -> bf16
        gemm_k<128, 3><<<dim3(32, 16, 1), blk, 0, stream>>>(
            hb, w1l, g, fc1b + (long long)l * 4 * DMODEL, nullptr,
            MTOK, 4 * DMODEL, DMODEL, DMODEL, DMODEL, 4 * DMODEL,
            0, 0, 0, 1.0f, 1);

        // fc2 split-K=4 -> partials; then x += sum + bias, hb = next LN
        gemm_k<128, 0><<<dim3(8, 16, 4), blk, 0, stream>>>(
            g, w2l, fp, nullptr, nullptr,
            MTOK, DMODEL, 1024, 4 * DMODEL, 4 * DMODEL, DMODEL,
            1024, 1024, MD, 1.0f, 1);
        const float* nlw = (l < 7) ? ln1w + (l + 1) * DMODEL : lnfw;
        const float* nlb = (l < 7) ? ln1b + (l + 1) * DMODEL : lnfb;
        fredln_k<4><<<MTOK / 4, blk, 0, stream>>>(
            fp, MD, fc2b + l * DMODEL, x, nlw, nlb, hb);
    }

    // tok_emb -> bf16 (tokb aliases dead activation buffers)
    cvt_k<<<2048, blk, 0, stream>>>(tok, tokb, NVOCAB * DMODEL / 4);

    // logits = lnf @ tok_emb^T via 256x256 8-phase kernel (grid = 125*8)
    gemm256_k<<<dim3((NVOCAB / 256) * (MTOK / 256)), dim3(512), 131072, stream>>>(
        hb, tokb, out, DMODEL, DMODEL, DMODEL, NVOCAB, NVOCAB / 256);
}